// Round 4
// baseline (460.173 us; speedup 1.0000x reference)
//
#include <hip/hip_runtime.h>

#define BB 64
#define PP 100
#define NN 1000
#define DDIM 128
#define HH 8
#define NSPL 8
#define TN 25   // K/V rows staged in LDS per chunk in attn

// ---------------------------------------------------------------------------
// Fused K+V projection, uniform-x structure.
// Block 256 = {tid<128: K col j | tid>=128: V col j}; ALL threads process the
// SAME 16 rows, so x addresses are block-uniform -> s_load (SMEM pipe) and
// x values ride in SGPRs (v_fma v,s,v,v). Round-3 version was VMEM-issue
// bound (VALUBusy 28%): per-lane float4 loads of wave-uniform x data.
// grid = rows/16.
// ---------------------------------------------------------------------------
__global__ __launch_bounds__(256) void proj_kv_kernel(
    const float* __restrict__ x, const float* __restrict__ Wa,
    const float* __restrict__ Wb, float* __restrict__ outa,
    float* __restrict__ outb)
{
  const int tid = threadIdx.x;
  const int j = tid & 127;
  const float* __restrict__ W = (tid < 128) ? Wa : Wb;
  float* __restrict__ out = (tid < 128) ? outa : outb;
  const float* xb = x + (size_t)blockIdx.x * (16 * DDIM);

  float acc[16];
#pragma unroll
  for (int r = 0; r < 16; ++r) acc[r] = 0.f;

#pragma unroll 2
  for (int dc = 0; dc < DDIM; dc += 4) {
    const float w0 = W[(dc + 0) * DDIM + j];
    const float w1 = W[(dc + 1) * DDIM + j];
    const float w2 = W[(dc + 2) * DDIM + j];
    const float w3 = W[(dc + 3) * DDIM + j];
#pragma unroll
    for (int r = 0; r < 16; ++r) {
      const float4 xv = *(const float4*)(xb + r * DDIM + dc);  // uniform -> s_load
      acc[r] = fmaf(xv.w, w3, fmaf(xv.z, w2, fmaf(xv.y, w1, fmaf(xv.x, w0, acc[r]))));
    }
  }
  float* o = out + (size_t)blockIdx.x * (16 * DDIM) + j;
#pragma unroll
  for (int r = 0; r < 16; ++r) o[r * DDIM] = acc[r];
}

// ---------------------------------------------------------------------------
// Fused Q projection: out = (x1@W1 + x2@W2) * scale. 32-row tile; row-half
// chosen via readfirstlane so x addresses are provably wave-uniform.
// grid = rows/32, block 256 (j = tid&127).
// ---------------------------------------------------------------------------
__global__ __launch_bounds__(256) void proj_q2_kernel(
    const float* __restrict__ x1, const float* __restrict__ x2,
    const float* __restrict__ W1, const float* __restrict__ W2,
    float* __restrict__ out, float scale)
{
  const int tid = threadIdx.x;
  const int j = tid & 127;
  const int rhalf = __builtin_amdgcn_readfirstlane(tid >> 7);  // SGPR -> uniform
  const size_t r0 = (size_t)blockIdx.x * 32 + rhalf * 16;
  const float* xb1 = x1 + r0 * DDIM;
  const float* xb2 = x2 + r0 * DDIM;

  float acc[16];
#pragma unroll
  for (int r = 0; r < 16; ++r) acc[r] = 0.f;

#pragma unroll 2
  for (int dc = 0; dc < DDIM; dc += 4) {
    const float a0 = W1[(dc + 0) * DDIM + j];
    const float a1 = W1[(dc + 1) * DDIM + j];
    const float a2 = W1[(dc + 2) * DDIM + j];
    const float a3 = W1[(dc + 3) * DDIM + j];
#pragma unroll
    for (int r = 0; r < 16; ++r) {
      const float4 xv = *(const float4*)(xb1 + r * DDIM + dc);
      acc[r] = fmaf(xv.w, a3, fmaf(xv.z, a2, fmaf(xv.y, a1, fmaf(xv.x, a0, acc[r]))));
    }
    const float b0 = W2[(dc + 0) * DDIM + j];
    const float b1 = W2[(dc + 1) * DDIM + j];
    const float b2 = W2[(dc + 2) * DDIM + j];
    const float b3 = W2[(dc + 3) * DDIM + j];
#pragma unroll
    for (int r = 0; r < 16; ++r) {
      const float4 xv = *(const float4*)(xb2 + r * DDIM + dc);
      acc[r] = fmaf(xv.w, b3, fmaf(xv.z, b2, fmaf(xv.y, b1, fmaf(xv.x, b0, acc[r]))));
    }
  }
  float* o = out + r0 * DDIM + j;
#pragma unroll
  for (int r = 0; r < 16; ++r) o[r * DDIM] = acc[r] * scale;
}

// ---------------------------------------------------------------------------
// Combine projection with bias: out = x@W + bias. Same uniform-x structure.
// grid = rows/32, block 256.
// ---------------------------------------------------------------------------
__global__ __launch_bounds__(256) void proj_bias_kernel(
    const float* __restrict__ x, const float* __restrict__ W,
    const float* __restrict__ bias, float* __restrict__ out)
{
  const int tid = threadIdx.x;
  const int j = tid & 127;
  const int rhalf = __builtin_amdgcn_readfirstlane(tid >> 7);
  const size_t r0 = (size_t)blockIdx.x * 32 + rhalf * 16;
  const float* xb = x + r0 * DDIM;
  const float bj = bias[j];

  float acc[16];
#pragma unroll
  for (int r = 0; r < 16; ++r) acc[r] = bj;

#pragma unroll 2
  for (int dc = 0; dc < DDIM; dc += 4) {
    const float w0 = W[(dc + 0) * DDIM + j];
    const float w1 = W[(dc + 1) * DDIM + j];
    const float w2 = W[(dc + 2) * DDIM + j];
    const float w3 = W[(dc + 3) * DDIM + j];
#pragma unroll
    for (int r = 0; r < 16; ++r) {
      const float4 xv = *(const float4*)(xb + r * DDIM + dc);
      acc[r] = fmaf(xv.w, w3, fmaf(xv.z, w2, fmaf(xv.y, w1, fmaf(xv.x, w0, acc[r]))));
    }
  }
  float* o = out + r0 * DDIM + j;
#pragma unroll
  for (int r = 0; r < 16; ++r) o[r * DDIM] = acc[r];
}

// ---------------------------------------------------------------------------
// attention, split over N, K/V staged in LDS. thread = (p-pair, head).
// grid = BB*NSPL, block = 448 (pg<50 active). (unchanged this round)
// ---------------------------------------------------------------------------
__global__ __launch_bounds__(448) void attn_kernel(
    const float* __restrict__ Q, const float* __restrict__ K,
    const float* __restrict__ V, const float* __restrict__ mask,
    float* __restrict__ po, float* __restrict__ lsum)
{
  __shared__ float Ks[TN * DDIM];
  __shared__ float Vs[TN * DDIM];

  const int b = blockIdx.x >> 3;
  const int split = blockIdx.x & 7;
  const int t = threadIdx.x;
  const int pg = t >> 3;
  const int h = t & 7;
  const bool act = pg < 50;
  const int p0 = (act ? pg : 49) * 2;

  float q0[16], q1[16];
  const float* qp0 = Q + (b * PP + p0) * DDIM + h * 16;   // Q pre-scaled by 0.25
#pragma unroll
  for (int c = 0; c < 4; ++c) {
    const float4 a = *(const float4*)(qp0 + 4 * c);
    const float4 bq = *(const float4*)(qp0 + DDIM + 4 * c);
    q0[4*c+0]=a.x;  q0[4*c+1]=a.y;  q0[4*c+2]=a.z;  q0[4*c+3]=a.w;
    q1[4*c+0]=bq.x; q1[4*c+1]=bq.y; q1[4*c+2]=bq.z; q1[4*c+3]=bq.w;
  }
  float a0[16], a1[16];
#pragma unroll
  for (int i = 0; i < 16; ++i) { a0[i] = 0.f; a1[i] = 0.f; }
  float l0 = 0.f, l1 = 0.f;

  const float* m0 = mask + (b * PP + p0) * NN;
  const float* m1 = m0 + NN;

  const int n0 = split * (NN / NSPL);           // 125 n per split
  for (int c0 = 0; c0 < NN / NSPL; c0 += TN) {  // 5 chunks of 25
    __syncthreads();                            // prev chunk fully consumed
    for (int idx = t; idx < TN * 32; idx += 448) {
      const int row = idx >> 5;
      const int col = (idx & 31) * 4;
      const int g = (b * NN + n0 + c0 + row) * DDIM + col;
      *(float4*)&Ks[row * DDIM + col] = *(const float4*)(K + g);
      *(float4*)&Vs[row * DDIM + col] = *(const float4*)(V + g);
    }
    __syncthreads();
#pragma unroll 5
    for (int nn2 = 0; nn2 < TN; ++nn2) {
      const int n = n0 + c0 + nn2;
      const float* kn = &Ks[nn2 * DDIM + h * 16];
      float kr[16];
#pragma unroll
      for (int c = 0; c < 4; ++c) {
        const float4 kv = *(const float4*)(kn + 4 * c);
        kr[4*c+0]=kv.x; kr[4*c+1]=kv.y; kr[4*c+2]=kv.z; kr[4*c+3]=kv.w;
      }
      float s0a=0.f, s0b=0.f, s1a=0.f, s1b=0.f;
#pragma unroll
      for (int i = 0; i < 8; ++i) {
        s0a = fmaf(q0[i],   kr[i],   s0a);
        s0b = fmaf(q0[i+8], kr[i+8], s0b);
        s1a = fmaf(q1[i],   kr[i],   s1a);
        s1b = fmaf(q1[i+8], kr[i+8], s1b);
      }
      const float e0 = __expf((s0a + s0b) + m0[n]);
      const float e1 = __expf((s1a + s1b) + m1[n]);
      l0 += e0; l1 += e1;
      const float* vn = &Vs[nn2 * DDIM + h * 16];
#pragma unroll
      for (int c = 0; c < 4; ++c) {
        const float4 vv = *(const float4*)(vn + 4 * c);
        a0[4*c+0] = fmaf(e0, vv.x, a0[4*c+0]);
        a0[4*c+1] = fmaf(e0, vv.y, a0[4*c+1]);
        a0[4*c+2] = fmaf(e0, vv.z, a0[4*c+2]);
        a0[4*c+3] = fmaf(e0, vv.w, a0[4*c+3]);
        a1[4*c+0] = fmaf(e1, vv.x, a1[4*c+0]);
        a1[4*c+1] = fmaf(e1, vv.y, a1[4*c+1]);
        a1[4*c+2] = fmaf(e1, vv.z, a1[4*c+2]);
        a1[4*c+3] = fmaf(e1, vv.w, a1[4*c+3]);
      }
    }
  }
  if (act) {
    const int base = (b * NSPL + split) * PP + p0;
    float* d0 = po + base * DDIM + h * 16;
#pragma unroll
    for (int c = 0; c < 4; ++c) {
      *(float4*)(d0 + 4*c)        = make_float4(a0[4*c+0],a0[4*c+1],a0[4*c+2],a0[4*c+3]);
      *(float4*)(d0 + DDIM + 4*c) = make_float4(a1[4*c+0],a1[4*c+1],a1[4*c+2],a1[4*c+3]);
    }
    lsum[base * HH + h]       = l0;
    lsum[(base + 1) * HH + h] = l1;
  }
}

// ---------------------------------------------------------------------------
// merge: mh_in[b][p][d] = (sum_s po) / (sum_s lsum[h(d)])
// ---------------------------------------------------------------------------
__global__ __launch_bounds__(256) void merge_kernel(
    const float* __restrict__ po, const float* __restrict__ lsum,
    float* __restrict__ mh_in)
{
  const int idx = blockIdx.x * 256 + threadIdx.x;   // over BB*PP*DDIM
  const int d = idx & 127;
  const int row = idx >> 7;        // b*PP + p
  const int b = row / PP;
  const int p = row - b * PP;
  const int h = d >> 4;
  float s = 0.f, lt = 0.f;
#pragma unroll
  for (int sp = 0; sp < NSPL; ++sp) {
    const int base = (b * NSPL + sp) * PP + p;
    s  += po[base * DDIM + d];
    lt += lsum[base * HH + h];
  }
  mh_in[idx] = s / lt;
}

// ---------------------------------------------------------------------------
// score2 + bias + mask + exp  (softmax numerator; scores bounded by 10.2 so
// no max subtraction needed). Writes e to out, chunk-partial sums to ssum.
// grid = BB*4chunks*2phalf = 512, block = 256 (thread = one n; t<250 active)
// ---------------------------------------------------------------------------
__global__ __launch_bounds__(256) void score2_kernel(
    const float* __restrict__ enc, const float* __restrict__ mh,
    const float* __restrict__ mask, const float* __restrict__ bias_table,
    const int* __restrict__ group_ids, const int* __restrict__ cur_min,
    float* __restrict__ out, float* __restrict__ ssum)
{
  const int b = blockIdx.x >> 3;
  const int chunk = (blockIdx.x >> 1) & 3;
  const int phalf = blockIdx.x & 1;
  const int t = threadIdx.x;
  const int nn = chunk * 250 + t;
  const bool act = (t < 250);
  const int nc = act ? nn : chunk * 250;

  float er[DDIM];
  {
    const float* ep = enc + (b * NN + nc) * DDIM;
#pragma unroll
    for (int c = 0; c < 32; ++c) {
      const float4 v4 = *(const float4*)(ep + 4 * c);
      er[4*c+0]=v4.x; er[4*c+1]=v4.y; er[4*c+2]=v4.z; er[4*c+3]=v4.w;
    }
  }
  const int gid = group_ids[b * NN + nc];
  const float t0 = bias_table[0], t1 = bias_table[1], t2 = bias_table[2],
              t3 = bias_table[3], t4 = bias_table[4];

  __shared__ float psum[50];
  if (t < 50) psum[t] = 0.f;
  __syncthreads();

  const float inv_sqrt_emb = 0.08838834764831845f;  // 1/sqrt(128)
  const int p0 = phalf * 50;
  for (int pi = 0; pi < 50; ++pi) {
    const int p = p0 + pi;
    const float* mhp = mh + (b * PP + p) * DDIM;
    float d0=0.f, d1=0.f, d2=0.f, d3=0.f;
#pragma unroll
    for (int d = 0; d < DDIM; d += 4) {
      d0 = fmaf(er[d+0], mhp[d+0], d0);
      d1 = fmaf(er[d+1], mhp[d+1], d1);
      d2 = fmaf(er[d+2], mhp[d+2], d2);
      d3 = fmaf(er[d+3], mhp[d+3], d3);
    }
    const float dot = (d0 + d1) + (d2 + d3);
    // 10*tanh(x) = 10 - 20/(exp(2x)+1); saturates gracefully at +-10
    const float ex = __expf(dot * inv_sqrt_emb * 2.0f);
    const float sc = 10.0f - 20.0f / (ex + 1.0f);
    const int cmp = cur_min[b * PP + p];
    int delta = gid - cmp;
    delta = delta < 0 ? 0 : (delta > 4 ? 4 : delta);
    const float pb = (delta == 0) ? t0 : (delta == 1) ? t1 : (delta == 2) ? t2
                   : (delta == 3) ? t3 : t4;
    const float m = mask[(b * PP + p) * NN + nc];
    const float e = act ? __expf(sc + pb + m) : 0.0f;   // exp(-inf)=0 handles mask
    if (act) out[(b * PP + p) * NN + nn] = e;
    float wsum = e;
#pragma unroll
    for (int off = 1; off < 64; off <<= 1) wsum += __shfl_xor(wsum, off, 64);
    if ((t & 63) == 0) atomicAdd(&psum[pi], wsum);
  }
  __syncthreads();
  if (t < 50) ssum[(b * PP + p0 + t) * 4 + chunk] = psum[t];
}

// ---------------------------------------------------------------------------
// normalize: out[row][n] /= sum of 4 chunk partials
// ---------------------------------------------------------------------------
__global__ __launch_bounds__(256) void norm_kernel(
    const float* __restrict__ ssum, float* __restrict__ out)
{
  const int row = blockIdx.x;   // b*PP + p
  const float s = ssum[row*4+0] + ssum[row*4+1] + ssum[row*4+2] + ssum[row*4+3];
  const float inv = 1.0f / s;
#pragma unroll
  for (int i = 0; i < 4; ++i) {
    const int c = i * 256 + (int)threadIdx.x;
    if (c < NN) out[row * NN + c] *= inv;
  }
}

// ---------------------------------------------------------------------------
extern "C" void kernel_launch(void* const* d_in, const int* in_sizes, int n_in,
                              void* d_out, int out_size, void* d_ws, size_t ws_size,
                              hipStream_t stream)
{
  (void)in_sizes; (void)n_in; (void)out_size; (void)ws_size;
  const float* enc_nodes  = (const float*)d_in[0];
  const float* enc_q1     = (const float*)d_in[1];
  const float* enc_last   = (const float*)d_in[2];
  const float* ninf       = (const float*)d_in[3];
  const float* Wq_first   = (const float*)d_in[4];
  const float* Wq_last    = (const float*)d_in[5];
  const float* Wk         = (const float*)d_in[6];
  const float* Wv         = (const float*)d_in[7];
  const float* W_comb     = (const float*)d_in[8];
  const float* b_comb     = (const float*)d_in[9];
  const float* bias_table = (const float*)d_in[10];
  const int*   group_ids  = (const int*)d_in[11];
  const int*   cur_min    = (const int*)d_in[12];
  float* out = (float*)d_out;
  float* ws  = (float*)d_ws;

  float* Qw = ws;                    //   819200 floats (reused as mh_in after attn)
  float* Kw = Qw + 819200;           //  8192000
  float* Vw = Kw + 8192000;          //  8192000
  float* po = Vw + 8192000;          //  6553600  (BB*NSPL*PP*DDIM)
  float* ls = po + 6553600;          //   409600  (BB*NSPL*PP*HH)
  float* mh = ls + 409600;           //   819200
  float* sm = mh + 819200;           //    25600  (BB*PP*4)

  // Q = (q1@Wq_first + last@Wq_last) * 0.25  (fold 1/sqrt(QD))
  proj_q2_kernel<<<BB*PP/32, 256, 0, stream>>>(enc_q1, enc_last, Wq_first, Wq_last,
                                               Qw, 0.25f);
  // K, V projections fused (one pass over enc_nodes, uniform-x s_load form)
  proj_kv_kernel<<<BB*NN/16, 256, 0, stream>>>(enc_nodes, Wk, Wv, Kw, Vw);
  // attention partials (LDS-staged K/V)
  attn_kernel<<<BB*NSPL, 448, 0, stream>>>(Qw, Kw, Vw, ninf, po, ls);
  // merge partials -> mh_in (reuses Qw)
  merge_kernel<<<3200, 256, 0, stream>>>(po, ls, Qw);
  // combine: mh = mh_in @ W_comb + b_comb
  proj_bias_kernel<<<BB*PP/32, 256, 0, stream>>>(Qw, W_comb, b_comb, mh);
  // final scores + exp + partial sums
  score2_kernel<<<BB*8, 256, 0, stream>>>(enc_nodes, mh, ninf, bias_table,
                                          group_ids, cur_min, out, sm);
  // normalize
  norm_kernel<<<BB*PP, 256, 0, stream>>>(sm, out);
}

// Round 5
// 376.542 us; speedup vs baseline: 1.2221x; 1.2221x over previous
//
#include <hip/hip_runtime.h>

#define BB 64
#define PP 100
#define NN 1000
#define DDIM 128
#define HH 8
#define NSPL 8
#define TN 25   // K/V rows staged in LDS per chunk in attn

typedef __attribute__((ext_vector_type(8))) short bf16x8;   // 8 bf16 = 4 VGPRs
typedef __attribute__((ext_vector_type(16))) float f32x16;  // MFMA 32x32 acc
typedef __attribute__((ext_vector_type(4))) unsigned u32x4;

__device__ __forceinline__ unsigned bf16rne(float x) {
  unsigned u = __float_as_uint(x);
  return (u + 0x7FFFu + ((u >> 16) & 1u)) >> 16;
}

// ---------------------------------------------------------------------------
// pack W (fp32 128x128) -> MFMA B-fragment layout, split hi/lo bf16.
// wfrag[mat(2)][ct(4)][ks(8)][half(2)][lane(64)] : u32x4 (=8 bf16)
// B-frag semantics (32x32x16): lane holds B[k][col], col=32ct+(lane&31),
// k = 16ks + 8*(lane>>5) + i  (i = element 0..7).
// 4096 threads total.
// ---------------------------------------------------------------------------
__global__ __launch_bounds__(256) void pack_w_kernel(
    const float* __restrict__ Wk, const float* __restrict__ Wv,
    u32x4* __restrict__ wfrag)
{
  const int gid = blockIdx.x * 256 + threadIdx.x;  // [0, 4096)
  const int mat = gid >> 11;
  const int ct = (gid >> 9) & 3;
  const int ks = (gid >> 6) & 7;
  const int lane = gid & 63;
  const float* __restrict__ W = mat ? Wv : Wk;
  const int col = ct * 32 + (lane & 31);
  const int k0 = ks * 16 + (lane >> 5) * 8;
  unsigned hi[4], lo[4];
#pragma unroll
  for (int j = 0; j < 4; ++j) {
    const float x0 = W[(k0 + 2 * j) * DDIM + col];
    const float x1 = W[(k0 + 2 * j + 1) * DDIM + col];
    const unsigned h0 = bf16rne(x0), h1 = bf16rne(x1);
    hi[j] = h0 | (h1 << 16);
    lo[j] = bf16rne(x0 - __uint_as_float(h0 << 16)) |
            (bf16rne(x1 - __uint_as_float(h1 << 16)) << 16);
  }
  const int base = (((mat * 4 + ct) * 8 + ks) * 2) * 64 + lane;
  wfrag[base]      = u32x4{hi[0], hi[1], hi[2], hi[3]};
  wfrag[base + 64] = u32x4{lo[0], lo[1], lo[2], lo[3]};
}

// ---------------------------------------------------------------------------
// K+V projection via MFMA 32x32x16 bf16, split-precision (hi+lo):
//   X@W = Xhi*Whi + Xhi*Wlo + Xlo*Whi   (lo*lo ~2^-18 dropped)
// Block 256 = 4 waves; wave tile 64 rows x 64 cols; block tile 128x128.
// Two passes (K then V) to keep acc at 64 VGPR. A-frags direct from global
// (each X element read once per pass; one 64B line per (row,ks)); B-frags
// from prepacked wfrag, 1 dwordx4/lane, L1-hot. No LDS, no barriers.
// grid = 64000/128 = 500.
// ---------------------------------------------------------------------------
__global__ __launch_bounds__(256) void proj_kv_mfma_kernel(
    const float* __restrict__ x, const u32x4* __restrict__ wfrag,
    float* __restrict__ outk, float* __restrict__ outv)
{
  const int tid = threadIdx.x;
  const int lane = tid & 63;
  const int wid = tid >> 6;
  const int rtp = wid >> 1;   // wave row-pair (0..1)
  const int ctp = wid & 1;    // wave col-pair (0..1)
  const int arow = blockIdx.x * 128 + rtp * 64 + (lane & 31);  // A row (+32*rt)
  const int kgrp = (lane >> 5) * 8;                            // k sub-group

#pragma unroll 1
  for (int mat = 0; mat < 2; ++mat) {
    float* __restrict__ out = mat ? outv : outk;
    f32x16 acc[2][2];
#pragma unroll
    for (int a = 0; a < 2; ++a)
#pragma unroll
      for (int b = 0; b < 2; ++b)
#pragma unroll
        for (int i = 0; i < 16; ++i) acc[a][b][i] = 0.f;

#pragma unroll 1
    for (int ks = 0; ks < 8; ++ks) {
      bf16x8 ahi[2], alo[2];
#pragma unroll
      for (int rt = 0; rt < 2; ++rt) {
        const float* xp = x + (size_t)(arow + rt * 32) * DDIM + ks * 16 + kgrp;
        const float4 xa = *(const float4*)xp;
        const float4 xb = *(const float4*)(xp + 4);
        const float xs0 = xa.x, xs1 = xa.y, xs2 = xa.z, xs3 = xa.w;
        const float xs4 = xb.x, xs5 = xb.y, xs6 = xb.z, xs7 = xb.w;
        unsigned h0, h1, hi4[4], lo4[4];
        h0 = bf16rne(xs0); h1 = bf16rne(xs1);
        hi4[0] = h0 | (h1 << 16);
        lo4[0] = bf16rne(xs0 - __uint_as_float(h0 << 16)) |
                 (bf16rne(xs1 - __uint_as_float(h1 << 16)) << 16);
        h0 = bf16rne(xs2); h1 = bf16rne(xs3);
        hi4[1] = h0 | (h1 << 16);
        lo4[1] = bf16rne(xs2 - __uint_as_float(h0 << 16)) |
                 (bf16rne(xs3 - __uint_as_float(h1 << 16)) << 16);
        h0 = bf16rne(xs4); h1 = bf16rne(xs5);
        hi4[2] = h0 | (h1 << 16);
        lo4[2] = bf16rne(xs4 - __uint_as_float(h0 << 16)) |
                 (bf16rne(xs5 - __uint_as_float(h1 << 16)) << 16);
        h0 = bf16rne(xs6); h1 = bf16rne(xs7);
        hi4[3] = h0 | (h1 << 16);
        lo4[3] = bf16rne(xs6 - __uint_as_float(h0 << 16)) |
                 (bf16rne(xs7 - __uint_as_float(h1 << 16)) << 16);
        ahi[rt] = __builtin_bit_cast(bf16x8, u32x4{hi4[0], hi4[1], hi4[2], hi4[3]});
        alo[rt] = __builtin_bit_cast(bf16x8, u32x4{lo4[0], lo4[1], lo4[2], lo4[3]});
      }
#pragma unroll
      for (int ct = 0; ct < 2; ++ct) {
        const int c = ctp * 2 + ct;
        const int fo = (((mat * 4 + c) * 8 + ks) * 2) * 64 + lane;
        const bf16x8 bhi = __builtin_bit_cast(bf16x8, wfrag[fo]);
        const bf16x8 blo = __builtin_bit_cast(bf16x8, wfrag[fo + 64]);
#pragma unroll
        for (int rt = 0; rt < 2; ++rt) {
          acc[rt][ct] = __builtin_amdgcn_mfma_f32_32x32x16_bf16(
              ahi[rt], bhi, acc[rt][ct], 0, 0, 0);
          acc[rt][ct] = __builtin_amdgcn_mfma_f32_32x32x16_bf16(
              ahi[rt], blo, acc[rt][ct], 0, 0, 0);
          acc[rt][ct] = __builtin_amdgcn_mfma_f32_32x32x16_bf16(
              alo[rt], bhi, acc[rt][ct], 0, 0, 0);
        }
      }
    }
    // C/D layout (m74/m101): col = lane&31, row = (reg&3) + 8*(reg>>2) + 4*(lane>>5)
#pragma unroll
    for (int rt = 0; rt < 2; ++rt)
#pragma unroll
      for (int ct = 0; ct < 2; ++ct) {
        const int colg = ctp * 64 + ct * 32 + (lane & 31);
        const int rowg0 = blockIdx.x * 128 + rtp * 64 + rt * 32 + 4 * (lane >> 5);
#pragma unroll
        for (int r = 0; r < 16; ++r) {
          const int rowg = rowg0 + (r & 3) + 8 * (r >> 2);
          out[(size_t)rowg * DDIM + colg] = acc[rt][ct][r];
        }
      }
  }
}

// ---------------------------------------------------------------------------
// Fused Q projection: out = (x1@W1 + x2@W2) * scale. (unchanged)
// ---------------------------------------------------------------------------
__global__ __launch_bounds__(256) void proj_q2_kernel(
    const float* __restrict__ x1, const float* __restrict__ x2,
    const float* __restrict__ W1, const float* __restrict__ W2,
    float* __restrict__ out, float scale)
{
  const int tid = threadIdx.x;
  const int j = tid & 127;
  const int rhalf = __builtin_amdgcn_readfirstlane(tid >> 7);  // SGPR -> uniform
  const size_t r0 = (size_t)blockIdx.x * 32 + rhalf * 16;
  const float* xb1 = x1 + r0 * DDIM;
  const float* xb2 = x2 + r0 * DDIM;

  float acc[16];
#pragma unroll
  for (int r = 0; r < 16; ++r) acc[r] = 0.f;

#pragma unroll 2
  for (int dc = 0; dc < DDIM; dc += 4) {
    const float a0 = W1[(dc + 0) * DDIM + j];
    const float a1 = W1[(dc + 1) * DDIM + j];
    const float a2 = W1[(dc + 2) * DDIM + j];
    const float a3 = W1[(dc + 3) * DDIM + j];
#pragma unroll
    for (int r = 0; r < 16; ++r) {
      const float4 xv = *(const float4*)(xb1 + r * DDIM + dc);
      acc[r] = fmaf(xv.w, a3, fmaf(xv.z, a2, fmaf(xv.y, a1, fmaf(xv.x, a0, acc[r]))));
    }
    const float b0 = W2[(dc + 0) * DDIM + j];
    const float b1 = W2[(dc + 1) * DDIM + j];
    const float b2 = W2[(dc + 2) * DDIM + j];
    const float b3 = W2[(dc + 3) * DDIM + j];
#pragma unroll
    for (int r = 0; r < 16; ++r) {
      const float4 xv = *(const float4*)(xb2 + r * DDIM + dc);
      acc[r] = fmaf(xv.w, b3, fmaf(xv.z, b2, fmaf(xv.y, b1, fmaf(xv.x, b0, acc[r]))));
    }
  }
  float* o = out + r0 * DDIM + j;
#pragma unroll
  for (int r = 0; r < 16; ++r) o[r * DDIM] = acc[r] * scale;
}

// ---------------------------------------------------------------------------
// Combine projection with bias: out = x@W + bias. (unchanged)
// ---------------------------------------------------------------------------
__global__ __launch_bounds__(256) void proj_bias_kernel(
    const float* __restrict__ x, const float* __restrict__ W,
    const float* __restrict__ bias, float* __restrict__ out)
{
  const int tid = threadIdx.x;
  const int j = tid & 127;
  const int rhalf = __builtin_amdgcn_readfirstlane(tid >> 7);
  const size_t r0 = (size_t)blockIdx.x * 32 + rhalf * 16;
  const float* xb = x + r0 * DDIM;
  const float bj = bias[j];

  float acc[16];
#pragma unroll
  for (int r = 0; r < 16; ++r) acc[r] = bj;

#pragma unroll 2
  for (int dc = 0; dc < DDIM; dc += 4) {
    const float w0 = W[(dc + 0) * DDIM + j];
    const float w1 = W[(dc + 1) * DDIM + j];
    const float w2 = W[(dc + 2) * DDIM + j];
    const float w3 = W[(dc + 3) * DDIM + j];
#pragma unroll
    for (int r = 0; r < 16; ++r) {
      const float4 xv = *(const float4*)(xb + r * DDIM + dc);
      acc[r] = fmaf(xv.w, w3, fmaf(xv.z, w2, fmaf(xv.y, w1, fmaf(xv.x, w0, acc[r]))));
    }
  }
  float* o = out + r0 * DDIM + j;
#pragma unroll
  for (int r = 0; r < 16; ++r) o[r * DDIM] = acc[r];
}

// ---------------------------------------------------------------------------
// attention, split over N, K/V staged in LDS. thread = (p-pair, head).
// grid = BB*NSPL, block = 448 (pg<50 active). (unchanged this round)
// ---------------------------------------------------------------------------
__global__ __launch_bounds__(448) void attn_kernel(
    const float* __restrict__ Q, const float* __restrict__ K,
    const float* __restrict__ V, const float* __restrict__ mask,
    float* __restrict__ po, float* __restrict__ lsum)
{
  __shared__ float Ks[TN * DDIM];
  __shared__ float Vs[TN * DDIM];

  const int b = blockIdx.x >> 3;
  const int split = blockIdx.x & 7;
  const int t = threadIdx.x;
  const int pg = t >> 3;
  const int h = t & 7;
  const bool act = pg < 50;
  const int p0 = (act ? pg : 49) * 2;

  float q0[16], q1[16];
  const float* qp0 = Q + (b * PP + p0) * DDIM + h * 16;   // Q pre-scaled by 0.25
#pragma unroll
  for (int c = 0; c < 4; ++c) {
    const float4 a = *(const float4*)(qp0 + 4 * c);
    const float4 bq = *(const float4*)(qp0 + DDIM + 4 * c);
    q0[4*c+0]=a.x;  q0[4*c+1]=a.y;  q0[4*c+2]=a.z;  q0[4*c+3]=a.w;
    q1[4*c+0]=bq.x; q1[4*c+1]=bq.y; q1[4*c+2]=bq.z; q1[4*c+3]=bq.w;
  }
  float a0[16], a1[16];
#pragma unroll
  for (int i = 0; i < 16; ++i) { a0[i] = 0.f; a1[i] = 0.f; }
  float l0 = 0.f, l1 = 0.f;

  const float* m0 = mask + (b * PP + p0) * NN;
  const float* m1 = m0 + NN;

  const int n0 = split * (NN / NSPL);           // 125 n per split
  for (int c0 = 0; c0 < NN / NSPL; c0 += TN) {  // 5 chunks of 25
    __syncthreads();                            // prev chunk fully consumed
    for (int idx = t; idx < TN * 32; idx += 448) {
      const int row = idx >> 5;
      const int col = (idx & 31) * 4;
      const int g = (b * NN + n0 + c0 + row) * DDIM + col;
      *(float4*)&Ks[row * DDIM + col] = *(const float4*)(K + g);
      *(float4*)&Vs[row * DDIM + col] = *(const float4*)(V + g);
    }
    __syncthreads();
#pragma unroll 5
    for (int nn2 = 0; nn2 < TN; ++nn2) {
      const int n = n0 + c0 + nn2;
      const float* kn = &Ks[nn2 * DDIM + h * 16];
      float kr[16];
#pragma unroll
      for (int c = 0; c < 4; ++c) {
        const float4 kv = *(const float4*)(kn + 4 * c);
        kr[4*c+0]=kv.x; kr[4*c+1]=kv.y; kr[4*c+2]=kv.z; kr[4*c+3]=kv.w;
      }
      float s0a=0.f, s0b=0.f, s1a=0.f, s1b=0.f;
#pragma unroll
      for (int i = 0; i < 8; ++i) {
        s0a = fmaf(q0[i],   kr[i],   s0a);
        s0b = fmaf(q0[i+8], kr[i+8], s0b);
        s1a = fmaf(q1[i],   kr[i],   s1a);
        s1b = fmaf(q1[i+8], kr[i+8], s1b);
      }
      const float e0 = __expf((s0a + s0b) + m0[n]);
      const float e1 = __expf((s1a + s1b) + m1[n]);
      l0 += e0; l1 += e1;
      const float* vn = &Vs[nn2 * DDIM + h * 16];
#pragma unroll
      for (int c = 0; c < 4; ++c) {
        const float4 vv = *(const float4*)(vn + 4 * c);
        a0[4*c+0] = fmaf(e0, vv.x, a0[4*c+0]);
        a0[4*c+1] = fmaf(e0, vv.y, a0[4*c+1]);
        a0[4*c+2] = fmaf(e0, vv.z, a0[4*c+2]);
        a0[4*c+3] = fmaf(e0, vv.w, a0[4*c+3]);
        a1[4*c+0] = fmaf(e1, vv.x, a1[4*c+0]);
        a1[4*c+1] = fmaf(e1, vv.y, a1[4*c+1]);
        a1[4*c+2] = fmaf(e1, vv.z, a1[4*c+2]);
        a1[4*c+3] = fmaf(e1, vv.w, a1[4*c+3]);
      }
    }
  }
  if (act) {
    const int base = (b * NSPL + split) * PP + p0;
    float* d0 = po + base * DDIM + h * 16;
#pragma unroll
    for (int c = 0; c < 4; ++c) {
      *(float4*)(d0 + 4*c)        = make_float4(a0[4*c+0],a0[4*c+1],a0[4*c+2],a0[4*c+3]);
      *(float4*)(d0 + DDIM + 4*c) = make_float4(a1[4*c+0],a1[4*c+1],a1[4*c+2],a1[4*c+3]);
    }
    lsum[base * HH + h]       = l0;
    lsum[(base + 1) * HH + h] = l1;
  }
}

// ---------------------------------------------------------------------------
// merge: mh_in[b][p][d] = (sum_s po) / (sum_s lsum[h(d)])  (unchanged)
// ---------------------------------------------------------------------------
__global__ __launch_bounds__(256) void merge_kernel(
    const float* __restrict__ po, const float* __restrict__ lsum,
    float* __restrict__ mh_in)
{
  const int idx = blockIdx.x * 256 + threadIdx.x;   // over BB*PP*DDIM
  const int d = idx & 127;
  const int row = idx >> 7;        // b*PP + p
  const int b = row / PP;
  const int p = row - b * PP;
  const int h = d >> 4;
  float s = 0.f, lt = 0.f;
#pragma unroll
  for (int sp = 0; sp < NSPL; ++sp) {
    const int base = (b * NSPL + sp) * PP + p;
    s  += po[base * DDIM + d];
    lt += lsum[base * HH + h];
  }
  mh_in[idx] = s / lt;
}

// ---------------------------------------------------------------------------
// score2 + bias + mask + exp. (unchanged)
// ---------------------------------------------------------------------------
__global__ __launch_bounds__(256) void score2_kernel(
    const float* __restrict__ enc, const float* __restrict__ mh,
    const float* __restrict__ mask, const float* __restrict__ bias_table,
    const int* __restrict__ group_ids, const int* __restrict__ cur_min,
    float* __restrict__ out, float* __restrict__ ssum)
{
  const int b = blockIdx.x >> 3;
  const int chunk = (blockIdx.x >> 1) & 3;
  const int phalf = blockIdx.x & 1;
  const int t = threadIdx.x;
  const int nn = chunk * 250 + t;
  const bool act = (t < 250);
  const int nc = act ? nn : chunk * 250;

  float er[DDIM];
  {
    const float* ep = enc + (b * NN + nc) * DDIM;
#pragma unroll
    for (int c = 0; c < 32; ++c) {
      const float4 v4 = *(const float4*)(ep + 4 * c);
      er[4*c+0]=v4.x; er[4*c+1]=v4.y; er[4*c+2]=v4.z; er[4*c+3]=v4.w;
    }
  }
  const int gid = group_ids[b * NN + nc];
  const float t0 = bias_table[0], t1 = bias_table[1], t2 = bias_table[2],
              t3 = bias_table[3], t4 = bias_table[4];

  __shared__ float psum[50];
  if (t < 50) psum[t] = 0.f;
  __syncthreads();

  const float inv_sqrt_emb = 0.08838834764831845f;  // 1/sqrt(128)
  const int p0 = phalf * 50;
  for (int pi = 0; pi < 50; ++pi) {
    const int p = p0 + pi;
    const float* mhp = mh + (b * PP + p) * DDIM;
    float d0=0.f, d1=0.f, d2=0.f, d3=0.f;
#pragma unroll
    for (int d = 0; d < DDIM; d += 4) {
      d0 = fmaf(er[d+0], mhp[d+0], d0);
      d1 = fmaf(er[d+1], mhp[d+1], d1);
      d2 = fmaf(er[d+2], mhp[d+2], d2);
      d3 = fmaf(er[d+3], mhp[d+3], d3);
    }
    const float dot = (d0 + d1) + (d2 + d3);
    // 10*tanh(x) = 10 - 20/(exp(2x)+1)
    const float ex = __expf(dot * inv_sqrt_emb * 2.0f);
    const float sc = 10.0f - 20.0f / (ex + 1.0f);
    const int cmp = cur_min[b * PP + p];
    int delta = gid - cmp;
    delta = delta < 0 ? 0 : (delta > 4 ? 4 : delta);
    const float pb = (delta == 0) ? t0 : (delta == 1) ? t1 : (delta == 2) ? t2
                   : (delta == 3) ? t3 : t4;
    const float m = mask[(b * PP + p) * NN + nc];
    const float e = act ? __expf(sc + pb + m) : 0.0f;   // exp(-inf)=0 handles mask
    if (act) out[(b * PP + p) * NN + nn] = e;
    float wsum = e;
#pragma unroll
    for (int off = 1; off < 64; off <<= 1) wsum += __shfl_xor(wsum, off, 64);
    if ((t & 63) == 0) atomicAdd(&psum[pi], wsum);
  }
  __syncthreads();
  if (t < 50) ssum[(b * PP + p0 + t) * 4 + chunk] = psum[t];
}

// ---------------------------------------------------------------------------
// normalize: out[row][n] /= sum of 4 chunk partials  (unchanged)
// ---------------------------------------------------------------------------
__global__ __launch_bounds__(256) void norm_kernel(
    const float* __restrict__ ssum, float* __restrict__ out)
{
  const int row = blockIdx.x;   // b*PP + p
  const float s = ssum[row*4+0] + ssum[row*4+1] + ssum[row*4+2] + ssum[row*4+3];
  const float inv = 1.0f / s;
#pragma unroll
  for (int i = 0; i < 4; ++i) {
    const int c = i * 256 + (int)threadIdx.x;
    if (c < NN) out[row * NN + c] *= inv;
  }
}

// ---------------------------------------------------------------------------
extern "C" void kernel_launch(void* const* d_in, const int* in_sizes, int n_in,
                              void* d_out, int out_size, void* d_ws, size_t ws_size,
                              hipStream_t stream)
{
  (void)in_sizes; (void)n_in; (void)out_size; (void)ws_size;
  const float* enc_nodes  = (const float*)d_in[0];
  const float* enc_q1     = (const float*)d_in[1];
  const float* enc_last   = (const float*)d_in[2];
  const float* ninf       = (const float*)d_in[3];
  const float* Wq_first   = (const float*)d_in[4];
  const float* Wq_last    = (const float*)d_in[5];
  const float* Wk         = (const float*)d_in[6];
  const float* Wv         = (const float*)d_in[7];
  const float* W_comb     = (const float*)d_in[8];
  const float* b_comb     = (const float*)d_in[9];
  const float* bias_table = (const float*)d_in[10];
  const int*   group_ids  = (const int*)d_in[11];
  const int*   cur_min    = (const int*)d_in[12];
  float* out = (float*)d_out;
  float* ws  = (float*)d_ws;

  float* Qw = ws;                    //   819200 floats (reused as mh_in after attn)
  float* Kw = Qw + 819200;           //  8192000
  float* Vw = Kw + 8192000;          //  8192000
  float* po = Vw + 8192000;          //  6553600  (BB*NSPL*PP*DDIM)
  float* ls = po + 6553600;          //   409600  (BB*NSPL*PP*HH)
  float* mh = ls + 409600;           //   819200
  float* sm = mh + 819200;           //    25600  (BB*PP*4)

  // wfrag (128 KB) aliases the head of po: pack_w + proj_kv complete before
  // attn writes po (stream-ordered), so no conflict.
  u32x4* wfrag = (u32x4*)po;

  // pack W_k/W_v into split-bf16 MFMA fragments
  pack_w_kernel<<<16, 256, 0, stream>>>(Wk, Wv, wfrag);
  // Q = (q1@Wq_first + last@Wq_last) * 0.25  (fold 1/sqrt(QD))
  proj_q2_kernel<<<BB*PP/32, 256, 0, stream>>>(enc_q1, enc_last, Wq_first, Wq_last,
                                               Qw, 0.25f);
  // K, V projections via split-bf16 MFMA
  proj_kv_mfma_kernel<<<BB*NN/128, 256, 0, stream>>>(enc_nodes, wfrag, Kw, Vw);
  // attention partials (LDS-staged K/V)
  attn_kernel<<<BB*NSPL, 448, 0, stream>>>(Qw, Kw, Vw, ninf, po, ls);
  // merge partials -> mh_in (reuses Qw)
  merge_kernel<<<3200, 256, 0, stream>>>(po, ls, Qw);
  // combine: mh = mh_in @ W_comb + b_comb
  proj_bias_kernel<<<BB*PP/32, 256, 0, stream>>>(Qw, W_comb, b_comb, mh);
  // final scores + exp + partial sums
  score2_kernel<<<BB*8, 256, 0, stream>>>(enc_nodes, mh, ninf, bias_table,
                                          group_ids, cur_min, out, sm);
  // normalize
  norm_kernel<<<BB*PP, 256, 0, stream>>>(sm, out);
}

// Round 6
// 289.724 us; speedup vs baseline: 1.5883x; 1.2997x over previous
//
#include <hip/hip_runtime.h>

#define BB 64
#define PP 100
#define NN 1000
#define DDIM 128
#define HH 8
#define NSPL 8
#define TN 25   // K/V rows staged in LDS per chunk in attn

typedef __attribute__((ext_vector_type(8))) short bf16x8;   // 8 bf16 = 4 VGPRs
typedef __attribute__((ext_vector_type(16))) float f32x16;  // MFMA 32x32 acc
typedef __attribute__((ext_vector_type(4))) unsigned u32x4;

__device__ __forceinline__ unsigned bf16rne(float x) {
  unsigned u = __float_as_uint(x);
  return (u + 0x7FFFu + ((u >> 16) & 1u)) >> 16;
}

// split 8 contiguous floats into hi/lo bf16x8 fragments
__device__ __forceinline__ void split8(const float* __restrict__ p,
                                       bf16x8& hi8, bf16x8& lo8) {
  const float4 a = *(const float4*)p;
  const float4 c = *(const float4*)(p + 4);
  const float v0 = a.x, v1 = a.y, v2 = a.z, v3 = a.w;
  const float v4 = c.x, v5 = c.y, v6 = c.z, v7 = c.w;
  unsigned hi[4], lo[4];
  unsigned h0, h1;
  h0 = bf16rne(v0); h1 = bf16rne(v1);
  hi[0] = h0 | (h1 << 16);
  lo[0] = bf16rne(v0 - __uint_as_float(h0 << 16)) |
          (bf16rne(v1 - __uint_as_float(h1 << 16)) << 16);
  h0 = bf16rne(v2); h1 = bf16rne(v3);
  hi[1] = h0 | (h1 << 16);
  lo[1] = bf16rne(v2 - __uint_as_float(h0 << 16)) |
          (bf16rne(v3 - __uint_as_float(h1 << 16)) << 16);
  h0 = bf16rne(v4); h1 = bf16rne(v5);
  hi[2] = h0 | (h1 << 16);
  lo[2] = bf16rne(v4 - __uint_as_float(h0 << 16)) |
          (bf16rne(v5 - __uint_as_float(h1 << 16)) << 16);
  h0 = bf16rne(v6); h1 = bf16rne(v7);
  hi[3] = h0 | (h1 << 16);
  lo[3] = bf16rne(v6 - __uint_as_float(h0 << 16)) |
          (bf16rne(v7 - __uint_as_float(h1 << 16)) << 16);
  hi8 = __builtin_bit_cast(bf16x8, u32x4{hi[0], hi[1], hi[2], hi[3]});
  lo8 = __builtin_bit_cast(bf16x8, u32x4{lo[0], lo[1], lo[2], lo[3]});
}

// ---------------------------------------------------------------------------
// pack W (fp32 128x128) -> MFMA B-fragment layout, split hi/lo bf16.
// (unchanged, verified round 5)
// ---------------------------------------------------------------------------
__global__ __launch_bounds__(256) void pack_w_kernel(
    const float* __restrict__ Wk, const float* __restrict__ Wv,
    u32x4* __restrict__ wfrag)
{
  const int gid = blockIdx.x * 256 + threadIdx.x;  // [0, 4096)
  const int mat = gid >> 11;
  const int ct = (gid >> 9) & 3;
  const int ks = (gid >> 6) & 7;
  const int lane = gid & 63;
  const float* __restrict__ W = mat ? Wv : Wk;
  const int col = ct * 32 + (lane & 31);
  const int k0 = ks * 16 + (lane >> 5) * 8;
  unsigned hi[4], lo[4];
#pragma unroll
  for (int j = 0; j < 4; ++j) {
    const float x0 = W[(k0 + 2 * j) * DDIM + col];
    const float x1 = W[(k0 + 2 * j + 1) * DDIM + col];
    const unsigned h0 = bf16rne(x0), h1 = bf16rne(x1);
    hi[j] = h0 | (h1 << 16);
    lo[j] = bf16rne(x0 - __uint_as_float(h0 << 16)) |
            (bf16rne(x1 - __uint_as_float(h1 << 16)) << 16);
  }
  const int base = (((mat * 4 + ct) * 8 + ks) * 2) * 64 + lane;
  wfrag[base]      = u32x4{hi[0], hi[1], hi[2], hi[3]};
  wfrag[base + 64] = u32x4{lo[0], lo[1], lo[2], lo[3]};
}

// ---------------------------------------------------------------------------
// K+V projection via MFMA 32x32x16 bf16, split-precision. (unchanged, r5)
// ---------------------------------------------------------------------------
__global__ __launch_bounds__(256) void proj_kv_mfma_kernel(
    const float* __restrict__ x, const u32x4* __restrict__ wfrag,
    float* __restrict__ outk, float* __restrict__ outv)
{
  const int tid = threadIdx.x;
  const int lane = tid & 63;
  const int wid = tid >> 6;
  const int rtp = wid >> 1;   // wave row-pair (0..1)
  const int ctp = wid & 1;    // wave col-pair (0..1)
  const int arow = blockIdx.x * 128 + rtp * 64 + (lane & 31);
  const int kgrp = (lane >> 5) * 8;

#pragma unroll 1
  for (int mat = 0; mat < 2; ++mat) {
    float* __restrict__ out = mat ? outv : outk;
    f32x16 acc[2][2];
#pragma unroll
    for (int a = 0; a < 2; ++a)
#pragma unroll
      for (int b = 0; b < 2; ++b)
#pragma unroll
        for (int i = 0; i < 16; ++i) acc[a][b][i] = 0.f;

#pragma unroll 1
    for (int ks = 0; ks < 8; ++ks) {
      bf16x8 ahi[2], alo[2];
#pragma unroll
      for (int rt = 0; rt < 2; ++rt) {
        const float* xp = x + (size_t)(arow + rt * 32) * DDIM + ks * 16 + kgrp;
        split8(xp, ahi[rt], alo[rt]);
      }
#pragma unroll
      for (int ct = 0; ct < 2; ++ct) {
        const int c = ctp * 2 + ct;
        const int fo = (((mat * 4 + c) * 8 + ks) * 2) * 64 + lane;
        const bf16x8 bhi = __builtin_bit_cast(bf16x8, wfrag[fo]);
        const bf16x8 blo = __builtin_bit_cast(bf16x8, wfrag[fo + 64]);
#pragma unroll
        for (int rt = 0; rt < 2; ++rt) {
          acc[rt][ct] = __builtin_amdgcn_mfma_f32_32x32x16_bf16(
              ahi[rt], bhi, acc[rt][ct], 0, 0, 0);
          acc[rt][ct] = __builtin_amdgcn_mfma_f32_32x32x16_bf16(
              ahi[rt], blo, acc[rt][ct], 0, 0, 0);
          acc[rt][ct] = __builtin_amdgcn_mfma_f32_32x32x16_bf16(
              alo[rt], bhi, acc[rt][ct], 0, 0, 0);
        }
      }
    }
#pragma unroll
    for (int rt = 0; rt < 2; ++rt)
#pragma unroll
      for (int ct = 0; ct < 2; ++ct) {
        const int colg = ctp * 64 + ct * 32 + (lane & 31);
        const int rowg0 = blockIdx.x * 128 + rtp * 64 + rt * 32 + 4 * (lane >> 5);
#pragma unroll
        for (int r = 0; r < 16; ++r) {
          const int rowg = rowg0 + (r & 3) + 8 * (r >> 2);
          out[(size_t)rowg * DDIM + colg] = acc[rt][ct][r];
        }
      }
  }
}

// ---------------------------------------------------------------------------
// Fused Q projection: out = (x1@W1 + x2@W2) * scale. (unchanged)
// ---------------------------------------------------------------------------
__global__ __launch_bounds__(256) void proj_q2_kernel(
    const float* __restrict__ x1, const float* __restrict__ x2,
    const float* __restrict__ W1, const float* __restrict__ W2,
    float* __restrict__ out, float scale)
{
  const int tid = threadIdx.x;
  const int j = tid & 127;
  const int rhalf = __builtin_amdgcn_readfirstlane(tid >> 7);
  const size_t r0 = (size_t)blockIdx.x * 32 + rhalf * 16;
  const float* xb1 = x1 + r0 * DDIM;
  const float* xb2 = x2 + r0 * DDIM;

  float acc[16];
#pragma unroll
  for (int r = 0; r < 16; ++r) acc[r] = 0.f;

#pragma unroll 2
  for (int dc = 0; dc < DDIM; dc += 4) {
    const float a0 = W1[(dc + 0) * DDIM + j];
    const float a1 = W1[(dc + 1) * DDIM + j];
    const float a2 = W1[(dc + 2) * DDIM + j];
    const float a3 = W1[(dc + 3) * DDIM + j];
#pragma unroll
    for (int r = 0; r < 16; ++r) {
      const float4 xv = *(const float4*)(xb1 + r * DDIM + dc);
      acc[r] = fmaf(xv.w, a3, fmaf(xv.z, a2, fmaf(xv.y, a1, fmaf(xv.x, a0, acc[r]))));
    }
    const float b0 = W2[(dc + 0) * DDIM + j];
    const float b1 = W2[(dc + 1) * DDIM + j];
    const float b2 = W2[(dc + 2) * DDIM + j];
    const float b3 = W2[(dc + 3) * DDIM + j];
#pragma unroll
    for (int r = 0; r < 16; ++r) {
      const float4 xv = *(const float4*)(xb2 + r * DDIM + dc);
      acc[r] = fmaf(xv.w, b3, fmaf(xv.z, b2, fmaf(xv.y, b1, fmaf(xv.x, b0, acc[r]))));
    }
  }
  float* o = out + r0 * DDIM + j;
#pragma unroll
  for (int r = 0; r < 16; ++r) o[r * DDIM] = acc[r] * scale;
}

// ---------------------------------------------------------------------------
// Combine projection with bias: out = x@W + bias. (unchanged)
// ---------------------------------------------------------------------------
__global__ __launch_bounds__(256) void proj_bias_kernel(
    const float* __restrict__ x, const float* __restrict__ W,
    const float* __restrict__ bias, float* __restrict__ out)
{
  const int tid = threadIdx.x;
  const int j = tid & 127;
  const int rhalf = __builtin_amdgcn_readfirstlane(tid >> 7);
  const size_t r0 = (size_t)blockIdx.x * 32 + rhalf * 16;
  const float* xb = x + r0 * DDIM;
  const float bj = bias[j];

  float acc[16];
#pragma unroll
  for (int r = 0; r < 16; ++r) acc[r] = bj;

#pragma unroll 2
  for (int dc = 0; dc < DDIM; dc += 4) {
    const float w0 = W[(dc + 0) * DDIM + j];
    const float w1 = W[(dc + 1) * DDIM + j];
    const float w2 = W[(dc + 2) * DDIM + j];
    const float w3 = W[(dc + 3) * DDIM + j];
#pragma unroll
    for (int r = 0; r < 16; ++r) {
      const float4 xv = *(const float4*)(xb + r * DDIM + dc);
      acc[r] = fmaf(xv.w, w3, fmaf(xv.z, w2, fmaf(xv.y, w1, fmaf(xv.x, w0, acc[r]))));
    }
  }
  float* o = out + r0 * DDIM + j;
#pragma unroll
  for (int r = 0; r < 16; ++r) o[r * DDIM] = acc[r];
}

// ---------------------------------------------------------------------------
// attention, split over N, K/V staged in LDS. (unchanged)
// ---------------------------------------------------------------------------
__global__ __launch_bounds__(448) void attn_kernel(
    const float* __restrict__ Q, const float* __restrict__ K,
    const float* __restrict__ V, const float* __restrict__ mask,
    float* __restrict__ po, float* __restrict__ lsum)
{
  __shared__ float Ks[TN * DDIM];
  __shared__ float Vs[TN * DDIM];

  const int b = blockIdx.x >> 3;
  const int split = blockIdx.x & 7;
  const int t = threadIdx.x;
  const int pg = t >> 3;
  const int h = t & 7;
  const bool act = pg < 50;
  const int p0 = (act ? pg : 49) * 2;

  float q0[16], q1[16];
  const float* qp0 = Q + (b * PP + p0) * DDIM + h * 16;   // Q pre-scaled by 0.25
#pragma unroll
  for (int c = 0; c < 4; ++c) {
    const float4 a = *(const float4*)(qp0 + 4 * c);
    const float4 bq = *(const float4*)(qp0 + DDIM + 4 * c);
    q0[4*c+0]=a.x;  q0[4*c+1]=a.y;  q0[4*c+2]=a.z;  q0[4*c+3]=a.w;
    q1[4*c+0]=bq.x; q1[4*c+1]=bq.y; q1[4*c+2]=bq.z; q1[4*c+3]=bq.w;
  }
  float a0[16], a1[16];
#pragma unroll
  for (int i = 0; i < 16; ++i) { a0[i] = 0.f; a1[i] = 0.f; }
  float l0 = 0.f, l1 = 0.f;

  const float* m0 = mask + (b * PP + p0) * NN;
  const float* m1 = m0 + NN;

  const int n0 = split * (NN / NSPL);           // 125 n per split
  for (int c0 = 0; c0 < NN / NSPL; c0 += TN) {  // 5 chunks of 25
    __syncthreads();                            // prev chunk fully consumed
    for (int idx = t; idx < TN * 32; idx += 448) {
      const int row = idx >> 5;
      const int col = (idx & 31) * 4;
      const int g = (b * NN + n0 + c0 + row) * DDIM + col;
      *(float4*)&Ks[row * DDIM + col] = *(const float4*)(K + g);
      *(float4*)&Vs[row * DDIM + col] = *(const float4*)(V + g);
    }
    __syncthreads();
#pragma unroll 5
    for (int nn2 = 0; nn2 < TN; ++nn2) {
      const int n = n0 + c0 + nn2;
      const float* kn = &Ks[nn2 * DDIM + h * 16];
      float kr[16];
#pragma unroll
      for (int c = 0; c < 4; ++c) {
        const float4 kv = *(const float4*)(kn + 4 * c);
        kr[4*c+0]=kv.x; kr[4*c+1]=kv.y; kr[4*c+2]=kv.z; kr[4*c+3]=kv.w;
      }
      float s0a=0.f, s0b=0.f, s1a=0.f, s1b=0.f;
#pragma unroll
      for (int i = 0; i < 8; ++i) {
        s0a = fmaf(q0[i],   kr[i],   s0a);
        s0b = fmaf(q0[i+8], kr[i+8], s0b);
        s1a = fmaf(q1[i],   kr[i],   s1a);
        s1b = fmaf(q1[i+8], kr[i+8], s1b);
      }
      const float e0 = __expf((s0a + s0b) + m0[n]);
      const float e1 = __expf((s1a + s1b) + m1[n]);
      l0 += e0; l1 += e1;
      const float* vn = &Vs[nn2 * DDIM + h * 16];
#pragma unroll
      for (int c = 0; c < 4; ++c) {
        const float4 vv = *(const float4*)(vn + 4 * c);
        a0[4*c+0] = fmaf(e0, vv.x, a0[4*c+0]);
        a0[4*c+1] = fmaf(e0, vv.y, a0[4*c+1]);
        a0[4*c+2] = fmaf(e0, vv.z, a0[4*c+2]);
        a0[4*c+3] = fmaf(e0, vv.w, a0[4*c+3]);
        a1[4*c+0] = fmaf(e1, vv.x, a1[4*c+0]);
        a1[4*c+1] = fmaf(e1, vv.y, a1[4*c+1]);
        a1[4*c+2] = fmaf(e1, vv.z, a1[4*c+2]);
        a1[4*c+3] = fmaf(e1, vv.w, a1[4*c+3]);
      }
    }
  }
  if (act) {
    const int base = (b * NSPL + split) * PP + p0;
    float* d0 = po + base * DDIM + h * 16;
#pragma unroll
    for (int c = 0; c < 4; ++c) {
      *(float4*)(d0 + 4*c)        = make_float4(a0[4*c+0],a0[4*c+1],a0[4*c+2],a0[4*c+3]);
      *(float4*)(d0 + DDIM + 4*c) = make_float4(a1[4*c+0],a1[4*c+1],a1[4*c+2],a1[4*c+3]);
    }
    lsum[base * HH + h]       = l0;
    lsum[(base + 1) * HH + h] = l1;
  }
}

// ---------------------------------------------------------------------------
// merge: mh_in[b][p][d] = (sum_s po) / (sum_s lsum[h(d)])  (unchanged)
// ---------------------------------------------------------------------------
__global__ __launch_bounds__(256) void merge_kernel(
    const float* __restrict__ po, const float* __restrict__ lsum,
    float* __restrict__ mh_in)
{
  const int idx = blockIdx.x * 256 + threadIdx.x;   // over BB*PP*DDIM
  const int d = idx & 127;
  const int row = idx >> 7;        // b*PP + p
  const int b = row / PP;
  const int p = row - b * PP;
  const int h = d >> 4;
  float s = 0.f, lt = 0.f;
#pragma unroll
  for (int sp = 0; sp < NSPL; ++sp) {
    const int base = (b * NSPL + sp) * PP + p;
    s  += po[base * DDIM + d];
    lt += lsum[base * HH + h];
  }
  mh_in[idx] = s / lt;
}

// ---------------------------------------------------------------------------
// score2 via MFMA 32x32x16 split-bf16 (round-5 score2 was a latency-bound
// VALU GEMM: VGPR=76 -> er[] rematerialized from L1, grid-capped 20% occ).
// C[b][p][n] = mh[b,p,:] . enc[b,n,:]. Block = (b, 64-wide n-chunk), 4 waves
// = 4 m-tiles (rows 0..127, p<100 valid). Fragment mapping identical to the
// numerically-verified proj_kv_mfma. Fused epilogue: tanh, priority bias,
// mask, exp, 32-lane shfl row-reduce -> per-chunk partial sums (determin.).
// grid = BB*16.
// ---------------------------------------------------------------------------
__global__ __launch_bounds__(256) void score2_mfma_kernel(
    const float* __restrict__ enc, const float* __restrict__ mh,
    const float* __restrict__ mask, const float* __restrict__ bias_table,
    const int* __restrict__ group_ids, const int* __restrict__ cur_min,
    float* __restrict__ out, float* __restrict__ ssum)
{
  const int b   = blockIdx.x >> 4;
  const int nc  = blockIdx.x & 15;
  const int n0  = nc * 64;
  const int tid = threadIdx.x;
  const int lane = tid & 63;
  const int mt   = tid >> 6;        // wave = m-tile (rows 32mt..32mt+31)
  const int half = lane >> 5;
  const int l31  = lane & 31;

  f32x16 acc[2];
#pragma unroll
  for (int c = 0; c < 2; ++c)
#pragma unroll
    for (int i = 0; i < 16; ++i) acc[c][i] = 0.f;

  // A: mh row (b*100 + 32mt + l31); rows >=100 read garbage in ws (masked on
  // write; max row 6427 stays inside ws). B: enc rows clamped to n<1000.
  const float* mha = mh + ((size_t)(b * PP + 32 * mt + l31)) * DDIM + half * 8;
  const float* encb = enc + (size_t)b * NN * DDIM + half * 8;
  const int nsrc0 = min(n0 + l31, NN - 1);
  const int nsrc1 = min(n0 + 32 + l31, NN - 1);

#pragma unroll 1
  for (int ks = 0; ks < 8; ++ks) {
    bf16x8 ahi, alo;
    split8(mha + ks * 16, ahi, alo);
    bf16x8 bhi0, blo0, bhi1, blo1;
    split8(encb + (size_t)nsrc0 * DDIM + ks * 16, bhi0, blo0);
    split8(encb + (size_t)nsrc1 * DDIM + ks * 16, bhi1, blo1);
    acc[0] = __builtin_amdgcn_mfma_f32_32x32x16_bf16(ahi, bhi0, acc[0], 0, 0, 0);
    acc[0] = __builtin_amdgcn_mfma_f32_32x32x16_bf16(ahi, blo0, acc[0], 0, 0, 0);
    acc[0] = __builtin_amdgcn_mfma_f32_32x32x16_bf16(alo, bhi0, acc[0], 0, 0, 0);
    acc[1] = __builtin_amdgcn_mfma_f32_32x32x16_bf16(ahi, bhi1, acc[1], 0, 0, 0);
    acc[1] = __builtin_amdgcn_mfma_f32_32x32x16_bf16(ahi, blo1, acc[1], 0, 0, 0);
    acc[1] = __builtin_amdgcn_mfma_f32_32x32x16_bf16(alo, bhi1, acc[1], 0, 0, 0);
  }

  // epilogue. C layout: col = l31 (n within col-tile), row = (r&3)+8*(r>>2)+4*half
  const float t0 = bias_table[0], t1 = bias_table[1], t2 = bias_table[2],
              t3 = bias_table[3], t4 = bias_table[4];
  const float two_inv_sqrt_emb = 0.1767766952966369f;  // 2/sqrt(128)

  float rsum[16];
#pragma unroll
  for (int r = 0; r < 16; ++r) rsum[r] = 0.f;

#pragma unroll
  for (int ct = 0; ct < 2; ++ct) {
    const int n = n0 + ct * 32 + l31;
    const bool nvalid = n < NN;
    const int nr = nvalid ? n : NN - 1;
    const int gid = group_ids[b * NN + nr];
#pragma unroll
    for (int r = 0; r < 16; ++r) {
      const int p = 32 * mt + (r & 3) + 8 * (r >> 2) + 4 * half;
      const bool pvalid = p < PP;
      const int pr = pvalid ? p : PP - 1;
      const float m = mask[((size_t)(b * PP + pr)) * NN + nr];
      const float ex = __expf(acc[ct][r] * two_inv_sqrt_emb);
      const float sc = 10.0f - 20.0f / (ex + 1.0f);
      const int cmp = cur_min[b * PP + pr];
      int delta = gid - cmp;
      delta = delta < 0 ? 0 : (delta > 4 ? 4 : delta);
      const float pb = (delta == 0) ? t0 : (delta == 1) ? t1 : (delta == 2) ? t2
                     : (delta == 3) ? t3 : t4;
      float e = (nvalid && pvalid) ? __expf(sc + pb + m) : 0.0f;
      if (nvalid && pvalid) out[((size_t)(b * PP + p)) * NN + n] = e;
      // reduce across the 32 lanes holding this row
      float ws = e;
#pragma unroll
      for (int off = 1; off < 32; off <<= 1) ws += __shfl_xor(ws, off, 64);
      rsum[r] += ws;
    }
  }
  if (l31 == 0) {
#pragma unroll
    for (int r = 0; r < 16; ++r) {
      const int p = 32 * mt + (r & 3) + 8 * (r >> 2) + 4 * half;
      if (p < PP) ssum[(size_t)(b * PP + p) * 16 + nc] = rsum[r];
    }
  }
}

// ---------------------------------------------------------------------------
// normalize: out[row][n] /= sum of 16 chunk partials
// ---------------------------------------------------------------------------
__global__ __launch_bounds__(256) void norm_kernel(
    const float* __restrict__ ssum, float* __restrict__ out)
{
  const int row = blockIdx.x;   // b*PP + p
  float s = 0.f;
#pragma unroll
  for (int i = 0; i < 16; ++i) s += ssum[(size_t)row * 16 + i];
  const float inv = 1.0f / s;
#pragma unroll
  for (int i = 0; i < 4; ++i) {
    const int c = i * 256 + (int)threadIdx.x;
    if (c < NN) out[(size_t)row * NN + c] *= inv;
  }
}

// ---------------------------------------------------------------------------
extern "C" void kernel_launch(void* const* d_in, const int* in_sizes, int n_in,
                              void* d_out, int out_size, void* d_ws, size_t ws_size,
                              hipStream_t stream)
{
  (void)in_sizes; (void)n_in; (void)out_size; (void)ws_size;
  const float* enc_nodes  = (const float*)d_in[0];
  const float* enc_q1     = (const float*)d_in[1];
  const float* enc_last   = (const float*)d_in[2];
  const float* ninf       = (const float*)d_in[3];
  const float* Wq_first   = (const float*)d_in[4];
  const float* Wq_last    = (const float*)d_in[5];
  const float* Wk         = (const float*)d_in[6];
  const float* Wv         = (const float*)d_in[7];
  const float* W_comb     = (const float*)d_in[8];
  const float* b_comb     = (const float*)d_in[9];
  const float* bias_table = (const float*)d_in[10];
  const int*   group_ids  = (const int*)d_in[11];
  const int*   cur_min    = (const int*)d_in[12];
  float* out = (float*)d_out;
  float* ws  = (float*)d_ws;

  float* Qw = ws;                    //   819200 floats (reused as mh_in after attn)
  float* Kw = Qw + 819200;           //  8192000
  float* Vw = Kw + 8192000;          //  8192000
  float* po = Vw + 8192000;          //  6553600  (BB*NSPL*PP*DDIM)
  float* ls = po + 6553600;          //   409600  (BB*NSPL*PP*HH)
  float* mh = ls + 409600;           //   819200
  float* sm = mh + 819200;           //   102400  (BB*PP*16)

  // wfrag (128 KB) aliases the head of po: pack_w + proj_kv complete before
  // attn writes po (stream-ordered), so no conflict.
  u32x4* wfrag = (u32x4*)po;

  // pack W_k/W_v into split-bf16 MFMA fragments
  pack_w_kernel<<<16, 256, 0, stream>>>(Wk, Wv, wfrag);
  // Q = (q1@Wq_first + last@Wq_last) * 0.25  (fold 1/sqrt(QD))
  proj_q2_kernel<<<BB*PP/32, 256, 0, stream>>>(enc_q1, enc_last, Wq_first, Wq_last,
                                               Qw, 0.25f);
  // K, V projections via split-bf16 MFMA
  proj_kv_mfma_kernel<<<BB*NN/128, 256, 0, stream>>>(enc_nodes, wfrag, Kw, Vw);
  // attention partials (LDS-staged K/V)
  attn_kernel<<<BB*NSPL, 448, 0, stream>>>(Qw, Kw, Vw, ninf, po, ls);
  // merge partials -> mh_in (reuses Qw)
  merge_kernel<<<3200, 256, 0, stream>>>(po, ls, Qw);
  // combine: mh = mh_in @ W_comb + b_comb
  proj_bias_kernel<<<BB*PP/32, 256, 0, stream>>>(Qw, W_comb, b_comb, mh);
  // final scores via MFMA + fused epilogue
  score2_mfma_kernel<<<BB*16, 256, 0, stream>>>(enc_nodes, mh, ninf, bias_table,
                                                group_ids, cur_min, out, sm);
  // normalize
  norm_kernel<<<BB*PP, 256, 0, stream>>>(sm, out);
}

// Round 7
// 288.601 us; speedup vs baseline: 1.5945x; 1.0039x over previous
//
#include <hip/hip_runtime.h>

#define BB 64
#define PP 100
#define NN 1000
#define DDIM 128
#define HH 8
#define NSPL 8
#define TN 25   // K/V rows staged in LDS per chunk in attn

typedef __attribute__((ext_vector_type(8))) short bf16x8;   // 8 bf16 = 4 VGPRs
typedef __attribute__((ext_vector_type(16))) float f32x16;  // MFMA 32x32 acc
typedef __attribute__((ext_vector_type(4))) unsigned u32x4;

__device__ __forceinline__ unsigned bf16rne(float x) {
  unsigned u = __float_as_uint(x);
  return (u + 0x7FFFu + ((u >> 16) & 1u)) >> 16;
}

// split 8 contiguous floats into hi/lo bf16x8 fragments
__device__ __forceinline__ void split8(const float* __restrict__ p,
                                       bf16x8& hi8, bf16x8& lo8) {
  const float4 a = *(const float4*)p;
  const float4 c = *(const float4*)(p + 4);
  const float v0 = a.x, v1 = a.y, v2 = a.z, v3 = a.w;
  const float v4 = c.x, v5 = c.y, v6 = c.z, v7 = c.w;
  unsigned hi[4], lo[4];
  unsigned h0, h1;
  h0 = bf16rne(v0); h1 = bf16rne(v1);
  hi[0] = h0 | (h1 << 16);
  lo[0] = bf16rne(v0 - __uint_as_float(h0 << 16)) |
          (bf16rne(v1 - __uint_as_float(h1 << 16)) << 16);
  h0 = bf16rne(v2); h1 = bf16rne(v3);
  hi[1] = h0 | (h1 << 16);
  lo[1] = bf16rne(v2 - __uint_as_float(h0 << 16)) |
          (bf16rne(v3 - __uint_as_float(h1 << 16)) << 16);
  h0 = bf16rne(v4); h1 = bf16rne(v5);
  hi[2] = h0 | (h1 << 16);
  lo[2] = bf16rne(v4 - __uint_as_float(h0 << 16)) |
          (bf16rne(v5 - __uint_as_float(h1 << 16)) << 16);
  h0 = bf16rne(v6); h1 = bf16rne(v7);
  hi[3] = h0 | (h1 << 16);
  lo[3] = bf16rne(v6 - __uint_as_float(h0 << 16)) |
          (bf16rne(v7 - __uint_as_float(h1 << 16)) << 16);
  hi8 = __builtin_bit_cast(bf16x8, u32x4{hi[0], hi[1], hi[2], hi[3]});
  lo8 = __builtin_bit_cast(bf16x8, u32x4{lo[0], lo[1], lo[2], lo[3]});
}

// ---------------------------------------------------------------------------
// pack W (fp32 128x128) -> MFMA B-fragment layout, split hi/lo bf16.
// (unchanged, verified round 5)
// ---------------------------------------------------------------------------
__global__ __launch_bounds__(256) void pack_w_kernel(
    const float* __restrict__ Wk, const float* __restrict__ Wv,
    u32x4* __restrict__ wfrag)
{
  const int gid = blockIdx.x * 256 + threadIdx.x;  // [0, 4096)
  const int mat = gid >> 11;
  const int ct = (gid >> 9) & 3;
  const int ks = (gid >> 6) & 7;
  const int lane = gid & 63;
  const float* __restrict__ W = mat ? Wv : Wk;
  const int col = ct * 32 + (lane & 31);
  const int k0 = ks * 16 + (lane >> 5) * 8;
  unsigned hi[4], lo[4];
#pragma unroll
  for (int j = 0; j < 4; ++j) {
    const float x0 = W[(k0 + 2 * j) * DDIM + col];
    const float x1 = W[(k0 + 2 * j + 1) * DDIM + col];
    const unsigned h0 = bf16rne(x0), h1 = bf16rne(x1);
    hi[j] = h0 | (h1 << 16);
    lo[j] = bf16rne(x0 - __uint_as_float(h0 << 16)) |
            (bf16rne(x1 - __uint_as_float(h1 << 16)) << 16);
  }
  const int base = (((mat * 4 + ct) * 8 + ks) * 2) * 64 + lane;
  wfrag[base]      = u32x4{hi[0], hi[1], hi[2], hi[3]};
  wfrag[base + 64] = u32x4{lo[0], lo[1], lo[2], lo[3]};
}

// ---------------------------------------------------------------------------
// K+V projection via MFMA 32x32x16 bf16, split-precision. (unchanged, r5)
// ---------------------------------------------------------------------------
__global__ __launch_bounds__(256) void proj_kv_mfma_kernel(
    const float* __restrict__ x, const u32x4* __restrict__ wfrag,
    float* __restrict__ outk, float* __restrict__ outv)
{
  const int tid = threadIdx.x;
  const int lane = tid & 63;
  const int wid = tid >> 6;
  const int rtp = wid >> 1;   // wave row-pair (0..1)
  const int ctp = wid & 1;    // wave col-pair (0..1)
  const int arow = blockIdx.x * 128 + rtp * 64 + (lane & 31);
  const int kgrp = (lane >> 5) * 8;

#pragma unroll 1
  for (int mat = 0; mat < 2; ++mat) {
    float* __restrict__ out = mat ? outv : outk;
    f32x16 acc[2][2];
#pragma unroll
    for (int a = 0; a < 2; ++a)
#pragma unroll
      for (int b = 0; b < 2; ++b)
#pragma unroll
        for (int i = 0; i < 16; ++i) acc[a][b][i] = 0.f;

#pragma unroll 1
    for (int ks = 0; ks < 8; ++ks) {
      bf16x8 ahi[2], alo[2];
#pragma unroll
      for (int rt = 0; rt < 2; ++rt) {
        const float* xp = x + (size_t)(arow + rt * 32) * DDIM + ks * 16 + kgrp;
        split8(xp, ahi[rt], alo[rt]);
      }
#pragma unroll
      for (int ct = 0; ct < 2; ++ct) {
        const int c = ctp * 2 + ct;
        const int fo = (((mat * 4 + c) * 8 + ks) * 2) * 64 + lane;
        const bf16x8 bhi = __builtin_bit_cast(bf16x8, wfrag[fo]);
        const bf16x8 blo = __builtin_bit_cast(bf16x8, wfrag[fo + 64]);
#pragma unroll
        for (int rt = 0; rt < 2; ++rt) {
          acc[rt][ct] = __builtin_amdgcn_mfma_f32_32x32x16_bf16(
              ahi[rt], bhi, acc[rt][ct], 0, 0, 0);
          acc[rt][ct] = __builtin_amdgcn_mfma_f32_32x32x16_bf16(
              ahi[rt], blo, acc[rt][ct], 0, 0, 0);
          acc[rt][ct] = __builtin_amdgcn_mfma_f32_32x32x16_bf16(
              alo[rt], bhi, acc[rt][ct], 0, 0, 0);
        }
      }
    }
#pragma unroll
    for (int rt = 0; rt < 2; ++rt)
#pragma unroll
      for (int ct = 0; ct < 2; ++ct) {
        const int colg = ctp * 64 + ct * 32 + (lane & 31);
        const int rowg0 = blockIdx.x * 128 + rtp * 64 + rt * 32 + 4 * (lane >> 5);
#pragma unroll
        for (int r = 0; r < 16; ++r) {
          const int rowg = rowg0 + (r & 3) + 8 * (r >> 2);
          out[(size_t)rowg * DDIM + colg] = acc[rt][ct][r];
        }
      }
  }
}

// ---------------------------------------------------------------------------
// Fused Q projection: out = (x1@W1 + x2@W2) * scale. (unchanged)
// ---------------------------------------------------------------------------
__global__ __launch_bounds__(256) void proj_q2_kernel(
    const float* __restrict__ x1, const float* __restrict__ x2,
    const float* __restrict__ W1, const float* __restrict__ W2,
    float* __restrict__ out, float scale)
{
  const int tid = threadIdx.x;
  const int j = tid & 127;
  const int rhalf = __builtin_amdgcn_readfirstlane(tid >> 7);
  const size_t r0 = (size_t)blockIdx.x * 32 + rhalf * 16;
  const float* xb1 = x1 + r0 * DDIM;
  const float* xb2 = x2 + r0 * DDIM;

  float acc[16];
#pragma unroll
  for (int r = 0; r < 16; ++r) acc[r] = 0.f;

#pragma unroll 2
  for (int dc = 0; dc < DDIM; dc += 4) {
    const float a0 = W1[(dc + 0) * DDIM + j];
    const float a1 = W1[(dc + 1) * DDIM + j];
    const float a2 = W1[(dc + 2) * DDIM + j];
    const float a3 = W1[(dc + 3) * DDIM + j];
#pragma unroll
    for (int r = 0; r < 16; ++r) {
      const float4 xv = *(const float4*)(xb1 + r * DDIM + dc);
      acc[r] = fmaf(xv.w, a3, fmaf(xv.z, a2, fmaf(xv.y, a1, fmaf(xv.x, a0, acc[r]))));
    }
    const float b0 = W2[(dc + 0) * DDIM + j];
    const float b1 = W2[(dc + 1) * DDIM + j];
    const float b2 = W2[(dc + 2) * DDIM + j];
    const float b3 = W2[(dc + 3) * DDIM + j];
#pragma unroll
    for (int r = 0; r < 16; ++r) {
      const float4 xv = *(const float4*)(xb2 + r * DDIM + dc);
      acc[r] = fmaf(xv.w, b3, fmaf(xv.z, b2, fmaf(xv.y, b1, fmaf(xv.x, b0, acc[r]))));
    }
  }
  float* o = out + r0 * DDIM + j;
#pragma unroll
  for (int r = 0; r < 16; ++r) o[r * DDIM] = acc[r] * scale;
}

// ---------------------------------------------------------------------------
// Combine projection with bias: out = x@W + bias. (unchanged)
// ---------------------------------------------------------------------------
__global__ __launch_bounds__(256) void proj_bias_kernel(
    const float* __restrict__ x, const float* __restrict__ W,
    const float* __restrict__ bias, float* __restrict__ out)
{
  const int tid = threadIdx.x;
  const int j = tid & 127;
  const int rhalf = __builtin_amdgcn_readfirstlane(tid >> 7);
  const size_t r0 = (size_t)blockIdx.x * 32 + rhalf * 16;
  const float* xb = x + r0 * DDIM;
  const float bj = bias[j];

  float acc[16];
#pragma unroll
  for (int r = 0; r < 16; ++r) acc[r] = bj;

#pragma unroll 2
  for (int dc = 0; dc < DDIM; dc += 4) {
    const float w0 = W[(dc + 0) * DDIM + j];
    const float w1 = W[(dc + 1) * DDIM + j];
    const float w2 = W[(dc + 2) * DDIM + j];
    const float w3 = W[(dc + 3) * DDIM + j];
#pragma unroll
    for (int r = 0; r < 16; ++r) {
      const float4 xv = *(const float4*)(xb + r * DDIM + dc);
      acc[r] = fmaf(xv.w, w3, fmaf(xv.z, w2, fmaf(xv.y, w1, fmaf(xv.x, w0, acc[r]))));
    }
  }
  float* o = out + r0 * DDIM + j;
#pragma unroll
  for (int r = 0; r < 16; ++r) o[r * DDIM] = acc[r];
}

// ---------------------------------------------------------------------------
// attention, split over N, K/V staged in LDS with a CHUNK-SWIZZLED layout.
// Round-6 layout: lane reads chunk (h,c) at dword h*16+c*4 -> 8 h-chunks at
// stride 64B land on 2 bank-quads = 4-way conflict (SQ_LDS_BANK_CONFLICT
// 1.4e7, LDS pipe 4x oversubscribed vs VALU). Swizzle: chunk (h,c) stored at
// chunk index c*8+h -> for fixed c the 8 h-groups hit 8 distinct bank-quads,
// conflict-free; 8-lane same-address broadcast remains free.
// thread = (p-pair, head). grid = BB*NSPL, block = 448 (pg<50 active).
// ---------------------------------------------------------------------------
__global__ __launch_bounds__(448) void attn_kernel(
    const float* __restrict__ Q, const float* __restrict__ K,
    const float* __restrict__ V, const float* __restrict__ mask,
    float* __restrict__ po, float* __restrict__ lsum)
{
  __shared__ float Ks[TN * DDIM];
  __shared__ float Vs[TN * DDIM];

  const int b = blockIdx.x >> 3;
  const int split = blockIdx.x & 7;
  const int t = threadIdx.x;
  const int pg = t >> 3;
  const int h = t & 7;
  const bool act = pg < 50;
  const int p0 = (act ? pg : 49) * 2;

  float q0[16], q1[16];
  const float* qp0 = Q + (b * PP + p0) * DDIM + h * 16;   // Q pre-scaled by 0.25
#pragma unroll
  for (int c = 0; c < 4; ++c) {
    const float4 a = *(const float4*)(qp0 + 4 * c);
    const float4 bq = *(const float4*)(qp0 + DDIM + 4 * c);
    q0[4*c+0]=a.x;  q0[4*c+1]=a.y;  q0[4*c+2]=a.z;  q0[4*c+3]=a.w;
    q1[4*c+0]=bq.x; q1[4*c+1]=bq.y; q1[4*c+2]=bq.z; q1[4*c+3]=bq.w;
  }
  float a0[16], a1[16];
#pragma unroll
  for (int i = 0; i < 16; ++i) { a0[i] = 0.f; a1[i] = 0.f; }
  float l0 = 0.f, l1 = 0.f;

  const float* m0 = mask + (b * PP + p0) * NN;
  const float* m1 = m0 + NN;

  const int n0 = split * (NN / NSPL);           // 125 n per split
  for (int c0 = 0; c0 < NN / NSPL; c0 += TN) {  // 5 chunks of 25
    __syncthreads();                            // prev chunk fully consumed
    for (int idx = t; idx < TN * 32; idx += 448) {
      const int row = idx >> 5;
      const int chunk = idx & 31;                       // 16B chunk within row
      const int sc = ((chunk & 3) << 3) + (chunk >> 2); // swizzled chunk pos
      const int g = (b * NN + n0 + c0 + row) * DDIM + chunk * 4;
      *(float4*)&Ks[row * DDIM + sc * 4] = *(const float4*)(K + g);
      *(float4*)&Vs[row * DDIM + sc * 4] = *(const float4*)(V + g);
    }
    __syncthreads();
#pragma unroll 5
    for (int nn2 = 0; nn2 < TN; ++nn2) {
      const int n = n0 + c0 + nn2;
      // swizzled read: chunk (h,c) lives at dword offset c*32 + h*4
      const float* kn = &Ks[nn2 * DDIM + h * 4];
      float kr[16];
#pragma unroll
      for (int c = 0; c < 4; ++c) {
        const float4 kv = *(const float4*)(kn + 32 * c);
        kr[4*c+0]=kv.x; kr[4*c+1]=kv.y; kr[4*c+2]=kv.z; kr[4*c+3]=kv.w;
      }
      float s0a=0.f, s0b=0.f, s1a=0.f, s1b=0.f;
#pragma unroll
      for (int i = 0; i < 8; ++i) {
        s0a = fmaf(q0[i],   kr[i],   s0a);
        s0b = fmaf(q0[i+8], kr[i+8], s0b);
        s1a = fmaf(q1[i],   kr[i],   s1a);
        s1b = fmaf(q1[i+8], kr[i+8], s1b);
      }
      const float e0 = __expf((s0a + s0b) + m0[n]);
      const float e1 = __expf((s1a + s1b) + m1[n]);
      l0 += e0; l1 += e1;
      const float* vn = &Vs[nn2 * DDIM + h * 4];
#pragma unroll
      for (int c = 0; c < 4; ++c) {
        const float4 vv = *(const float4*)(vn + 32 * c);
        a0[4*c+0] = fmaf(e0, vv.x, a0[4*c+0]);
        a0[4*c+1] = fmaf(e0, vv.y, a0[4*c+1]);
        a0[4*c+2] = fmaf(e0, vv.z, a0[4*c+2]);
        a0[4*c+3] = fmaf(e0, vv.w, a0[4*c+3]);
        a1[4*c+0] = fmaf(e1, vv.x, a1[4*c+0]);
        a1[4*c+1] = fmaf(e1, vv.y, a1[4*c+1]);
        a1[4*c+2] = fmaf(e1, vv.z, a1[4*c+2]);
        a1[4*c+3] = fmaf(e1, vv.w, a1[4*c+3]);
      }
    }
  }
  if (act) {
    const int base = (b * NSPL + split) * PP + p0;
    float* d0 = po + base * DDIM + h * 16;
#pragma unroll
    for (int c = 0; c < 4; ++c) {
      *(float4*)(d0 + 4*c)        = make_float4(a0[4*c+0],a0[4*c+1],a0[4*c+2],a0[4*c+3]);
      *(float4*)(d0 + DDIM + 4*c) = make_float4(a1[4*c+0],a1[4*c+1],a1[4*c+2],a1[4*c+3]);
    }
    lsum[base * HH + h]       = l0;
    lsum[(base + 1) * HH + h] = l1;
  }
}

// ---------------------------------------------------------------------------
// merge: mh_in[b][p][d] = (sum_s po) / (sum_s lsum[h(d)])  (unchanged)
// ---------------------------------------------------------------------------
__global__ __launch_bounds__(256) void merge_kernel(
    const float* __restrict__ po, const float* __restrict__ lsum,
    float* __restrict__ mh_in)
{
  const int idx = blockIdx.x * 256 + threadIdx.x;   // over BB*PP*DDIM
  const int d = idx & 127;
  const int row = idx >> 7;        // b*PP + p
  const int b = row / PP;
  const int p = row - b * PP;
  const int h = d >> 4;
  float s = 0.f, lt = 0.f;
#pragma unroll
  for (int sp = 0; sp < NSPL; ++sp) {
    const int base = (b * NSPL + sp) * PP + p;
    s  += po[base * DDIM + d];
    lt += lsum[base * HH + h];
  }
  mh_in[idx] = s / lt;
}

// ---------------------------------------------------------------------------
// score2 via MFMA 32x32x16 split-bf16 + fused epilogue. (unchanged, r6)
// ---------------------------------------------------------------------------
__global__ __launch_bounds__(256) void score2_mfma_kernel(
    const float* __restrict__ enc, const float* __restrict__ mh,
    const float* __restrict__ mask, const float* __restrict__ bias_table,
    const int* __restrict__ group_ids, const int* __restrict__ cur_min,
    float* __restrict__ out, float* __restrict__ ssum)
{
  const int b   = blockIdx.x >> 4;
  const int nc  = blockIdx.x & 15;
  const int n0  = nc * 64;
  const int tid = threadIdx.x;
  const int lane = tid & 63;
  const int mt   = tid >> 6;        // wave = m-tile (rows 32mt..32mt+31)
  const int half = lane >> 5;
  const int l31  = lane & 31;

  f32x16 acc[2];
#pragma unroll
  for (int c = 0; c < 2; ++c)
#pragma unroll
    for (int i = 0; i < 16; ++i) acc[c][i] = 0.f;

  const float* mha = mh + ((size_t)(b * PP + 32 * mt + l31)) * DDIM + half * 8;
  const float* encb = enc + (size_t)b * NN * DDIM + half * 8;
  const int nsrc0 = min(n0 + l31, NN - 1);
  const int nsrc1 = min(n0 + 32 + l31, NN - 1);

#pragma unroll 1
  for (int ks = 0; ks < 8; ++ks) {
    bf16x8 ahi, alo;
    split8(mha + ks * 16, ahi, alo);
    bf16x8 bhi0, blo0, bhi1, blo1;
    split8(encb + (size_t)nsrc0 * DDIM + ks * 16, bhi0, blo0);
    split8(encb + (size_t)nsrc1 * DDIM + ks * 16, bhi1, blo1);
    acc[0] = __builtin_amdgcn_mfma_f32_32x32x16_bf16(ahi, bhi0, acc[0], 0, 0, 0);
    acc[0] = __builtin_amdgcn_mfma_f32_32x32x16_bf16(ahi, blo0, acc[0], 0, 0, 0);
    acc[0] = __builtin_amdgcn_mfma_f32_32x32x16_bf16(alo, bhi0, acc[0], 0, 0, 0);
    acc[1] = __builtin_amdgcn_mfma_f32_32x32x16_bf16(ahi, bhi1, acc[1], 0, 0, 0);
    acc[1] = __builtin_amdgcn_mfma_f32_32x32x16_bf16(ahi, blo1, acc[1], 0, 0, 0);
    acc[1] = __builtin_amdgcn_mfma_f32_32x32x16_bf16(alo, bhi1, acc[1], 0, 0, 0);
  }

  const float t0 = bias_table[0], t1 = bias_table[1], t2 = bias_table[2],
              t3 = bias_table[3], t4 = bias_table[4];
  const float two_inv_sqrt_emb = 0.1767766952966369f;  // 2/sqrt(128)

  float rsum[16];
#pragma unroll
  for (int r = 0; r < 16; ++r) rsum[r] = 0.f;

#pragma unroll
  for (int ct = 0; ct < 2; ++ct) {
    const int n = n0 + ct * 32 + l31;
    const bool nvalid = n < NN;
    const int nr = nvalid ? n : NN - 1;
    const int gid = group_ids[b * NN + nr];
#pragma unroll
    for (int r = 0; r < 16; ++r) {
      const int p = 32 * mt + (r & 3) + 8 * (r >> 2) + 4 * half;
      const bool pvalid = p < PP;
      const int pr = pvalid ? p : PP - 1;
      const float m = mask[((size_t)(b * PP + pr)) * NN + nr];
      const float ex = __expf(acc[ct][r] * two_inv_sqrt_emb);
      const float sc = 10.0f - 20.0f / (ex + 1.0f);
      const int cmp = cur_min[b * PP + pr];
      int delta = gid - cmp;
      delta = delta < 0 ? 0 : (delta > 4 ? 4 : delta);
      const float pb = (delta == 0) ? t0 : (delta == 1) ? t1 : (delta == 2) ? t2
                     : (delta == 3) ? t3 : t4;
      float e = (nvalid && pvalid) ? __expf(sc + pb + m) : 0.0f;
      if (nvalid && pvalid) out[((size_t)(b * PP + p)) * NN + n] = e;
      float ws = e;
#pragma unroll
      for (int off = 1; off < 32; off <<= 1) ws += __shfl_xor(ws, off, 64);
      rsum[r] += ws;
    }
  }
  if (l31 == 0) {
#pragma unroll
    for (int r = 0; r < 16; ++r) {
      const int p = 32 * mt + (r & 3) + 8 * (r >> 2) + 4 * half;
      if (p < PP) ssum[(size_t)(b * PP + p) * 16 + nc] = rsum[r];
    }
  }
}

// ---------------------------------------------------------------------------
// normalize: out[row][n] /= sum of 16 chunk partials  (unchanged)
// ---------------------------------------------------------------------------
__global__ __launch_bounds__(256) void norm_kernel(
    const float* __restrict__ ssum, float* __restrict__ out)
{
  const int row = blockIdx.x;   // b*PP + p
  float s = 0.f;
#pragma unroll
  for (int i = 0; i < 16; ++i) s += ssum[(size_t)row * 16 + i];
  const float inv = 1.0f / s;
#pragma unroll
  for (int i = 0; i < 4; ++i) {
    const int c = i * 256 + (int)threadIdx.x;
    if (c < NN) out[(size_t)row * NN + c] *= inv;
  }
}

// ---------------------------------------------------------------------------
extern "C" void kernel_launch(void* const* d_in, const int* in_sizes, int n_in,
                              void* d_out, int out_size, void* d_ws, size_t ws_size,
                              hipStream_t stream)
{
  (void)in_sizes; (void)n_in; (void)out_size; (void)ws_size;
  const float* enc_nodes  = (const float*)d_in[0];
  const float* enc_q1     = (const float*)d_in[1];
  const float* enc_last   = (const float*)d_in[2];
  const float* ninf       = (const float*)d_in[3];
  const float* Wq_first   = (const float*)d_in[4];
  const float* Wq_last    = (const float*)d_in[5];
  const float* Wk         = (const float*)d_in[6];
  const float* Wv         = (const float*)d_in[7];
  const float* W_comb     = (const float*)d_in[8];
  const float* b_comb     = (const float*)d_in[9];
  const float* bias_table = (const float*)d_in[10];
  const int*   group_ids  = (const int*)d_in[11];
  const int*   cur_min    = (const int*)d_in[12];
  float* out = (float*)d_out;
  float* ws  = (float*)d_ws;

  float* Qw = ws;                    //   819200 floats (reused as mh_in after attn)
  float* Kw = Qw + 819200;           //  8192000
  float* Vw = Kw + 8192000;          //  8192000
  float* po = Vw + 8192000;          //  6553600  (BB*NSPL*PP*DDIM)
  float* ls = po + 6553600;          //   409600  (BB*NSPL*PP*HH)
  float* mh = ls + 409600;           //   819200
  float* sm = mh + 819200;           //   102400  (BB*PP*16)

  // wfrag (128 KB) aliases the head of po: pack_w + proj_kv complete before
  // attn writes po (stream-ordered), so no conflict.
  u32x4* wfrag = (u32x4*)po;

  // pack W_k/W_v into split-bf16 MFMA fragments
  pack_w_kernel<<<16, 256, 0, stream>>>(Wk, Wv, wfrag);
  // Q = (q1@Wq_first + last@Wq_last) * 0.25  (fold 1/sqrt(QD))
  proj_q2_kernel<<<BB*PP/32, 256, 0, stream>>>(enc_q1, enc_last, Wq_first, Wq_last,
                                               Qw, 0.25f);
  // K, V projections via split-bf16 MFMA
  proj_kv_mfma_kernel<<<BB*NN/128, 256, 0, stream>>>(enc_nodes, wfrag, Kw, Vw);
  // attention partials (LDS-staged K/V, swizzled layout)
  attn_kernel<<<BB*NSPL, 448, 0, stream>>>(Qw, Kw, Vw, ninf, po, ls);
  // merge partials -> mh_in (reuses Qw)
  merge_kernel<<<3200, 256, 0, stream>>>(po, ls, Qw);
  // combine: mh = mh_in @ W_comb + b_comb
  proj_bias_kernel<<<BB*PP/32, 256, 0, stream>>>(Qw, W_comb, b_comb, mh);
  // final scores via MFMA + fused epilogue
  score2_mfma_kernel<<<BB*16, 256, 0, stream>>>(enc_nodes, mh, ninf, bias_table,
                                                group_ids, cur_min, out, sm);
  // normalize
  norm_kernel<<<BB*PP, 256, 0, stream>>>(sm, out);
}

// Round 8
// 272.762 us; speedup vs baseline: 1.6871x; 1.0581x over previous
//
#include <hip/hip_runtime.h>

#define BB 64
#define PP 100
#define NN 1000
#define DDIM 128
#define HH 8
#define NSPL 8

typedef __attribute__((ext_vector_type(8))) short bf16x8;   // 8 bf16 = 4 VGPRs
typedef __attribute__((ext_vector_type(16))) float f32x16;  // MFMA 32x32 acc
typedef __attribute__((ext_vector_type(4))) unsigned u32x4;

__device__ __forceinline__ unsigned bf16rne(float x) {
  unsigned u = __float_as_uint(x);
  return (u + 0x7FFFu + ((u >> 16) & 1u)) >> 16;
}
__device__ __forceinline__ unsigned pk_bf16(float a, float b) {
  return bf16rne(a) | (bf16rne(b) << 16);
}

// split 8 contiguous floats into hi/lo bf16x8 fragments
__device__ __forceinline__ void split8(const float* __restrict__ p,
                                       bf16x8& hi8, bf16x8& lo8) {
  const float4 a = *(const float4*)p;
  const float4 c = *(const float4*)(p + 4);
  float v[8] = {a.x, a.y, a.z, a.w, c.x, c.y, c.z, c.w};
  unsigned hw[4], lw[4];
#pragma unroll
  for (int j = 0; j < 4; ++j) {
    const unsigned h0 = bf16rne(v[2*j]), h1 = bf16rne(v[2*j+1]);
    hw[j] = h0 | (h1 << 16);
    lw[j] = bf16rne(v[2*j]   - __uint_as_float(h0 << 16)) |
            (bf16rne(v[2*j+1] - __uint_as_float(h1 << 16)) << 16);
  }
  hi8 = __builtin_bit_cast(bf16x8, u32x4{hw[0], hw[1], hw[2], hw[3]});
  lo8 = __builtin_bit_cast(bf16x8, u32x4{lw[0], lw[1], lw[2], lw[3]});
}

// ---------------------------------------------------------------------------
// pack W (fp32 128x128) -> MFMA B-fragment layout, split hi/lo bf16.
// (unchanged, verified round 5)
// ---------------------------------------------------------------------------
__global__ __launch_bounds__(256) void pack_w_kernel(
    const float* __restrict__ Wk, const float* __restrict__ Wv,
    u32x4* __restrict__ wfrag)
{
  const int gid = blockIdx.x * 256 + threadIdx.x;  // [0, 4096)
  const int mat = gid >> 11;
  const int ct = (gid >> 9) & 3;
  const int ks = (gid >> 6) & 7;
  const int lane = gid & 63;
  const float* __restrict__ W = mat ? Wv : Wk;
  const int col = ct * 32 + (lane & 31);
  const int k0 = ks * 16 + (lane >> 5) * 8;
  unsigned hi[4], lo[4];
#pragma unroll
  for (int j = 0; j < 4; ++j) {
    const float x0 = W[(k0 + 2 * j) * DDIM + col];
    const float x1 = W[(k0 + 2 * j + 1) * DDIM + col];
    const unsigned h0 = bf16rne(x0), h1 = bf16rne(x1);
    hi[j] = h0 | (h1 << 16);
    lo[j] = bf16rne(x0 - __uint_as_float(h0 << 16)) |
            (bf16rne(x1 - __uint_as_float(h1 << 16)) << 16);
  }
  const int base = (((mat * 4 + ct) * 8 + ks) * 2) * 64 + lane;
  wfrag[base]      = u32x4{hi[0], hi[1], hi[2], hi[3]};
  wfrag[base + 64] = u32x4{lo[0], lo[1], lo[2], lo[3]};
}

// ---------------------------------------------------------------------------
// K+V projection via MFMA 32x32x16 bf16, split-precision. (unchanged, r5)
// ---------------------------------------------------------------------------
__global__ __launch_bounds__(256) void proj_kv_mfma_kernel(
    const float* __restrict__ x, const u32x4* __restrict__ wfrag,
    float* __restrict__ outk, float* __restrict__ outv)
{
  const int tid = threadIdx.x;
  const int lane = tid & 63;
  const int wid = tid >> 6;
  const int rtp = wid >> 1;
  const int ctp = wid & 1;
  const int arow = blockIdx.x * 128 + rtp * 64 + (lane & 31);
  const int kgrp = (lane >> 5) * 8;

#pragma unroll 1
  for (int mat = 0; mat < 2; ++mat) {
    float* __restrict__ out = mat ? outv : outk;
    f32x16 acc[2][2];
#pragma unroll
    for (int a = 0; a < 2; ++a)
#pragma unroll
      for (int b = 0; b < 2; ++b)
#pragma unroll
        for (int i = 0; i < 16; ++i) acc[a][b][i] = 0.f;

#pragma unroll 1
    for (int ks = 0; ks < 8; ++ks) {
      bf16x8 ahi[2], alo[2];
#pragma unroll
      for (int rt = 0; rt < 2; ++rt) {
        const float* xp = x + (size_t)(arow + rt * 32) * DDIM + ks * 16 + kgrp;
        split8(xp, ahi[rt], alo[rt]);
      }
#pragma unroll
      for (int ct = 0; ct < 2; ++ct) {
        const int c = ctp * 2 + ct;
        const int fo = (((mat * 4 + c) * 8 + ks) * 2) * 64 + lane;
        const bf16x8 bhi = __builtin_bit_cast(bf16x8, wfrag[fo]);
        const bf16x8 blo = __builtin_bit_cast(bf16x8, wfrag[fo + 64]);
#pragma unroll
        for (int rt = 0; rt < 2; ++rt) {
          acc[rt][ct] = __builtin_amdgcn_mfma_f32_32x32x16_bf16(
              ahi[rt], bhi, acc[rt][ct], 0, 0, 0);
          acc[rt][ct] = __builtin_amdgcn_mfma_f32_32x32x16_bf16(
              ahi[rt], blo, acc[rt][ct], 0, 0, 0);
          acc[rt][ct] = __builtin_amdgcn_mfma_f32_32x32x16_bf16(
              alo[rt], bhi, acc[rt][ct], 0, 0, 0);
        }
      }
    }
#pragma unroll
    for (int rt = 0; rt < 2; ++rt)
#pragma unroll
      for (int ct = 0; ct < 2; ++ct) {
        const int colg = ctp * 64 + ct * 32 + (lane & 31);
        const int rowg0 = blockIdx.x * 128 + rtp * 64 + rt * 32 + 4 * (lane >> 5);
#pragma unroll
        for (int r = 0; r < 16; ++r) {
          const int rowg = rowg0 + (r & 3) + 8 * (r >> 2);
          out[(size_t)rowg * DDIM + colg] = acc[rt][ct][r];
        }
      }
  }
}

// ---------------------------------------------------------------------------
// Fused Q projection: out = (x1@W1 + x2@W2) * scale. (unchanged)
// ---------------------------------------------------------------------------
__global__ __launch_bounds__(256) void proj_q2_kernel(
    const float* __restrict__ x1, const float* __restrict__ x2,
    const float* __restrict__ W1, const float* __restrict__ W2,
    float* __restrict__ out, float scale)
{
  const int tid = threadIdx.x;
  const int j = tid & 127;
  const int rhalf = __builtin_amdgcn_readfirstlane(tid >> 7);
  const size_t r0 = (size_t)blockIdx.x * 32 + rhalf * 16;
  const float* xb1 = x1 + r0 * DDIM;
  const float* xb2 = x2 + r0 * DDIM;

  float acc[16];
#pragma unroll
  for (int r = 0; r < 16; ++r) acc[r] = 0.f;

#pragma unroll 2
  for (int dc = 0; dc < DDIM; dc += 4) {
    const float a0 = W1[(dc + 0) * DDIM + j];
    const float a1 = W1[(dc + 1) * DDIM + j];
    const float a2 = W1[(dc + 2) * DDIM + j];
    const float a3 = W1[(dc + 3) * DDIM + j];
#pragma unroll
    for (int r = 0; r < 16; ++r) {
      const float4 xv = *(const float4*)(xb1 + r * DDIM + dc);
      acc[r] = fmaf(xv.w, a3, fmaf(xv.z, a2, fmaf(xv.y, a1, fmaf(xv.x, a0, acc[r]))));
    }
    const float b0 = W2[(dc + 0) * DDIM + j];
    const float b1 = W2[(dc + 1) * DDIM + j];
    const float b2 = W2[(dc + 2) * DDIM + j];
    const float b3 = W2[(dc + 3) * DDIM + j];
#pragma unroll
    for (int r = 0; r < 16; ++r) {
      const float4 xv = *(const float4*)(xb2 + r * DDIM + dc);
      acc[r] = fmaf(xv.w, b3, fmaf(xv.z, b2, fmaf(xv.y, b1, fmaf(xv.x, b0, acc[r]))));
    }
  }
  float* o = out + r0 * DDIM + j;
#pragma unroll
  for (int r = 0; r < 16; ++r) o[r * DDIM] = acc[r] * scale;
}

// ---------------------------------------------------------------------------
// Combine projection with bias: out = x@W + bias. (unchanged)
// ---------------------------------------------------------------------------
__global__ __launch_bounds__(256) void proj_bias_kernel(
    const float* __restrict__ x, const float* __restrict__ W,
    const float* __restrict__ bias, float* __restrict__ out)
{
  const int tid = threadIdx.x;
  const int j = tid & 127;
  const int rhalf = __builtin_amdgcn_readfirstlane(tid >> 7);
  const size_t r0 = (size_t)blockIdx.x * 32 + rhalf * 16;
  const float* xb = x + r0 * DDIM;
  const float bj = bias[j];

  float acc[16];
#pragma unroll
  for (int r = 0; r < 16; ++r) acc[r] = bj;

#pragma unroll 2
  for (int dc = 0; dc < DDIM; dc += 4) {
    const float w0 = W[(dc + 0) * DDIM + j];
    const float w1 = W[(dc + 1) * DDIM + j];
    const float w2 = W[(dc + 2) * DDIM + j];
    const float w3 = W[(dc + 3) * DDIM + j];
#pragma unroll
    for (int r = 0; r < 16; ++r) {
      const float4 xv = *(const float4*)(xb + r * DDIM + dc);
      acc[r] = fmaf(xv.w, w3, fmaf(xv.z, w2, fmaf(xv.y, w1, fmaf(xv.x, w0, acc[r]))));
    }
  }
  float* o = out + r0 * DDIM + j;
#pragma unroll
  for (int r = 0; r < 16; ++r) o[r * DDIM] = acc[r];
}

// ---------------------------------------------------------------------------
// MFMA attention (replaces VALU attn: 95us, VALU floor ~48us was the wall).
// Block = (b, 128-n chunk); 8 waves, wave = head. Per 32-n tile:
//   S^T[n][p] = mfma(A=K-frag, B=Q^T-frag)  (3x split-bf16)
//   epilogue per lane (p = lane&31 fixed): +mask (LDS), exp, pad-kill
//   P routed C->A frag via pack + shfl_xor(32) half-exchange (T12 pattern)
//   out[p][d] += mfma(A=P, B=V)             (3x split-bf16 per 16-n ks)
// Unnormalized out + sum(e) written in the existing po/ls layout (merge
// kernel unchanged). Mask staged once per block in LDS [p][132] fp32; the
// only barrier. n padded to 1024: e forced 0 for n>=1000.
// ---------------------------------------------------------------------------
__global__ __launch_bounds__(512) void attn_mfma_kernel(
    const float* __restrict__ Q, const float* __restrict__ K,
    const float* __restrict__ V, const float* __restrict__ mask,
    float* __restrict__ po, float* __restrict__ lsum)
{
  __shared__ float mask_lds[PP * 132];   // [p][n-chunk], pad 132 for banks

  const int b = blockIdx.x >> 3;
  const int chunk = blockIdx.x & 7;
  const int n0 = chunk * 128;
  const int tid = threadIdx.x;
  const int h = tid >> 6;          // wave = head
  const int l = tid & 63;
  const int hi = l >> 5;
  const int l31 = l & 31;

  // stage mask rows [p][n0..n0+127] -> LDS (coalesced float4 reads)
  for (int idx = tid; idx < PP * 32; idx += 512) {
    const int p = idx >> 5;
    const int c = idx & 31;
    const int nsrc = min(n0 + 4 * c, NN - 4);
    *(float4*)&mask_lds[p * 132 + 4 * c] =
        *(const float4*)(mask + ((size_t)(b * PP + p)) * NN + nsrc);
  }
  __syncthreads();

  // Q B-fragments (col = p, k = d), split hi/lo; 4 p-tiles cover p 0..127
  bf16x8 qhi[4], qlo[4];
#pragma unroll
  for (int pt = 0; pt < 4; ++pt) {
    const int qrow = min(b * PP + pt * 32 + l31, BB * PP - 1);
    split8(Q + (size_t)qrow * DDIM + h * 16 + hi * 8, qhi[pt], qlo[pt]);
  }

  f32x16 oacc[4];
#pragma unroll
  for (int pt = 0; pt < 4; ++pt)
#pragma unroll
    for (int i = 0; i < 16; ++i) oacc[pt][i] = 0.f;
  float lacc[4] = {0.f, 0.f, 0.f, 0.f};

  const float* Kb = K + (size_t)b * NN * DDIM + h * 16;
  const float* Vb = V + (size_t)b * NN * DDIM + h * 16;
  const int dv = min(l31, 15);     // V col clamp (d<16 valid)

#pragma unroll 1
  for (int nt = 0; nt < 4; ++nt) {
    const int nb = n0 + nt * 32;   // absolute n of this 32-tile

    // K A-fragment: row n = nb + l31 (clamped), k = d slice
    bf16x8 khi, klo;
    {
      const int krow = min(nb + l31, NN - 1);
      split8(Kb + (size_t)krow * DDIM + hi * 8, khi, klo);
    }
    // V B-fragments for ks=0,1: lane holds V[n = nb+16ks+8hi+i][d = l31]
    bf16x8 vhi[2], vlo[2];
#pragma unroll
    for (int ks = 0; ks < 2; ++ks) {
      float vt[8];
#pragma unroll
      for (int i = 0; i < 8; ++i) {
        const int vrow = min(nb + ks * 16 + hi * 8 + i, NN - 1);
        vt[i] = Vb[(size_t)vrow * DDIM + dv];
      }
      unsigned vh[4], vl[4];
#pragma unroll
      for (int j = 0; j < 4; ++j) {
        const unsigned h0 = bf16rne(vt[2*j]), h1 = bf16rne(vt[2*j+1]);
        vh[j] = h0 | (h1 << 16);
        vl[j] = bf16rne(vt[2*j]   - __uint_as_float(h0 << 16)) |
                (bf16rne(vt[2*j+1] - __uint_as_float(h1 << 16)) << 16);
      }
      vhi[ks] = __builtin_bit_cast(bf16x8, u32x4{vh[0], vh[1], vh[2], vh[3]});
      vlo[ks] = __builtin_bit_cast(bf16x8, u32x4{vl[0], vl[1], vl[2], vl[3]});
    }

#pragma unroll
    for (int pt = 0; pt < 4; ++pt) {
      // S^T = K . Q^T  (C: col = p = l31, row = n = (r&3)+8(r>>2)+4hi)
      f32x16 s;
#pragma unroll
      for (int i = 0; i < 16; ++i) s[i] = 0.f;
      s = __builtin_amdgcn_mfma_f32_32x32x16_bf16(khi, qhi[pt], s, 0, 0, 0);
      s = __builtin_amdgcn_mfma_f32_32x32x16_bf16(khi, qlo[pt], s, 0, 0, 0);
      s = __builtin_amdgcn_mfma_f32_32x32x16_bf16(klo, qhi[pt], s, 0, 0, 0);

      // mask quads: r=4q..4q+3 <-> n_loc = 8q + 4hi + (0..3)
      const int prow = min(pt * 32 + l31, PP - 1);
      float mq[16];
#pragma unroll
      for (int q = 0; q < 4; ++q) {
        const float4 f =
            *(const float4*)&mask_lds[prow * 132 + nt * 32 + q * 8 + hi * 4];
        mq[4*q+0] = f.x; mq[4*q+1] = f.y; mq[4*q+2] = f.z; mq[4*q+3] = f.w;
      }
      // exp + pad-kill + lsum + hi/lo split
      float e[16], elo[16];
      unsigned ehw[16];
#pragma unroll
      for (int r = 0; r < 16; ++r) {
        const int n_abs = nb + (r & 3) + 8 * (r >> 2) + 4 * hi;
        float ev = __expf(s[r] + mq[r]);
        ev = (n_abs < NN) ? ev : 0.f;
        e[r] = ev;
        lacc[pt] += ev;
        ehw[r] = bf16rne(ev);
        elo[r] = ev - __uint_as_float(ehw[r] << 16);
      }
      // route C-layout P -> A-frag (half-wave exchange), per 16-n ks
#pragma unroll
      for (int ks = 0; ks < 2; ++ks) {
        const int rb = ks * 8;
        const unsigned t01h = ehw[rb+0] | (ehw[rb+1] << 16);
        const unsigned t23h = ehw[rb+2] | (ehw[rb+3] << 16);
        const unsigned t45h = ehw[rb+4] | (ehw[rb+5] << 16);
        const unsigned t67h = ehw[rb+6] | (ehw[rb+7] << 16);
        const unsigned t01l = pk_bf16(elo[rb+0], elo[rb+1]);
        const unsigned t23l = pk_bf16(elo[rb+2], elo[rb+3]);
        const unsigned t45l = pk_bf16(elo[rb+4], elo[rb+5]);
        const unsigned t67l = pk_bf16(elo[rb+6], elo[rb+7]);
        const unsigned s01h = (unsigned)__shfl_xor((int)t01h, 32, 64);
        const unsigned s23h = (unsigned)__shfl_xor((int)t23h, 32, 64);
        const unsigned s45h = (unsigned)__shfl_xor((int)t45h, 32, 64);
        const unsigned s67h = (unsigned)__shfl_xor((int)t67h, 32, 64);
        const unsigned s01l = (unsigned)__shfl_xor((int)t01l, 32, 64);
        const unsigned s23l = (unsigned)__shfl_xor((int)t23l, 32, 64);
        const unsigned s45l = (unsigned)__shfl_xor((int)t45l, 32, 64);
        const unsigned s67l = (unsigned)__shfl_xor((int)t67l, 32, 64);
        const bf16x8 pah = __builtin_bit_cast(bf16x8, u32x4{
            hi ? s45h : t01h, hi ? s67h : t23h,
            hi ? t45h : s01h, hi ? t67h : s23h});
        const bf16x8 pal = __builtin_bit_cast(bf16x8, u32x4{
            hi ? s45l : t01l, hi ? s67l : t23l,
            hi ? t45l : s01l, hi ? t67l : s23l});
        oacc[pt] = __builtin_amdgcn_mfma_f32_32x32x16_bf16(pah, vhi[ks], oacc[pt], 0, 0, 0);
        oacc[pt] = __builtin_amdgcn_mfma_f32_32x32x16_bf16(pah, vlo[ks], oacc[pt], 0, 0, 0);
        oacc[pt] = __builtin_amdgcn_mfma_f32_32x32x16_bf16(pal, vhi[ks], oacc[pt], 0, 0, 0);
      }
    }
  }

  // stores: po[(base+p)*128 + h*16 + d], ls[(base+p)*8 + h]
  const int base = (b * NSPL + chunk) * PP;
#pragma unroll
  for (int pt = 0; pt < 4; ++pt) {
    const float ltot = lacc[pt] + __shfl_xor(lacc[pt], 32, 64);
    const int pl = pt * 32 + l31;
    if (l < 32 && pl < PP)
      lsum[(size_t)(base + pl) * HH + h] = ltot;
#pragma unroll
    for (int r = 0; r < 16; ++r) {
      const int p = pt * 32 + (r & 3) + 8 * (r >> 2) + 4 * hi;
      if (l31 < 16 && p < PP)
        po[(size_t)(base + p) * DDIM + h * 16 + l31] = oacc[pt][r];
    }
  }
}

// ---------------------------------------------------------------------------
// merge: mh_in[b][p][d] = (sum_s po) / (sum_s lsum[h(d)])  (unchanged)
// ---------------------------------------------------------------------------
__global__ __launch_bounds__(256) void merge_kernel(
    const float* __restrict__ po, const float* __restrict__ lsum,
    float* __restrict__ mh_in)
{
  const int idx = blockIdx.x * 256 + threadIdx.x;   // over BB*PP*DDIM
  const int d = idx & 127;
  const int row = idx >> 7;        // b*PP + p
  const int b = row / PP;
  const int p = row - b * PP;
  const int h = d >> 4;
  float s = 0.f, lt = 0.f;
#pragma unroll
  for (int sp = 0; sp < NSPL; ++sp) {
    const int base = (b * NSPL + sp) * PP + p;
    s  += po[base * DDIM + d];
    lt += lsum[base * HH + h];
  }
  mh_in[idx] = s / lt;
}

// ---------------------------------------------------------------------------
// score2 via MFMA 32x32x16 split-bf16 + fused epilogue. (unchanged, r6)
// ---------------------------------------------------------------------------
__global__ __launch_bounds__(256) void score2_mfma_kernel(
    const float* __restrict__ enc, const float* __restrict__ mh,
    const float* __restrict__ mask, const float* __restrict__ bias_table,
    const int* __restrict__ group_ids, const int* __restrict__ cur_min,
    float* __restrict__ out, float* __restrict__ ssum)
{
  const int b   = blockIdx.x >> 4;
  const int nc  = blockIdx.x & 15;
  const int n0  = nc * 64;
  const int tid = threadIdx.x;
  const int lane = tid & 63;
  const int mt   = tid >> 6;
  const int half = lane >> 5;
  const int l31  = lane & 31;

  f32x16 acc[2];
#pragma unroll
  for (int c = 0; c < 2; ++c)
#pragma unroll
    for (int i = 0; i < 16; ++i) acc[c][i] = 0.f;

  const float* mha = mh + ((size_t)(b * PP + 32 * mt + l31)) * DDIM + half * 8;
  const float* encb = enc + (size_t)b * NN * DDIM + half * 8;
  const int nsrc0 = min(n0 + l31, NN - 1);
  const int nsrc1 = min(n0 + 32 + l31, NN - 1);

#pragma unroll 1
  for (int ks = 0; ks < 8; ++ks) {
    bf16x8 ahi, alo;
    split8(mha + ks * 16, ahi, alo);
    bf16x8 bhi0, blo0, bhi1, blo1;
    split8(encb + (size_t)nsrc0 * DDIM + ks * 16, bhi0, blo0);
    split8(encb + (size_t)nsrc1 * DDIM + ks * 16, bhi1, blo1);
    acc[0] = __builtin_amdgcn_mfma_f32_32x32x16_bf16(ahi, bhi0, acc[0], 0, 0, 0);
    acc[0] = __builtin_amdgcn_mfma_f32_32x32x16_bf16(ahi, blo0, acc[0], 0, 0, 0);
    acc[0] = __builtin_amdgcn_mfma_f32_32x32x16_bf16(alo, bhi0, acc[0], 0, 0, 0);
    acc[1] = __builtin_amdgcn_mfma_f32_32x32x16_bf16(ahi, bhi1, acc[1], 0, 0, 0);
    acc[1] = __builtin_amdgcn_mfma_f32_32x32x16_bf16(ahi, blo1, acc[1], 0, 0, 0);
    acc[1] = __builtin_amdgcn_mfma_f32_32x32x16_bf16(alo, bhi1, acc[1], 0, 0, 0);
  }

  const float t0 = bias_table[0], t1 = bias_table[1], t2 = bias_table[2],
              t3 = bias_table[3], t4 = bias_table[4];
  const float two_inv_sqrt_emb = 0.1767766952966369f;  // 2/sqrt(128)

  float rsum[16];
#pragma unroll
  for (int r = 0; r < 16; ++r) rsum[r] = 0.f;

#pragma unroll
  for (int ct = 0; ct < 2; ++ct) {
    const int n = n0 + ct * 32 + l31;
    const bool nvalid = n < NN;
    const int nr = nvalid ? n : NN - 1;
    const int gid = group_ids[b * NN + nr];
#pragma unroll
    for (int r = 0; r < 16; ++r) {
      const int p = 32 * mt + (r & 3) + 8 * (r >> 2) + 4 * half;
      const bool pvalid = p < PP;
      const int pr = pvalid ? p : PP - 1;
      const float m = mask[((size_t)(b * PP + pr)) * NN + nr];
      const float ex = __expf(acc[ct][r] * two_inv_sqrt_emb);
      const float sc = 10.0f - 20.0f / (ex + 1.0f);
      const int cmp = cur_min[b * PP + pr];
      int delta = gid - cmp;
      delta = delta < 0 ? 0 : (delta > 4 ? 4 : delta);
      const float pb = (delta == 0) ? t0 : (delta == 1) ? t1 : (delta == 2) ? t2
                     : (delta == 3) ? t3 : t4;
      float e = (nvalid && pvalid) ? __expf(sc + pb + m) : 0.0f;
      if (nvalid && pvalid) out[((size_t)(b * PP + p)) * NN + n] = e;
      float ws = e;
#pragma unroll
      for (int off = 1; off < 32; off <<= 1) ws += __shfl_xor(ws, off, 64);
      rsum[r] += ws;
    }
  }
  if (l31 == 0) {
#pragma unroll
    for (int r = 0; r < 16; ++r) {
      const int p = 32 * mt + (r & 3) + 8 * (r >> 2) + 4 * half;
      if (p < PP) ssum[(size_t)(b * PP + p) * 16 + nc] = rsum[r];
    }
  }
}

// ---------------------------------------------------------------------------
// normalize: out[row][n] /= sum of 16 chunk partials  (unchanged)
// ---------------------------------------------------------------------------
__global__ __launch_bounds__(256) void norm_kernel(
    const float* __restrict__ ssum, float* __restrict__ out)
{
  const int row = blockIdx.x;   // b*PP + p
  float s = 0.f;
#pragma unroll
  for (int i = 0; i < 16; ++i) s += ssum[(size_t)row * 16 + i];
  const float inv = 1.0f / s;
#pragma unroll
  for (int i = 0; i < 4; ++i) {
    const int c = i * 256 + (int)threadIdx.x;
    if (c < NN) out[(size_t)row * NN + c] *= inv;
  }
}

// ---------------------------------------------------------------------------
extern "C" void kernel_launch(void* const* d_in, const int* in_sizes, int n_in,
                              void* d_out, int out_size, void* d_ws, size_t ws_size,
                              hipStream_t stream)
{
  (void)in_sizes; (void)n_in; (void)out_size; (void)ws_size;
  const float* enc_nodes  = (const float*)d_in[0];
  const float* enc_q1     = (const float*)d_in[1];
  const float* enc_last   = (const float*)d_in[2];
  const float* ninf       = (const float*)d_in[3];
  const float* Wq_first   = (const float*)d_in[4];
  const float* Wq_last    = (const float*)d_in[5];
  const float* Wk         = (const float*)d_in[6];
  const float* Wv         = (const float*)d_in[7];
  const float* W_comb     = (const float*)d_in[8];
  const float* b_comb     = (const float*)d_in[9];
  const float* bias_table = (const float*)d_in[10];
  const int*   group_ids  = (const int*)d_in[11];
  const int*   cur_min    = (const int*)d_in[12];
  float* out = (float*)d_out;
  float* ws  = (float*)d_ws;

  float* Qw = ws;                    //   819200 floats (reused as mh_in after attn)
  float* Kw = Qw + 819200;           //  8192000
  float* Vw = Kw + 8192000;          //  8192000
  float* po = Vw + 8192000;          //  6553600  (BB*NSPL*PP*DDIM)
  float* ls = po + 6553600;          //   409600  (BB*NSPL*PP*HH)
  float* mh = ls + 409600;           //   819200
  float* sm = mh + 819200;           //   102400  (BB*PP*16)

  // wfrag (128 KB) aliases the head of po: pack_w + proj_kv complete before
  // attn writes po (stream-ordered), so no conflict.
  u32x4* wfrag = (u32x4*)po;

  // pack W_k/W_v into split-bf16 MFMA fragments
  pack_w_kernel<<<16, 256, 0, stream>>>(Wk, Wv, wfrag);
  // Q = (q1@Wq_first + last@Wq_last) * 0.25  (fold 1/sqrt(QD))
  proj_q2_kernel<<<BB*PP/32, 256, 0, stream>>>(enc_q1, enc_last, Wq_first, Wq_last,
                                               Qw, 0.25f);
  // K, V projections via split-bf16 MFMA
  proj_kv_mfma_kernel<<<BB*NN/128, 256, 0, stream>>>(enc_nodes, wfrag, Kw, Vw);
  // attention partials via MFMA (QK^T and PV on the matrix pipe)
  attn_mfma_kernel<<<BB*NSPL, 512, 0, stream>>>(Qw, Kw, Vw, ninf, po, ls);
  // merge partials -> mh_in (reuses Qw)
  merge_kernel<<<3200, 256, 0, stream>>>(po, ls, Qw);
  // combine: mh = mh_in @ W_comb + b_comb
  proj_bias_kernel<<<BB*PP/32, 256, 0, stream>>>(Qw, W_comb, b_comb, mh);
  // final scores via MFMA + fused epilogue
  score2_mfma_kernel<<<BB*16, 256, 0, stream>>>(enc_nodes, mh, ninf, bias_table,
                                                group_ids, cur_min, out, sm);
  // normalize
  norm_kernel<<<BB*PP, 256, 0, stream>>>(sm, out);
}

// Round 9
// 198.412 us; speedup vs baseline: 2.3193x; 1.3747x over previous
//
#include <hip/hip_runtime.h>

#define BB 64
#define PP 100
#define NN 1000
#define DDIM 128
#define HH 8
#define NSPL 8

typedef __attribute__((ext_vector_type(8))) short bf16x8;   // 8 bf16 = 4 VGPRs
typedef __attribute__((ext_vector_type(16))) float f32x16;  // MFMA 32x32 acc
typedef __attribute__((ext_vector_type(4))) unsigned u32x4;

__device__ __forceinline__ unsigned bf16rne(float x) {
  unsigned u = __float_as_uint(x);
  return (u + 0x7FFFu + ((u >> 16) & 1u)) >> 16;
}
__device__ __forceinline__ unsigned pk_bf16(float a, float b) {
  return bf16rne(a) | (bf16rne(b) << 16);
}

// split 8 contiguous floats into hi/lo bf16x8 fragments
__device__ __forceinline__ void split8(const float* __restrict__ p,
                                       bf16x8& hi8, bf16x8& lo8) {
  const float4 a = *(const float4*)p;
  const float4 c = *(const float4*)(p + 4);
  float v[8] = {a.x, a.y, a.z, a.w, c.x, c.y, c.z, c.w};
  unsigned hw[4], lw[4];
#pragma unroll
  for (int j = 0; j < 4; ++j) {
    const unsigned h0 = bf16rne(v[2*j]), h1 = bf16rne(v[2*j+1]);
    hw[j] = h0 | (h1 << 16);
    lw[j] = bf16rne(v[2*j]   - __uint_as_float(h0 << 16)) |
            (bf16rne(v[2*j+1] - __uint_as_float(h1 << 16)) << 16);
  }
  hi8 = __builtin_bit_cast(bf16x8, u32x4{hw[0], hw[1], hw[2], hw[3]});
  lo8 = __builtin_bit_cast(bf16x8, u32x4{lw[0], lw[1], lw[2], lw[3]});
}

// ---------------------------------------------------------------------------
// pack 5 weight matrices (fp32 128x128) -> MFMA B-fragment layout, split
// hi/lo bf16. mat: 0=Wk 1=Wv 2=Wq_first 3=Wq_last 4=W_comb.
// wfrag[((mat*4+ct)*8+ks)*2*64 + half*64 + lane]. 10240 threads (40 blocks).
// ---------------------------------------------------------------------------
__global__ __launch_bounds__(256) void pack_w_kernel(
    const float* __restrict__ W0, const float* __restrict__ W1,
    const float* __restrict__ W2, const float* __restrict__ W3,
    const float* __restrict__ W4, u32x4* __restrict__ wfrag)
{
  const int gid = blockIdx.x * 256 + threadIdx.x;  // [0, 10240)
  const int mat = gid >> 11;
  const int ct = (gid >> 9) & 3;
  const int ks = (gid >> 6) & 7;
  const int lane = gid & 63;
  const float* __restrict__ W =
      (mat == 0) ? W0 : (mat == 1) ? W1 : (mat == 2) ? W2 : (mat == 3) ? W3 : W4;
  const int col = ct * 32 + (lane & 31);
  const int k0 = ks * 16 + (lane >> 5) * 8;
  unsigned hi[4], lo[4];
#pragma unroll
  for (int j = 0; j < 4; ++j) {
    const float x0 = W[(k0 + 2 * j) * DDIM + col];
    const float x1 = W[(k0 + 2 * j + 1) * DDIM + col];
    const unsigned h0 = bf16rne(x0), h1 = bf16rne(x1);
    hi[j] = h0 | (h1 << 16);
    lo[j] = bf16rne(x0 - __uint_as_float(h0 << 16)) |
            (bf16rne(x1 - __uint_as_float(h1 << 16)) << 16);
  }
  const int base = (((mat * 4 + ct) * 8 + ks) * 2) * 64 + lane;
  wfrag[base]      = u32x4{hi[0], hi[1], hi[2], hi[3]};
  wfrag[base + 64] = u32x4{lo[0], lo[1], lo[2], lo[3]};
}

// ---------------------------------------------------------------------------
// K+V projection via MFMA 32x32x16 bf16, split-precision. (unchanged, r5)
// ---------------------------------------------------------------------------
__global__ __launch_bounds__(256) void proj_kv_mfma_kernel(
    const float* __restrict__ x, const u32x4* __restrict__ wfrag,
    float* __restrict__ outk, float* __restrict__ outv)
{
  const int tid = threadIdx.x;
  const int lane = tid & 63;
  const int wid = tid >> 6;
  const int rtp = wid >> 1;
  const int ctp = wid & 1;
  const int arow = blockIdx.x * 128 + rtp * 64 + (lane & 31);
  const int kgrp = (lane >> 5) * 8;

#pragma unroll 1
  for (int mat = 0; mat < 2; ++mat) {
    float* __restrict__ out = mat ? outv : outk;
    f32x16 acc[2][2];
#pragma unroll
    for (int a = 0; a < 2; ++a)
#pragma unroll
      for (int b = 0; b < 2; ++b)
#pragma unroll
        for (int i = 0; i < 16; ++i) acc[a][b][i] = 0.f;

#pragma unroll 1
    for (int ks = 0; ks < 8; ++ks) {
      bf16x8 ahi[2], alo[2];
#pragma unroll
      for (int rt = 0; rt < 2; ++rt) {
        const float* xp = x + (size_t)(arow + rt * 32) * DDIM + ks * 16 + kgrp;
        split8(xp, ahi[rt], alo[rt]);
      }
#pragma unroll
      for (int ct = 0; ct < 2; ++ct) {
        const int c = ctp * 2 + ct;
        const int fo = (((mat * 4 + c) * 8 + ks) * 2) * 64 + lane;
        const bf16x8 bhi = __builtin_bit_cast(bf16x8, wfrag[fo]);
        const bf16x8 blo = __builtin_bit_cast(bf16x8, wfrag[fo + 64]);
#pragma unroll
        for (int rt = 0; rt < 2; ++rt) {
          acc[rt][ct] = __builtin_amdgcn_mfma_f32_32x32x16_bf16(
              ahi[rt], bhi, acc[rt][ct], 0, 0, 0);
          acc[rt][ct] = __builtin_amdgcn_mfma_f32_32x32x16_bf16(
              ahi[rt], blo, acc[rt][ct], 0, 0, 0);
          acc[rt][ct] = __builtin_amdgcn_mfma_f32_32x32x16_bf16(
              alo[rt], bhi, acc[rt][ct], 0, 0, 0);
        }
      }
    }
#pragma unroll
    for (int rt = 0; rt < 2; ++rt)
#pragma unroll
      for (int ct = 0; ct < 2; ++ct) {
        const int colg = ctp * 64 + ct * 32 + (lane & 31);
        const int rowg0 = blockIdx.x * 128 + rtp * 64 + rt * 32 + 4 * (lane >> 5);
#pragma unroll
        for (int r = 0; r < 16; ++r) {
          const int rowg = rowg0 + (r & 3) + 8 * (r >> 2);
          out[(size_t)rowg * DDIM + colg] = acc[rt][ct][r];
        }
      }
  }
}

// ---------------------------------------------------------------------------
// Q projection via MFMA: out = (x1@Wq_first + x2@Wq_last) * scale.
// (replaces the round-4 s_load VALU version: 88.8us, occupancy 8%,
//  grid=200 latency-bound). Wave = 32 rows x 128 cols; both input GEMMs
//  accumulate into the same acc (the add is free). grid = 6400/128 = 50.
// ---------------------------------------------------------------------------
__global__ __launch_bounds__(256) void proj_q2_mfma_kernel(
    const float* __restrict__ x1, const float* __restrict__ x2,
    const u32x4* __restrict__ wfrag, float* __restrict__ out, float scale)
{
  const int tid = threadIdx.x;
  const int lane = tid & 63;
  const int w = tid >> 6;
  const int hi = lane >> 5;
  const int l31 = lane & 31;
  const int row0 = blockIdx.x * 128 + w * 32;
  const float* xr1 = x1 + (size_t)(row0 + l31) * DDIM + hi * 8;
  const float* xr2 = x2 + (size_t)(row0 + l31) * DDIM + hi * 8;

  f32x16 acc[4];
#pragma unroll
  for (int ct = 0; ct < 4; ++ct)
#pragma unroll
    for (int i = 0; i < 16; ++i) acc[ct][i] = 0.f;

#pragma unroll 1
  for (int ks = 0; ks < 8; ++ks) {
    bf16x8 a1h, a1l, a2h, a2l;
    split8(xr1 + ks * 16, a1h, a1l);
    split8(xr2 + ks * 16, a2h, a2l);
#pragma unroll
    for (int ct = 0; ct < 4; ++ct) {
      const int fo1 = (((2 * 4 + ct) * 8 + ks) * 2) * 64 + lane;  // Wq_first
      const bf16x8 b1h = __builtin_bit_cast(bf16x8, wfrag[fo1]);
      const bf16x8 b1l = __builtin_bit_cast(bf16x8, wfrag[fo1 + 64]);
      acc[ct] = __builtin_amdgcn_mfma_f32_32x32x16_bf16(a1h, b1h, acc[ct], 0, 0, 0);
      acc[ct] = __builtin_amdgcn_mfma_f32_32x32x16_bf16(a1h, b1l, acc[ct], 0, 0, 0);
      acc[ct] = __builtin_amdgcn_mfma_f32_32x32x16_bf16(a1l, b1h, acc[ct], 0, 0, 0);
      const int fo2 = (((3 * 4 + ct) * 8 + ks) * 2) * 64 + lane;  // Wq_last
      const bf16x8 b2h = __builtin_bit_cast(bf16x8, wfrag[fo2]);
      const bf16x8 b2l = __builtin_bit_cast(bf16x8, wfrag[fo2 + 64]);
      acc[ct] = __builtin_amdgcn_mfma_f32_32x32x16_bf16(a2h, b2h, acc[ct], 0, 0, 0);
      acc[ct] = __builtin_amdgcn_mfma_f32_32x32x16_bf16(a2h, b2l, acc[ct], 0, 0, 0);
      acc[ct] = __builtin_amdgcn_mfma_f32_32x32x16_bf16(a2l, b2h, acc[ct], 0, 0, 0);
    }
  }
#pragma unroll
  for (int ct = 0; ct < 4; ++ct) {
    const int colg = ct * 32 + l31;
    const int rowg0 = row0 + 4 * hi;
#pragma unroll
    for (int r = 0; r < 16; ++r) {
      const int rowg = rowg0 + (r & 3) + 8 * (r >> 2);
      out[(size_t)rowg * DDIM + colg] = acc[ct][r] * scale;
    }
  }
}

// ---------------------------------------------------------------------------
// Combine projection via MFMA: out = x@W_comb + bias. Same structure.
// grid = 50.
// ---------------------------------------------------------------------------
__global__ __launch_bounds__(256) void proj_comb_mfma_kernel(
    const float* __restrict__ x, const u32x4* __restrict__ wfrag,
    const float* __restrict__ bias, float* __restrict__ out)
{
  const int tid = threadIdx.x;
  const int lane = tid & 63;
  const int w = tid >> 6;
  const int hi = lane >> 5;
  const int l31 = lane & 31;
  const int row0 = blockIdx.x * 128 + w * 32;
  const float* xr = x + (size_t)(row0 + l31) * DDIM + hi * 8;

  f32x16 acc[4];
#pragma unroll
  for (int ct = 0; ct < 4; ++ct)
#pragma unroll
    for (int i = 0; i < 16; ++i) acc[ct][i] = 0.f;

#pragma unroll 1
  for (int ks = 0; ks < 8; ++ks) {
    bf16x8 ah, al;
    split8(xr + ks * 16, ah, al);
#pragma unroll
    for (int ct = 0; ct < 4; ++ct) {
      const int fo = (((4 * 4 + ct) * 8 + ks) * 2) * 64 + lane;  // W_comb
      const bf16x8 bh = __builtin_bit_cast(bf16x8, wfrag[fo]);
      const bf16x8 bl = __builtin_bit_cast(bf16x8, wfrag[fo + 64]);
      acc[ct] = __builtin_amdgcn_mfma_f32_32x32x16_bf16(ah, bh, acc[ct], 0, 0, 0);
      acc[ct] = __builtin_amdgcn_mfma_f32_32x32x16_bf16(ah, bl, acc[ct], 0, 0, 0);
      acc[ct] = __builtin_amdgcn_mfma_f32_32x32x16_bf16(al, bh, acc[ct], 0, 0, 0);
    }
  }
#pragma unroll
  for (int ct = 0; ct < 4; ++ct) {
    const int colg = ct * 32 + l31;
    const float bj = bias[colg];
    const int rowg0 = row0 + 4 * hi;
#pragma unroll
    for (int r = 0; r < 16; ++r) {
      const int rowg = rowg0 + (r & 3) + 8 * (r >> 2);
      out[(size_t)rowg * DDIM + colg] = acc[ct][r] + bj;
    }
  }
}

// ---------------------------------------------------------------------------
// MFMA attention. (unchanged, verified round 8)
// ---------------------------------------------------------------------------
__global__ __launch_bounds__(512) void attn_mfma_kernel(
    const float* __restrict__ Q, const float* __restrict__ K,
    const float* __restrict__ V, const float* __restrict__ mask,
    float* __restrict__ po, float* __restrict__ lsum)
{
  __shared__ float mask_lds[PP * 132];   // [p][n-chunk], pad 132 for banks

  const int b = blockIdx.x >> 3;
  const int chunk = blockIdx.x & 7;
  const int n0 = chunk * 128;
  const int tid = threadIdx.x;
  const int h = tid >> 6;          // wave = head
  const int l = tid & 63;
  const int hi = l >> 5;
  const int l31 = l & 31;

  for (int idx = tid; idx < PP * 32; idx += 512) {
    const int p = idx >> 5;
    const int c = idx & 31;
    const int nsrc = min(n0 + 4 * c, NN - 4);
    *(float4*)&mask_lds[p * 132 + 4 * c] =
        *(const float4*)(mask + ((size_t)(b * PP + p)) * NN + nsrc);
  }
  __syncthreads();

  bf16x8 qhi[4], qlo[4];
#pragma unroll
  for (int pt = 0; pt < 4; ++pt) {
    const int qrow = min(b * PP + pt * 32 + l31, BB * PP - 1);
    split8(Q + (size_t)qrow * DDIM + h * 16 + hi * 8, qhi[pt], qlo[pt]);
  }

  f32x16 oacc[4];
#pragma unroll
  for (int pt = 0; pt < 4; ++pt)
#pragma unroll
    for (int i = 0; i < 16; ++i) oacc[pt][i] = 0.f;
  float lacc[4] = {0.f, 0.f, 0.f, 0.f};

  const float* Kb = K + (size_t)b * NN * DDIM + h * 16;
  const float* Vb = V + (size_t)b * NN * DDIM + h * 16;
  const int dv = min(l31, 15);

#pragma unroll 1
  for (int nt = 0; nt < 4; ++nt) {
    const int nb = n0 + nt * 32;

    bf16x8 khi, klo;
    {
      const int krow = min(nb + l31, NN - 1);
      split8(Kb + (size_t)krow * DDIM + hi * 8, khi, klo);
    }
    bf16x8 vhi[2], vlo[2];
#pragma unroll
    for (int ks = 0; ks < 2; ++ks) {
      float vt[8];
#pragma unroll
      for (int i = 0; i < 8; ++i) {
        const int vrow = min(nb + ks * 16 + hi * 8 + i, NN - 1);
        vt[i] = Vb[(size_t)vrow * DDIM + dv];
      }
      unsigned vh[4], vl[4];
#pragma unroll
      for (int j = 0; j < 4; ++j) {
        const unsigned h0 = bf16rne(vt[2*j]), h1 = bf16rne(vt[2*j+1]);
        vh[j] = h0 | (h1 << 16);
        vl[j] = bf16rne(vt[2*j]   - __uint_as_float(h0 << 16)) |
                (bf16rne(vt[2*j+1] - __uint_as_float(h1 << 16)) << 16);
      }
      vhi[ks] = __builtin_bit_cast(bf16x8, u32x4{vh[0], vh[1], vh[2], vh[3]});
      vlo[ks] = __builtin_bit_cast(bf16x8, u32x4{vl[0], vl[1], vl[2], vl[3]});
    }

#pragma unroll
    for (int pt = 0; pt < 4; ++pt) {
      f32x16 s;
#pragma unroll
      for (int i = 0; i < 16; ++i) s[i] = 0.f;
      s = __builtin_amdgcn_mfma_f32_32x32x16_bf16(khi, qhi[pt], s, 0, 0, 0);
      s = __builtin_amdgcn_mfma_f32_32x32x16_bf16(khi, qlo[pt], s, 0, 0, 0);
      s = __builtin_amdgcn_mfma_f32_32x32x16_bf16(klo, qhi[pt], s, 0, 0, 0);

      const int prow = min(pt * 32 + l31, PP - 1);
      float mq[16];
#pragma unroll
      for (int q = 0; q < 4; ++q) {
        const float4 f =
            *(const float4*)&mask_lds[prow * 132 + nt * 32 + q * 8 + hi * 4];
        mq[4*q+0] = f.x; mq[4*q+1] = f.y; mq[4*q+2] = f.z; mq[4*q+3] = f.w;
      }
      float e[16], elo[16];
      unsigned ehw[16];
#pragma unroll
      for (int r = 0; r < 16; ++r) {
        const int n_abs = nb + (r & 3) + 8 * (r >> 2) + 4 * hi;
        float ev = __expf(s[r] + mq[r]);
        ev = (n_abs < NN) ? ev : 0.f;
        e[r] = ev;
        lacc[pt] += ev;
        ehw[r] = bf16rne(ev);
        elo[r] = ev - __uint_as_float(ehw[r] << 16);
      }
#pragma unroll
      for (int ks = 0; ks < 2; ++ks) {
        const int rb = ks * 8;
        const unsigned t01h = ehw[rb+0] | (ehw[rb+1] << 16);
        const unsigned t23h = ehw[rb+2] | (ehw[rb+3] << 16);
        const unsigned t45h = ehw[rb+4] | (ehw[rb+5] << 16);
        const unsigned t67h = ehw[rb+6] | (ehw[rb+7] << 16);
        const unsigned t01l = pk_bf16(elo[rb+0], elo[rb+1]);
        const unsigned t23l = pk_bf16(elo[rb+2], elo[rb+3]);
        const unsigned t45l = pk_bf16(elo[rb+4], elo[rb+5]);
        const unsigned t67l = pk_bf16(elo[rb+6], elo[rb+7]);
        const unsigned s01h = (unsigned)__shfl_xor((int)t01h, 32, 64);
        const unsigned s23h = (unsigned)__shfl_xor((int)t23h, 32, 64);
        const unsigned s45h = (unsigned)__shfl_xor((int)t45h, 32, 64);
        const unsigned s67h = (unsigned)__shfl_xor((int)t67h, 32, 64);
        const unsigned s01l = (unsigned)__shfl_xor((int)t01l, 32, 64);
        const unsigned s23l = (unsigned)__shfl_xor((int)t23l, 32, 64);
        const unsigned s45l = (unsigned)__shfl_xor((int)t45l, 32, 64);
        const unsigned s67l = (unsigned)__shfl_xor((int)t67l, 32, 64);
        const bf16x8 pah = __builtin_bit_cast(bf16x8, u32x4{
            hi ? s45h : t01h, hi ? s67h : t23h,
            hi ? t45h : s01h, hi ? t67h : s23h});
        const bf16x8 pal = __builtin_bit_cast(bf16x8, u32x4{
            hi ? s45l : t01l, hi ? s67l : t23l,
            hi ? t45l : s01l, hi ? t67l : s23l});
        oacc[pt] = __builtin_amdgcn_mfma_f32_32x32x16_bf16(pah, vhi[ks], oacc[pt], 0, 0, 0);
        oacc[pt] = __builtin_amdgcn_mfma_f32_32x32x16_bf16(pah, vlo[ks], oacc[pt], 0, 0, 0);
        oacc[pt] = __builtin_amdgcn_mfma_f32_32x32x16_bf16(pal, vhi[ks], oacc[pt], 0, 0, 0);
      }
    }
  }

  const int base = (b * NSPL + chunk) * PP;
#pragma unroll
  for (int pt = 0; pt < 4; ++pt) {
    const float ltot = lacc[pt] + __shfl_xor(lacc[pt], 32, 64);
    const int pl = pt * 32 + l31;
    if (l < 32 && pl < PP)
      lsum[(size_t)(base + pl) * HH + h] = ltot;
#pragma unroll
    for (int r = 0; r < 16; ++r) {
      const int p = pt * 32 + (r & 3) + 8 * (r >> 2) + 4 * hi;
      if (l31 < 16 && p < PP)
        po[(size_t)(base + p) * DDIM + h * 16 + l31] = oacc[pt][r];
    }
  }
}

// ---------------------------------------------------------------------------
// merge: mh_in[b][p][d] = (sum_s po) / (sum_s lsum[h(d)])  (unchanged)
// ---------------------------------------------------------------------------
__global__ __launch_bounds__(256) void merge_kernel(
    const float* __restrict__ po, const float* __restrict__ lsum,
    float* __restrict__ mh_in)
{
  const int idx = blockIdx.x * 256 + threadIdx.x;   // over BB*PP*DDIM
  const int d = idx & 127;
  const int row = idx >> 7;        // b*PP + p
  const int b = row / PP;
  const int p = row - b * PP;
  const int h = d >> 4;
  float s = 0.f, lt = 0.f;
#pragma unroll
  for (int sp = 0; sp < NSPL; ++sp) {
    const int base = (b * NSPL + sp) * PP + p;
    s  += po[base * DDIM + d];
    lt += lsum[base * HH + h];
  }
  mh_in[idx] = s / lt;
}

// ---------------------------------------------------------------------------
// score2 via MFMA 32x32x16 split-bf16 + fused epilogue. (unchanged, r6)
// ---------------------------------------------------------------------------
__global__ __launch_bounds__(256) void score2_mfma_kernel(
    const float* __restrict__ enc, const float* __restrict__ mh,
    const float* __restrict__ mask, const float* __restrict__ bias_table,
    const int* __restrict__ group_ids, const int* __restrict__ cur_min,
    float* __restrict__ out, float* __restrict__ ssum)
{
  const int b   = blockIdx.x >> 4;
  const int nc  = blockIdx.x & 15;
  const int n0  = nc * 64;
  const int tid = threadIdx.x;
  const int lane = tid & 63;
  const int mt   = tid >> 6;
  const int half = lane >> 5;
  const int l31  = lane & 31;

  f32x16 acc[2];
#pragma unroll
  for (int c = 0; c < 2; ++c)
#pragma unroll
    for (int i = 0; i < 16; ++i) acc[c][i] = 0.f;

  const float* mha = mh + ((size_t)(b * PP + 32 * mt + l31)) * DDIM + half * 8;
  const float* encb = enc + (size_t)b * NN * DDIM + half * 8;
  const int nsrc0 = min(n0 + l31, NN - 1);
  const int nsrc1 = min(n0 + 32 + l31, NN - 1);

#pragma unroll 1
  for (int ks = 0; ks < 8; ++ks) {
    bf16x8 ahi, alo;
    split8(mha + ks * 16, ahi, alo);
    bf16x8 bhi0, blo0, bhi1, blo1;
    split8(encb + (size_t)nsrc0 * DDIM + ks * 16, bhi0, blo0);
    split8(encb + (size_t)nsrc1 * DDIM + ks * 16, bhi1, blo1);
    acc[0] = __builtin_amdgcn_mfma_f32_32x32x16_bf16(ahi, bhi0, acc[0], 0, 0, 0);
    acc[0] = __builtin_amdgcn_mfma_f32_32x32x16_bf16(ahi, blo0, acc[0], 0, 0, 0);
    acc[0] = __builtin_amdgcn_mfma_f32_32x32x16_bf16(alo, bhi0, acc[0], 0, 0, 0);
    acc[1] = __builtin_amdgcn_mfma_f32_32x32x16_bf16(ahi, bhi1, acc[1], 0, 0, 0);
    acc[1] = __builtin_amdgcn_mfma_f32_32x32x16_bf16(ahi, blo1, acc[1], 0, 0, 0);
    acc[1] = __builtin_amdgcn_mfma_f32_32x32x16_bf16(alo, bhi1, acc[1], 0, 0, 0);
  }

  const float t0 = bias_table[0], t1 = bias_table[1], t2 = bias_table[2],
              t3 = bias_table[3], t4 = bias_table[4];
  const float two_inv_sqrt_emb = 0.1767766952966369f;  // 2/sqrt(128)

  float rsum[16];
#pragma unroll
  for (int r = 0; r < 16; ++r) rsum[r] = 0.f;

#pragma unroll
  for (int ct = 0; ct < 2; ++ct) {
    const int n = n0 + ct * 32 + l31;
    const bool nvalid = n < NN;
    const int nr = nvalid ? n : NN - 1;
    const int gid = group_ids[b * NN + nr];
#pragma unroll
    for (int r = 0; r < 16; ++r) {
      const int p = 32 * mt + (r & 3) + 8 * (r >> 2) + 4 * half;
      const bool pvalid = p < PP;
      const int pr = pvalid ? p : PP - 1;
      const float m = mask[((size_t)(b * PP + pr)) * NN + nr];
      const float ex = __expf(acc[ct][r] * two_inv_sqrt_emb);
      const float sc = 10.0f - 20.0f / (ex + 1.0f);
      const int cmp = cur_min[b * PP + pr];
      int delta = gid - cmp;
      delta = delta < 0 ? 0 : (delta > 4 ? 4 : delta);
      const float pb = (delta == 0) ? t0 : (delta == 1) ? t1 : (delta == 2) ? t2
                     : (delta == 3) ? t3 : t4;
      float e = (nvalid && pvalid) ? __expf(sc + pb + m) : 0.0f;
      if (nvalid && pvalid) out[((size_t)(b * PP + p)) * NN + n] = e;
      float ws = e;
#pragma unroll
      for (int off = 1; off < 32; off <<= 1) ws += __shfl_xor(ws, off, 64);
      rsum[r] += ws;
    }
  }
  if (l31 == 0) {
#pragma unroll
    for (int r = 0; r < 16; ++r) {
      const int p = 32 * mt + (r & 3) + 8 * (r >> 2) + 4 * half;
      if (p < PP) ssum[(size_t)(b * PP + p) * 16 + nc] = rsum[r];
    }
  }
}

// ---------------------------------------------------------------------------
// normalize: out[row][n] /= sum of 16 chunk partials  (unchanged)
// ---------------------------------------------------------------------------
__global__ __launch_bounds__(256) void norm_kernel(
    const float* __restrict__ ssum, float* __restrict__ out)
{
  const int row = blockIdx.x;   // b*PP + p
  float s = 0.f;
#pragma unroll
  for (int i = 0; i < 16; ++i) s += ssum[(size_t)row * 16 + i];
  const float inv = 1.0f / s;
#pragma unroll
  for (int i = 0; i < 4; ++i) {
    const int c = i * 256 + (int)threadIdx.x;
    if (c < NN) out[(size_t)row * NN + c] *= inv;
  }
}

// ---------------------------------------------------------------------------
extern "C" void kernel_launch(void* const* d_in, const int* in_sizes, int n_in,
                              void* d_out, int out_size, void* d_ws, size_t ws_size,
                              hipStream_t stream)
{
  (void)in_sizes; (void)n_in; (void)out_size; (void)ws_size;
  const float* enc_nodes  = (const float*)d_in[0];
  const float* enc_q1     = (const float*)d_in[1];
  const float* enc_last   = (const float*)d_in[2];
  const float* ninf       = (const float*)d_in[3];
  const float* Wq_first   = (const float*)d_in[4];
  const float* Wq_last    = (const float*)d_in[5];
  const float* Wk         = (const float*)d_in[6];
  const float* Wv         = (const float*)d_in[7];
  const float* W_comb     = (const float*)d_in[8];
  const float* b_comb     = (const float*)d_in[9];
  const float* bias_table = (const float*)d_in[10];
  const int*   group_ids  = (const int*)d_in[11];
  const int*   cur_min    = (const int*)d_in[12];
  float* out = (float*)d_out;
  float* ws  = (float*)d_ws;

  float* Qw = ws;                    //   819200 floats (reused as mh_in after attn)
  float* Kw = Qw + 819200;           //  8192000
  float* Vw = Kw + 8192000;          //  8192000
  float* po = Vw + 8192000;          //  6553600  (BB*NSPL*PP*DDIM)
  float* ls = po + 6553600;          //   409600  (BB*NSPL*PP*HH)
  float* mh = ls + 409600;           //   819200
  float* sm = mh + 819200;           //   102400  (BB*PP*16)

  // wfrag (320 KB, 5 matrices) aliases sm: wfrag is consumed by the proj
  // kernels (steps 2,3,6); sm is first written by score2 (step 7) -- safe.
  // (Previously aliased po, but attn (step 4) writes po before the combine
  //  proj (step 6) reads W_comb fragments.)
  u32x4* wfrag = (u32x4*)sm;

  // pack all 5 weight matrices into split-bf16 MFMA fragments
  pack_w_kernel<<<40, 256, 0, stream>>>(Wk, Wv, Wq_first, Wq_last, W_comb, wfrag);
  // Q = (q1@Wq_first + last@Wq_last) * 0.25 via MFMA (fold 1/sqrt(QD))
  proj_q2_mfma_kernel<<<BB*PP/128, 256, 0, stream>>>(enc_q1, enc_last, wfrag,
                                                     Qw, 0.25f);
  // K, V projections via split-bf16 MFMA
  proj_kv_mfma_kernel<<<BB*NN/128, 256, 0, stream>>>(enc_nodes, wfrag, Kw, Vw);
  // attention partials via MFMA (QK^T and PV on the matrix pipe)
  attn_mfma_kernel<<<BB*NSPL, 512, 0, stream>>>(Qw, Kw, Vw, ninf, po, ls);
  // merge partials -> mh_in (reuses Qw)
  merge_kernel<<<3200, 256, 0, stream>>>(po, ls, Qw);
  // combine: mh = mh_in @ W_comb + b_comb via MFMA
  proj_comb_mfma_kernel<<<BB*PP/128, 256, 0, stream>>>(Qw, wfrag, b_comb, mh);
  // final scores via MFMA + fused epilogue
  score2_mfma_kernel<<<BB*16, 256, 0, stream>>>(enc_nodes, mh, ninf, bias_table,
                                                group_ids, cur_min, out, sm);
  // normalize
  norm_kernel<<<BB*PP, 256, 0, stream>>>(sm, out);
}

// Round 11
// 182.177 us; speedup vs baseline: 2.5260x; 1.0891x over previous
//
#include <hip/hip_runtime.h>

#define BB 64
#define PP 100
#define NN 1000
#define DDIM 128
#define HH 8
#define NSPL 8

typedef __attribute__((ext_vector_type(8))) short bf16x8;   // 8 bf16 = 4 VGPRs
typedef __attribute__((ext_vector_type(16))) float f32x16;  // MFMA 32x32 acc
typedef __attribute__((ext_vector_type(4))) unsigned u32x4;

__device__ __forceinline__ unsigned bf16rne(float x) {
  unsigned u = __float_as_uint(x);
  return (u + 0x7FFFu + ((u >> 16) & 1u)) >> 16;
}
// packed bf16 pair (integer-only; round-10's __hip_bfloat162 bit_cast does
// not compile -- "source type must be trivially copyable")
__device__ __forceinline__ unsigned pk_bf16(float a, float b) {
  return bf16rne(a) | (bf16rne(b) << 16);
}

// split 8 contiguous floats into hi/lo bf16x8 fragments
__device__ __forceinline__ void split8(const float* __restrict__ p,
                                       bf16x8& hi8, bf16x8& lo8) {
  const float4 a = *(const float4*)p;
  const float4 c = *(const float4*)(p + 4);
  float v[8] = {a.x, a.y, a.z, a.w, c.x, c.y, c.z, c.w};
  unsigned hw[4], lw[4];
#pragma unroll
  for (int j = 0; j < 4; ++j) {
    const unsigned h0 = bf16rne(v[2*j]), h1 = bf16rne(v[2*j+1]);
    hw[j] = h0 | (h1 << 16);
    lw[j] = bf16rne(v[2*j]   - __uint_as_float(h0 << 16)) |
            (bf16rne(v[2*j+1] - __uint_as_float(h1 << 16)) << 16);
  }
  hi8 = __builtin_bit_cast(bf16x8, u32x4{hw[0], hw[1], hw[2], hw[3]});
  lo8 = __builtin_bit_cast(bf16x8, u32x4{lw[0], lw[1], lw[2], lw[3]});
}

// ---------------------------------------------------------------------------
// pack 5 weight matrices (fp32 128x128) -> MFMA B-fragment layout, split
// hi/lo bf16. mat: 0=Wk 1=Wv 2=Wq_first 3=Wq_last 4=W_comb. (unchanged)
// ---------------------------------------------------------------------------
__global__ __launch_bounds__(256) void pack_w_kernel(
    const float* __restrict__ W0, const float* __restrict__ W1,
    const float* __restrict__ W2, const float* __restrict__ W3,
    const float* __restrict__ W4, u32x4* __restrict__ wfrag)
{
  const int gid = blockIdx.x * 256 + threadIdx.x;  // [0, 10240)
  const int mat = gid >> 11;
  const int ct = (gid >> 9) & 3;
  const int ks = (gid >> 6) & 7;
  const int lane = gid & 63;
  const float* __restrict__ W =
      (mat == 0) ? W0 : (mat == 1) ? W1 : (mat == 2) ? W2 : (mat == 3) ? W3 : W4;
  const int col = ct * 32 + (lane & 31);
  const int k0 = ks * 16 + (lane >> 5) * 8;
  unsigned hi[4], lo[4];
#pragma unroll
  for (int j = 0; j < 4; ++j) {
    const float x0 = W[(k0 + 2 * j) * DDIM + col];
    const float x1 = W[(k0 + 2 * j + 1) * DDIM + col];
    const unsigned h0 = bf16rne(x0), h1 = bf16rne(x1);
    hi[j] = h0 | (h1 << 16);
    lo[j] = bf16rne(x0 - __uint_as_float(h0 << 16)) |
            (bf16rne(x1 - __uint_as_float(h1 << 16)) << 16);
  }
  const int base = (((mat * 4 + ct) * 8 + ks) * 2) * 64 + lane;
  wfrag[base]      = u32x4{hi[0], hi[1], hi[2], hi[3]};
  wfrag[base + 64] = u32x4{lo[0], lo[1], lo[2], lo[3]};
}

// ---------------------------------------------------------------------------
// K+V projection via MFMA 32x32x16 bf16, split-precision. (unchanged, r5)
// ---------------------------------------------------------------------------
__global__ __launch_bounds__(256) void proj_kv_mfma_kernel(
    const float* __restrict__ x, const u32x4* __restrict__ wfrag,
    float* __restrict__ outk, float* __restrict__ outv)
{
  const int tid = threadIdx.x;
  const int lane = tid & 63;
  const int wid = tid >> 6;
  const int rtp = wid >> 1;
  const int ctp = wid & 1;
  const int arow = blockIdx.x * 128 + rtp * 64 + (lane & 31);
  const int kgrp = (lane >> 5) * 8;

#pragma unroll 1
  for (int mat = 0; mat < 2; ++mat) {
    float* __restrict__ out = mat ? outv : outk;
    f32x16 acc[2][2];
#pragma unroll
    for (int a = 0; a < 2; ++a)
#pragma unroll
      for (int b = 0; b < 2; ++b)
#pragma unroll
        for (int i = 0; i < 16; ++i) acc[a][b][i] = 0.f;

#pragma unroll 1
    for (int ks = 0; ks < 8; ++ks) {
      bf16x8 ahi[2], alo[2];
#pragma unroll
      for (int rt = 0; rt < 2; ++rt) {
        const float* xp = x + (size_t)(arow + rt * 32) * DDIM + ks * 16 + kgrp;
        split8(xp, ahi[rt], alo[rt]);
      }
#pragma unroll
      for (int ct = 0; ct < 2; ++ct) {
        const int c = ctp * 2 + ct;
        const int fo = (((mat * 4 + c) * 8 + ks) * 2) * 64 + lane;
        const bf16x8 bhi = __builtin_bit_cast(bf16x8, wfrag[fo]);
        const bf16x8 blo = __builtin_bit_cast(bf16x8, wfrag[fo + 64]);
#pragma unroll
        for (int rt = 0; rt < 2; ++rt) {
          acc[rt][ct] = __builtin_amdgcn_mfma_f32_32x32x16_bf16(
              ahi[rt], bhi, acc[rt][ct], 0, 0, 0);
          acc[rt][ct] = __builtin_amdgcn_mfma_f32_32x32x16_bf16(
              ahi[rt], blo, acc[rt][ct], 0, 0, 0);
          acc[rt][ct] = __builtin_amdgcn_mfma_f32_32x32x16_bf16(
              alo[rt], bhi, acc[rt][ct], 0, 0, 0);
        }
      }
    }
#pragma unroll
    for (int rt = 0; rt < 2; ++rt)
#pragma unroll
      for (int ct = 0; ct < 2; ++ct) {
        const int colg = ctp * 64 + ct * 32 + (lane & 31);
        const int rowg0 = blockIdx.x * 128 + rtp * 64 + rt * 32 + 4 * (lane >> 5);
#pragma unroll
        for (int r = 0; r < 16; ++r) {
          const int rowg = rowg0 + (r & 3) + 8 * (r >> 2);
          out[(size_t)rowg * DDIM + colg] = acc[rt][ct][r];
        }
      }
  }
}

// ---------------------------------------------------------------------------
// Q projection via MFMA: out = (x1@Wq_first + x2@Wq_last) * scale. (r9)
// ---------------------------------------------------------------------------
__global__ __launch_bounds__(256) void proj_q2_mfma_kernel(
    const float* __restrict__ x1, const float* __restrict__ x2,
    const u32x4* __restrict__ wfrag, float* __restrict__ out, float scale)
{
  const int tid = threadIdx.x;
  const int lane = tid & 63;
  const int w = tid >> 6;
  const int hi = lane >> 5;
  const int l31 = lane & 31;
  const int row0 = blockIdx.x * 128 + w * 32;
  const float* xr1 = x1 + (size_t)(row0 + l31) * DDIM + hi * 8;
  const float* xr2 = x2 + (size_t)(row0 + l31) * DDIM + hi * 8;

  f32x16 acc[4];
#pragma unroll
  for (int ct = 0; ct < 4; ++ct)
#pragma unroll
    for (int i = 0; i < 16; ++i) acc[ct][i] = 0.f;

#pragma unroll 1
  for (int ks = 0; ks < 8; ++ks) {
    bf16x8 a1h, a1l, a2h, a2l;
    split8(xr1 + ks * 16, a1h, a1l);
    split8(xr2 + ks * 16, a2h, a2l);
#pragma unroll
    for (int ct = 0; ct < 4; ++ct) {
      const int fo1 = (((2 * 4 + ct) * 8 + ks) * 2) * 64 + lane;  // Wq_first
      const bf16x8 b1h = __builtin_bit_cast(bf16x8, wfrag[fo1]);
      const bf16x8 b1l = __builtin_bit_cast(bf16x8, wfrag[fo1 + 64]);
      acc[ct] = __builtin_amdgcn_mfma_f32_32x32x16_bf16(a1h, b1h, acc[ct], 0, 0, 0);
      acc[ct] = __builtin_amdgcn_mfma_f32_32x32x16_bf16(a1h, b1l, acc[ct], 0, 0, 0);
      acc[ct] = __builtin_amdgcn_mfma_f32_32x32x16_bf16(a1l, b1h, acc[ct], 0, 0, 0);
      const int fo2 = (((3 * 4 + ct) * 8 + ks) * 2) * 64 + lane;  // Wq_last
      const bf16x8 b2h = __builtin_bit_cast(bf16x8, wfrag[fo2]);
      const bf16x8 b2l = __builtin_bit_cast(bf16x8, wfrag[fo2 + 64]);
      acc[ct] = __builtin_amdgcn_mfma_f32_32x32x16_bf16(a2h, b2h, acc[ct], 0, 0, 0);
      acc[ct] = __builtin_amdgcn_mfma_f32_32x32x16_bf16(a2h, b2l, acc[ct], 0, 0, 0);
      acc[ct] = __builtin_amdgcn_mfma_f32_32x32x16_bf16(a2l, b2h, acc[ct], 0, 0, 0);
    }
  }
#pragma unroll
  for (int ct = 0; ct < 4; ++ct) {
    const int colg = ct * 32 + l31;
    const int rowg0 = row0 + 4 * hi;
#pragma unroll
    for (int r = 0; r < 16; ++r) {
      const int rowg = rowg0 + (r & 3) + 8 * (r >> 2);
      out[(size_t)rowg * DDIM + colg] = acc[ct][r] * scale;
    }
  }
}

// ---------------------------------------------------------------------------
// Combine projection via MFMA: out = x@W_comb + bias. (r9)
// ---------------------------------------------------------------------------
__global__ __launch_bounds__(256) void proj_comb_mfma_kernel(
    const float* __restrict__ x, const u32x4* __restrict__ wfrag,
    const float* __restrict__ bias, float* __restrict__ out)
{
  const int tid = threadIdx.x;
  const int lane = tid & 63;
  const int w = tid >> 6;
  const int hi = lane >> 5;
  const int l31 = lane & 31;
  const int row0 = blockIdx.x * 128 + w * 32;
  const float* xr = x + (size_t)(row0 + l31) * DDIM + hi * 8;

  f32x16 acc[4];
#pragma unroll
  for (int ct = 0; ct < 4; ++ct)
#pragma unroll
    for (int i = 0; i < 16; ++i) acc[ct][i] = 0.f;

#pragma unroll 1
  for (int ks = 0; ks < 8; ++ks) {
    bf16x8 ah, al;
    split8(xr + ks * 16, ah, al);
#pragma unroll
    for (int ct = 0; ct < 4; ++ct) {
      const int fo = (((4 * 4 + ct) * 8 + ks) * 2) * 64 + lane;  // W_comb
      const bf16x8 bh = __builtin_bit_cast(bf16x8, wfrag[fo]);
      const bf16x8 bl = __builtin_bit_cast(bf16x8, wfrag[fo + 64]);
      acc[ct] = __builtin_amdgcn_mfma_f32_32x32x16_bf16(ah, bh, acc[ct], 0, 0, 0);
      acc[ct] = __builtin_amdgcn_mfma_f32_32x32x16_bf16(ah, bl, acc[ct], 0, 0, 0);
      acc[ct] = __builtin_amdgcn_mfma_f32_32x32x16_bf16(al, bh, acc[ct], 0, 0, 0);
    }
  }
#pragma unroll
  for (int ct = 0; ct < 4; ++ct) {
    const int colg = ct * 32 + l31;
    const float bj = bias[colg];
    const int rowg0 = row0 + 4 * hi;
#pragma unroll
    for (int r = 0; r < 16; ++r) {
      const int rowg = rowg0 + (r & 3) + 8 * (r >> 2);
      out[(size_t)rowg * DDIM + colg] = acc[ct][r] + bj;
    }
  }
}

// ---------------------------------------------------------------------------
// MFMA attention, round-11 (= round-10 intent, compile-fixed): P single-bf16
// -- drop the pal/elo split path (round-9 epilogue was ~270 VALU
// instr/(nt,pt), 60% of it P-lo bookkeeping; bf16 P adds ~0.2% rel weight
// error, normalization-protected). QK^T stays 3-term split (feeds exp), V
// stays split. MFMA/(nt,pt): 9 -> 7; VALU: ~270 -> ~120.
// ---------------------------------------------------------------------------
__global__ __launch_bounds__(512) void attn_mfma_kernel(
    const float* __restrict__ Q, const float* __restrict__ K,
    const float* __restrict__ V, const float* __restrict__ mask,
    float* __restrict__ po, float* __restrict__ lsum)
{
  __shared__ float mask_lds[PP * 132];   // [p][n-chunk], pad 132 for banks

  const int b = blockIdx.x >> 3;
  const int chunk = blockIdx.x & 7;
  const int n0 = chunk * 128;
  const int tid = threadIdx.x;
  const int h = tid >> 6;          // wave = head
  const int l = tid & 63;
  const int hi = l >> 5;
  const int l31 = l & 31;

  for (int idx = tid; idx < PP * 32; idx += 512) {
    const int p = idx >> 5;
    const int c = idx & 31;
    const int nsrc = min(n0 + 4 * c, NN - 4);
    *(float4*)&mask_lds[p * 132 + 4 * c] =
        *(const float4*)(mask + ((size_t)(b * PP + p)) * NN + nsrc);
  }
  __syncthreads();

  bf16x8 qhi[4], qlo[4];
#pragma unroll
  for (int pt = 0; pt < 4; ++pt) {
    const int qrow = min(b * PP + pt * 32 + l31, BB * PP - 1);
    split8(Q + (size_t)qrow * DDIM + h * 16 + hi * 8, qhi[pt], qlo[pt]);
  }

  f32x16 oacc[4];
#pragma unroll
  for (int pt = 0; pt < 4; ++pt)
#pragma unroll
    for (int i = 0; i < 16; ++i) oacc[pt][i] = 0.f;
  float lacc[4] = {0.f, 0.f, 0.f, 0.f};

  const float* Kb = K + (size_t)b * NN * DDIM + h * 16;
  const float* Vb = V + (size_t)b * NN * DDIM + h * 16;
  const int dv = min(l31, 15);

#pragma unroll 1
  for (int nt = 0; nt < 4; ++nt) {
    const int nb = n0 + nt * 32;

    bf16x8 khi, klo;
    {
      const int krow = min(nb + l31, NN - 1);
      split8(Kb + (size_t)krow * DDIM + hi * 8, khi, klo);
    }
    bf16x8 vhi[2], vlo[2];
#pragma unroll
    for (int ks = 0; ks < 2; ++ks) {
      float vt[8];
#pragma unroll
      for (int i = 0; i < 8; ++i) {
        const int vrow = min(nb + ks * 16 + hi * 8 + i, NN - 1);
        vt[i] = Vb[(size_t)vrow * DDIM + dv];
      }
      unsigned vh[4], vl[4];
#pragma unroll
      for (int j = 0; j < 4; ++j) {
        const unsigned h0 = bf16rne(vt[2*j]), h1 = bf16rne(vt[2*j+1]);
        vh[j] = h0 | (h1 << 16);
        vl[j] = bf16rne(vt[2*j]   - __uint_as_float(h0 << 16)) |
                (bf16rne(vt[2*j+1] - __uint_as_float(h1 << 16)) << 16);
      }
      vhi[ks] = __builtin_bit_cast(bf16x8, u32x4{vh[0], vh[1], vh[2], vh[3]});
      vlo[ks] = __builtin_bit_cast(bf16x8, u32x4{vl[0], vl[1], vl[2], vl[3]});
    }

#pragma unroll
    for (int pt = 0; pt < 4; ++pt) {
      f32x16 s;
#pragma unroll
      for (int i = 0; i < 16; ++i) s[i] = 0.f;
      s = __builtin_amdgcn_mfma_f32_32x32x16_bf16(khi, qhi[pt], s, 0, 0, 0);
      s = __builtin_amdgcn_mfma_f32_32x32x16_bf16(khi, qlo[pt], s, 0, 0, 0);
      s = __builtin_amdgcn_mfma_f32_32x32x16_bf16(klo, qhi[pt], s, 0, 0, 0);

      const int prow = min(pt * 32 + l31, PP - 1);
      float mq[16];
#pragma unroll
      for (int q = 0; q < 4; ++q) {
        const float4 f =
            *(const float4*)&mask_lds[prow * 132 + nt * 32 + q * 8 + hi * 4];
        mq[4*q+0] = f.x; mq[4*q+1] = f.y; mq[4*q+2] = f.z; mq[4*q+3] = f.w;
      }
      // exp + pad-kill + lsum; P packed to bf16 pairs (single precision)
      float ev[16];
#pragma unroll
      for (int r = 0; r < 16; ++r) {
        const int n_abs = nb + (r & 3) + 8 * (r >> 2) + 4 * hi;
        float e = __expf(s[r] + mq[r]);
        e = (n_abs < NN) ? e : 0.f;
        ev[r] = e;
        lacc[pt] += e;
      }
      unsigned u[8];
#pragma unroll
      for (int j = 0; j < 8; ++j) u[j] = pk_bf16(ev[2*j], ev[2*j+1]);
      // route C-layout P -> A-frag (half-wave exchange), per 16-n ks
#pragma unroll
      for (int ks = 0; ks < 2; ++ks) {
        const unsigned t01 = u[ks*4+0], t23 = u[ks*4+1];
        const unsigned t45 = u[ks*4+2], t67 = u[ks*4+3];
        const unsigned s01 = (unsigned)__shfl_xor((int)t01, 32, 64);
        const unsigned s23 = (unsigned)__shfl_xor((int)t23, 32, 64);
        const unsigned s45 = (unsigned)__shfl_xor((int)t45, 32, 64);
        const unsigned s67 = (unsigned)__shfl_xor((int)t67, 32, 64);
        const bf16x8 pah = __builtin_bit_cast(bf16x8, u32x4{
            hi ? s45 : t01, hi ? s67 : t23,
            hi ? t45 : s01, hi ? t67 : s23});
        oacc[pt] = __builtin_amdgcn_mfma_f32_32x32x16_bf16(pah, vhi[ks], oacc[pt], 0, 0, 0);
        oacc[pt] = __builtin_amdgcn_mfma_f32_32x32x16_bf16(pah, vlo[ks], oacc[pt], 0, 0, 0);
      }
    }
  }

  const int base = (b * NSPL + chunk) * PP;
#pragma unroll
  for (int pt = 0; pt < 4; ++pt) {
    const float ltot = lacc[pt] + __shfl_xor(lacc[pt], 32, 64);
    const int pl = pt * 32 + l31;
    if (l < 32 && pl < PP)
      lsum[(size_t)(base + pl) * HH + h] = ltot;
#pragma unroll
    for (int r = 0; r < 16; ++r) {
      const int p = pt * 32 + (r & 3) + 8 * (r >> 2) + 4 * hi;
      if (l31 < 16 && p < PP)
        po[(size_t)(base + p) * DDIM + h * 16 + l31] = oacc[pt][r];
    }
  }
}

// ---------------------------------------------------------------------------
// merge: mh_in[b][p][d] = (sum_s po) / (sum_s lsum[h(d)])  (unchanged)
// ---------------------------------------------------------------------------
__global__ __launch_bounds__(256) void merge_kernel(
    const float* __restrict__ po, const float* __restrict__ lsum,
    float* __restrict__ mh_in)
{
  const int idx = blockIdx.x * 256 + threadIdx.x;   // over BB*PP*DDIM
  const int d = idx & 127;
  const int row = idx >> 7;        // b*PP + p
  const int b = row / PP;
  const int p = row - b * PP;
  const int h = d >> 4;
  float s = 0.f, lt = 0.f;
#pragma unroll
  for (int sp = 0; sp < NSPL; ++sp) {
    const int base = (b * NSPL + sp) * PP + p;
    s  += po[base * DDIM + d];
    lt += lsum[base * HH + h];
  }
  mh_in[idx] = s / lt;
}

// ---------------------------------------------------------------------------
// score2 via MFMA 32x32x16 split-bf16 + fused epilogue. (unchanged, r6)
// ---------------------------------------------------------------------------
__global__ __launch_bounds__(256) void score2_mfma_kernel(
    const float* __restrict__ enc, const float* __restrict__ mh,
    const float* __restrict__ mask, const float* __restrict__ bias_table,
    const int* __restrict__ group_ids, const int* __restrict__ cur_min,
    float* __restrict__ out, float* __restrict__ ssum)
{
  const int b   = blockIdx.x >> 4;
  const int nc  = blockIdx.x & 15;
  const int n0  = nc * 64;
  const int tid = threadIdx.x;
  const int lane = tid & 63;
  const int mt   = tid >> 6;
  const int half = lane >> 5;
  const int l31  = lane & 31;

  f32x16 acc[2];
#pragma unroll
  for (int c = 0; c < 2; ++c)
#pragma unroll
    for (int i = 0; i < 16; ++i) acc[c][i] = 0.f;

  const float* mha = mh + ((size_t)(b * PP + 32 * mt + l31)) * DDIM + half * 8;
  const float* encb = enc + (size_t)b * NN * DDIM + half * 8;
  const int nsrc0 = min(n0 + l31, NN - 1);
  const int nsrc1 = min(n0 + 32 + l31, NN - 1);

#pragma unroll 1
  for (int ks = 0; ks < 8; ++ks) {
    bf16x8 ahi, alo;
    split8(mha + ks * 16, ahi, alo);
    bf16x8 bhi0, blo0, bhi1, blo1;
    split8(encb + (size_t)nsrc0 * DDIM + ks * 16, bhi0, blo0);
    split8(encb + (size_t)nsrc1 * DDIM + ks * 16, bhi1, blo1);
    acc[0] = __builtin_amdgcn_mfma_f32_32x32x16_bf16(ahi, bhi0, acc[0], 0, 0, 0);
    acc[0] = __builtin_amdgcn_mfma_f32_32x32x16_bf16(ahi, blo0, acc[0], 0, 0, 0);
    acc[0] = __builtin_amdgcn_mfma_f32_32x32x16_bf16(alo, bhi0, acc[0], 0, 0, 0);
    acc[1] = __builtin_amdgcn_mfma_f32_32x32x16_bf16(ahi, bhi1, acc[1], 0, 0, 0);
    acc[1] = __builtin_amdgcn_mfma_f32_32x32x16_bf16(ahi, blo1, acc[1], 0, 0, 0);
    acc[1] = __builtin_amdgcn_mfma_f32_32x32x16_bf16(alo, bhi1, acc[1], 0, 0, 0);
  }

  const float t0 = bias_table[0], t1 = bias_table[1], t2 = bias_table[2],
              t3 = bias_table[3], t4 = bias_table[4];
  const float two_inv_sqrt_emb = 0.1767766952966369f;  // 2/sqrt(128)

  float rsum[16];
#pragma unroll
  for (int r = 0; r < 16; ++r) rsum[r] = 0.f;

#pragma unroll
  for (int ct = 0; ct < 2; ++ct) {
    const int n = n0 + ct * 32 + l31;
    const bool nvalid = n < NN;
    const int nr = nvalid ? n : NN - 1;
    const int gid = group_ids[b * NN + nr];
#pragma unroll
    for (int r = 0; r < 16; ++r) {
      const int p = 32 * mt + (r & 3) + 8 * (r >> 2) + 4 * half;
      const bool pvalid = p < PP;
      const int pr = pvalid ? p : PP - 1;
      const float m = mask[((size_t)(b * PP + pr)) * NN + nr];
      const float ex = __expf(acc[ct][r] * two_inv_sqrt_emb);
      const float sc = 10.0f - 20.0f / (ex + 1.0f);
      const int cmp = cur_min[b * PP + pr];
      int delta = gid - cmp;
      delta = delta < 0 ? 0 : (delta > 4 ? 4 : delta);
      const float pb = (delta == 0) ? t0 : (delta == 1) ? t1 : (delta == 2) ? t2
                     : (delta == 3) ? t3 : t4;
      float e = (nvalid && pvalid) ? __expf(sc + pb + m) : 0.0f;
      if (nvalid && pvalid) out[((size_t)(b * PP + p)) * NN + n] = e;
      float ws = e;
#pragma unroll
      for (int off = 1; off < 32; off <<= 1) ws += __shfl_xor(ws, off, 64);
      rsum[r] += ws;
    }
  }
  if (l31 == 0) {
#pragma unroll
    for (int r = 0; r < 16; ++r) {
      const int p = 32 * mt + (r & 3) + 8 * (r >> 2) + 4 * half;
      if (p < PP) ssum[(size_t)(b * PP + p) * 16 + nc] = rsum[r];
    }
  }
}

// ---------------------------------------------------------------------------
// normalize: out[row][n] /= sum of 16 chunk partials  (unchanged)
// ---------------------------------------------------------------------------
__global__ __launch_bounds__(256) void norm_kernel(
    const float* __restrict__ ssum, float* __restrict__ out)
{
  const int row = blockIdx.x;   // b*PP + p
  float s = 0.f;
#pragma unroll
  for (int i = 0; i < 16; ++i) s += ssum[(size_t)row * 16 + i];
  const float inv = 1.0f / s;
#pragma unroll
  for (int i = 0; i < 4; ++i) {
    const int c = i * 256 + (int)threadIdx.x;
    if (c < NN) out[(size_t)row * NN + c] *= inv;
  }
}

// ---------------------------------------------------------------------------
extern "C" void kernel_launch(void* const* d_in, const int* in_sizes, int n_in,
                              void* d_out, int out_size, void* d_ws, size_t ws_size,
                              hipStream_t stream)
{
  (void)in_sizes; (void)n_in; (void)out_size; (void)ws_size;
  const float* enc_nodes  = (const float*)d_in[0];
  const float* enc_q1     = (const float*)d_in[1];
  const float* enc_last   = (const float*)d_in[2];
  const float* ninf       = (const float*)d_in[3];
  const float* Wq_first   = (const float*)d_in[4];
  const float* Wq_last    = (const float*)d_in[5];
  const float* Wk         = (const float*)d_in[6];
  const float* Wv         = (const float*)d_in[7];
  const float* W_comb     = (const float*)d_in[8];
  const float* b_comb     = (const float*)d_in[9];
  const float* bias_table = (const float*)d_in[10];
  const int*   group_ids  = (const int*)d_in[11];
  const int*   cur_min    = (const int*)d_in[12];
  float* out = (float*)d_out;
  float* ws  = (float*)d_ws;

  float* Qw = ws;                    //   819200 floats (reused as mh_in after attn)
  float* Kw = Qw + 819200;           //  8192000
  float* Vw = Kw + 8192000;          //  8192000
  float* po = Vw + 8192000;          //  6553600  (BB*NSPL*PP*DDIM)
  float* ls = po + 6553600;          //   409600  (BB*NSPL*PP*HH)
  float* mh = ls + 409600;           //   819200
  float* sm = mh + 819200;           //   102400  (BB*PP*16)

  // wfrag (320 KB, 5 matrices) aliases sm: consumed by proj kernels
  // (steps 2,3,6); sm first written by score2 (step 7) -- stream-safe.
  u32x4* wfrag = (u32x4*)sm;

  // pack all 5 weight matrices into split-bf16 MFMA fragments
  pack_w_kernel<<<40, 256, 0, stream>>>(Wk, Wv, Wq_first, Wq_last, W_comb, wfrag);
  // Q = (q1@Wq_first + last@Wq_last) * 0.25 via MFMA (fold 1/sqrt(QD))
  proj_q2_mfma_kernel<<<BB*PP/128, 256, 0, stream>>>(enc_q1, enc_last, wfrag,
                                                     Qw, 0.25f);
  // K, V projections via split-bf16 MFMA
  proj_kv_mfma_kernel<<<BB*NN/128, 256, 0, stream>>>(enc_nodes, wfrag, Kw, Vw);
  // attention partials via MFMA (QK^T and PV on the matrix pipe)
  attn_mfma_kernel<<<BB*NSPL, 512, 0, stream>>>(Qw, Kw, Vw, ninf, po, ls);
  // merge partials -> mh_in (reuses Qw)
  merge_kernel<<<3200, 256, 0, stream>>>(po, ls, Qw);
  // combine: mh = mh_in @ W_comb + b_comb via MFMA
  proj_comb_mfma_kernel<<<BB*PP/128, 256, 0, stream>>>(Qw, wfrag, b_comb, mh);
  // final scores via MFMA + fused epilogue
  score2_mfma_kernel<<<BB*16, 256, 0, stream>>>(enc_nodes, mh, ninf, bias_table,
                                                group_ids, cur_min, out, sm);
  // normalize
  norm_kernel<<<BB*PP, 256, 0, stream>>>(sm, out);
}

// Round 13
// 177.939 us; speedup vs baseline: 2.5861x; 1.0238x over previous
//
#include <hip/hip_runtime.h>

#define BB 64
#define PP 100
#define NN 1000
#define DDIM 128
#define HH 8
#define NSPL 8

typedef __attribute__((ext_vector_type(8))) short bf16x8;   // 8 bf16 = 4 VGPRs
typedef __attribute__((ext_vector_type(16))) float f32x16;  // MFMA 32x32 acc
typedef __attribute__((ext_vector_type(4))) unsigned u32x4;
typedef __attribute__((ext_vector_type(2))) unsigned u32x2;

__device__ __forceinline__ unsigned bf16rne(float x) {
  unsigned u = __float_as_uint(x);
  return (u + 0x7FFFu + ((u >> 16) & 1u)) >> 16;
}
__device__ __forceinline__ unsigned pk_bf16(float a, float b) {
  return bf16rne(a) | (bf16rne(b) << 16);
}

// split 8 contiguous floats into hi/lo bf16x8 fragments
__device__ __forceinline__ void split8(const float* __restrict__ p,
                                       bf16x8& hi8, bf16x8& lo8) {
  const float4 a = *(const float4*)p;
  const float4 c = *(const float4*)(p + 4);
  float v[8] = {a.x, a.y, a.z, a.w, c.x, c.y, c.z, c.w};
  unsigned hw[4], lw[4];
#pragma unroll
  for (int j = 0; j < 4; ++j) {
    const unsigned h0 = bf16rne(v[2*j]), h1 = bf16rne(v[2*j+1]);
    hw[j] = h0 | (h1 << 16);
    lw[j] = bf16rne(v[2*j]   - __uint_as_float(h0 << 16)) |
            (bf16rne(v[2*j+1] - __uint_as_float(h1 << 16)) << 16);
  }
  hi8 = __builtin_bit_cast(bf16x8, u32x4{hw[0], hw[1], hw[2], hw[3]});
  lo8 = __builtin_bit_cast(bf16x8, u32x4{lw[0], lw[1], lw[2], lw[3]});
}

// ---------------------------------------------------------------------------
// pack 5 weight matrices (fp32 128x128) -> MFMA B-fragment layout, split
// hi/lo bf16. mat: 0=Wk 1=Wv 2=Wq_first 3=Wq_last 4=W_comb. (unchanged)
// ---------------------------------------------------------------------------
__global__ __launch_bounds__(256) void pack_w_kernel(
    const float* __restrict__ W0, const float* __restrict__ W1,
    const float* __restrict__ W2, const float* __restrict__ W3,
    const float* __restrict__ W4, u32x4* __restrict__ wfrag)
{
  const int gid = blockIdx.x * 256 + threadIdx.x;  // [0, 10240)
  const int mat = gid >> 11;
  const int ct = (gid >> 9) & 3;
  const int ks = (gid >> 6) & 7;
  const int lane = gid & 63;
  const float* __restrict__ W =
      (mat == 0) ? W0 : (mat == 1) ? W1 : (mat == 2) ? W2 : (mat == 3) ? W3 : W4;
  const int col = ct * 32 + (lane & 31);
  const int k0 = ks * 16 + (lane >> 5) * 8;
  unsigned hi[4], lo[4];
#pragma unroll
  for (int j = 0; j < 4; ++j) {
    const float x0 = W[(k0 + 2 * j) * DDIM + col];
    const float x1 = W[(k0 + 2 * j + 1) * DDIM + col];
    const unsigned h0 = bf16rne(x0), h1 = bf16rne(x1);
    hi[j] = h0 | (h1 << 16);
    lo[j] = bf16rne(x0 - __uint_as_float(h0 << 16)) |
            (bf16rne(x1 - __uint_as_float(h1 << 16)) << 16);
  }
  const int base = (((mat * 4 + ct) * 8 + ks) * 2) * 64 + lane;
  wfrag[base]      = u32x4{hi[0], hi[1], hi[2], hi[3]};
  wfrag[base + 64] = u32x4{lo[0], lo[1], lo[2], lo[3]};
}

// ---------------------------------------------------------------------------
// K+V projection via MFMA 32x32x16 bf16, split-precision. (unchanged, r5)
// ---------------------------------------------------------------------------
__global__ __launch_bounds__(256) void proj_kv_mfma_kernel(
    const float* __restrict__ x, const u32x4* __restrict__ wfrag,
    float* __restrict__ outk, float* __restrict__ outv)
{
  const int tid = threadIdx.x;
  const int lane = tid & 63;
  const int wid = tid >> 6;
  const int rtp = wid >> 1;
  const int ctp = wid & 1;
  const int arow = blockIdx.x * 128 + rtp * 64 + (lane & 31);
  const int kgrp = (lane >> 5) * 8;

#pragma unroll 1
  for (int mat = 0; mat < 2; ++mat) {
    float* __restrict__ out = mat ? outv : outk;
    f32x16 acc[2][2];
#pragma unroll
    for (int a = 0; a < 2; ++a)
#pragma unroll
      for (int b = 0; b < 2; ++b)
#pragma unroll
        for (int i = 0; i < 16; ++i) acc[a][b][i] = 0.f;

#pragma unroll 1
    for (int ks = 0; ks < 8; ++ks) {
      bf16x8 ahi[2], alo[2];
#pragma unroll
      for (int rt = 0; rt < 2; ++rt) {
        const float* xp = x + (size_t)(arow + rt * 32) * DDIM + ks * 16 + kgrp;
        split8(xp, ahi[rt], alo[rt]);
      }
#pragma unroll
      for (int ct = 0; ct < 2; ++ct) {
        const int c = ctp * 2 + ct;
        const int fo = (((mat * 4 + c) * 8 + ks) * 2) * 64 + lane;
        const bf16x8 bhi = __builtin_bit_cast(bf16x8, wfrag[fo]);
        const bf16x8 blo = __builtin_bit_cast(bf16x8, wfrag[fo + 64]);
#pragma unroll
        for (int rt = 0; rt < 2; ++rt) {
          acc[rt][ct] = __builtin_amdgcn_mfma_f32_32x32x16_bf16(
              ahi[rt], bhi, acc[rt][ct], 0, 0, 0);
          acc[rt][ct] = __builtin_amdgcn_mfma_f32_32x32x16_bf16(
              ahi[rt], blo, acc[rt][ct], 0, 0, 0);
          acc[rt][ct] = __builtin_amdgcn_mfma_f32_32x32x16_bf16(
              alo[rt], bhi, acc[rt][ct], 0, 0, 0);
        }
      }
    }
#pragma unroll
    for (int rt = 0; rt < 2; ++rt)
#pragma unroll
      for (int ct = 0; ct < 2; ++ct) {
        const int colg = ctp * 64 + ct * 32 + (lane & 31);
        const int rowg0 = blockIdx.x * 128 + rtp * 64 + rt * 32 + 4 * (lane >> 5);
#pragma unroll
        for (int r = 0; r < 16; ++r) {
          const int rowg = rowg0 + (r & 3) + 8 * (r >> 2);
          out[(size_t)rowg * DDIM + colg] = acc[rt][ct][r];
        }
      }
  }
}

// ---------------------------------------------------------------------------
// Q projection via MFMA: out = (x1@Wq_first + x2@Wq_last) * scale. (r9)
// ---------------------------------------------------------------------------
__global__ __launch_bounds__(256) void proj_q2_mfma_kernel(
    const float* __restrict__ x1, const float* __restrict__ x2,
    const u32x4* __restrict__ wfrag, float* __restrict__ out, float scale)
{
  const int tid = threadIdx.x;
  const int lane = tid & 63;
  const int w = tid >> 6;
  const int hi = lane >> 5;
  const int l31 = lane & 31;
  const int row0 = blockIdx.x * 128 + w * 32;
  const float* xr1 = x1 + (size_t)(row0 + l31) * DDIM + hi * 8;
  const float* xr2 = x2 + (size_t)(row0 + l31) * DDIM + hi * 8;

  f32x16 acc[4];
#pragma unroll
  for (int ct = 0; ct < 4; ++ct)
#pragma unroll
    for (int i = 0; i < 16; ++i) acc[ct][i] = 0.f;

#pragma unroll 1
  for (int ks = 0; ks < 8; ++ks) {
    bf16x8 a1h, a1l, a2h, a2l;
    split8(xr1 + ks * 16, a1h, a1l);
    split8(xr2 + ks * 16, a2h, a2l);
#pragma unroll
    for (int ct = 0; ct < 4; ++ct) {
      const int fo1 = (((2 * 4 + ct) * 8 + ks) * 2) * 64 + lane;  // Wq_first
      const bf16x8 b1h = __builtin_bit_cast(bf16x8, wfrag[fo1]);
      const bf16x8 b1l = __builtin_bit_cast(bf16x8, wfrag[fo1 + 64]);
      acc[ct] = __builtin_amdgcn_mfma_f32_32x32x16_bf16(a1h, b1h, acc[ct], 0, 0, 0);
      acc[ct] = __builtin_amdgcn_mfma_f32_32x32x16_bf16(a1h, b1l, acc[ct], 0, 0, 0);
      acc[ct] = __builtin_amdgcn_mfma_f32_32x32x16_bf16(a1l, b1h, acc[ct], 0, 0, 0);
      const int fo2 = (((3 * 4 + ct) * 8 + ks) * 2) * 64 + lane;  // Wq_last
      const bf16x8 b2h = __builtin_bit_cast(bf16x8, wfrag[fo2]);
      const bf16x8 b2l = __builtin_bit_cast(bf16x8, wfrag[fo2 + 64]);
      acc[ct] = __builtin_amdgcn_mfma_f32_32x32x16_bf16(a2h, b2h, acc[ct], 0, 0, 0);
      acc[ct] = __builtin_amdgcn_mfma_f32_32x32x16_bf16(a2h, b2l, acc[ct], 0, 0, 0);
      acc[ct] = __builtin_amdgcn_mfma_f32_32x32x16_bf16(a2l, b2h, acc[ct], 0, 0, 0);
    }
  }
#pragma unroll
  for (int ct = 0; ct < 4; ++ct) {
    const int colg = ct * 32 + l31;
    const int rowg0 = row0 + 4 * hi;
#pragma unroll
    for (int r = 0; r < 16; ++r) {
      const int rowg = rowg0 + (r & 3) + 8 * (r >> 2);
      out[(size_t)rowg * DDIM + colg] = acc[ct][r] * scale;
    }
  }
}

// ---------------------------------------------------------------------------
// Combine projection via MFMA: out = x@W_comb + bias. (r9)
// ---------------------------------------------------------------------------
__global__ __launch_bounds__(256) void proj_comb_mfma_kernel(
    const float* __restrict__ x, const u32x4* __restrict__ wfrag,
    const float* __restrict__ bias, float* __restrict__ out)
{
  const int tid = threadIdx.x;
  const int lane = tid & 63;
  const int w = tid >> 6;
  const int hi = lane >> 5;
  const int l31 = lane & 31;
  const int row0 = blockIdx.x * 128 + w * 32;
  const float* xr = x + (size_t)(row0 + l31) * DDIM + hi * 8;

  f32x16 acc[4];
#pragma unroll
  for (int ct = 0; ct < 4; ++ct)
#pragma unroll
    for (int i = 0; i < 16; ++i) acc[ct][i] = 0.f;

#pragma unroll 1
  for (int ks = 0; ks < 8; ++ks) {
    bf16x8 ah, al;
    split8(xr + ks * 16, ah, al);
#pragma unroll
    for (int ct = 0; ct < 4; ++ct) {
      const int fo = (((4 * 4 + ct) * 8 + ks) * 2) * 64 + lane;  // W_comb
      const bf16x8 bh = __builtin_bit_cast(bf16x8, wfrag[fo]);
      const bf16x8 bl = __builtin_bit_cast(bf16x8, wfrag[fo + 64]);
      acc[ct] = __builtin_amdgcn_mfma_f32_32x32x16_bf16(ah, bh, acc[ct], 0, 0, 0);
      acc[ct] = __builtin_amdgcn_mfma_f32_32x32x16_bf16(ah, bl, acc[ct], 0, 0, 0);
      acc[ct] = __builtin_amdgcn_mfma_f32_32x32x16_bf16(al, bh, acc[ct], 0, 0, 0);
    }
  }
#pragma unroll
  for (int ct = 0; ct < 4; ++ct) {
    const int colg = ct * 32 + l31;
    const float bj = bias[colg];
    const int rowg0 = row0 + 4 * hi;
#pragma unroll
    for (int r = 0; r < 16; ++r) {
      const int rowg = rowg0 + (r & 3) + 8 * (r >> 2);
      out[(size_t)rowg * DDIM + colg] = acc[ct][r] + bj;
    }
  }
}

// ---------------------------------------------------------------------------
// MFMA attention, round-13 (= round-12 with the permlane operand order
// FIXED). V_PERMLANE32_SWAP_B32 semantics: vdst[32:63] <-> src[0:31];
// builtin returns {vdst_new, src_new}. Correct call is swap(t01, t45):
//   r0[0] = {lo: t01 own, hi: t45[l-32]}  = A-frag word0
//   r0[1] = {lo: t01[l+32], hi: t45 own}  = A-frag word2
// (round-12 passed (t45, t01) -- halves routed wrong, absmax 0.43.)
// Other r12 changes retained: mask as MFMA C-in; -inf pad staging.
// ---------------------------------------------------------------------------
__global__ __launch_bounds__(512) void attn_mfma_kernel(
    const float* __restrict__ Q, const float* __restrict__ K,
    const float* __restrict__ V, const float* __restrict__ mask,
    float* __restrict__ po, float* __restrict__ lsum)
{
  __shared__ float mask_lds[PP * 132];   // [p][n-chunk], pad 132 for banks

  const int b = blockIdx.x >> 3;
  const int chunk = blockIdx.x & 7;
  const int n0 = chunk * 128;
  const int tid = threadIdx.x;
  const int h = tid >> 6;          // wave = head
  const int l = tid & 63;
  const int hi = l >> 5;
  const int l31 = l & 31;

  const float NINF = -__builtin_huge_valf();
  for (int idx = tid; idx < PP * 32; idx += 512) {
    const int p = idx >> 5;
    const int c = idx & 31;
    const int nb4 = n0 + 4 * c;
    const int nsrc = min(nb4, NN - 4);
    float4 f = *(const float4*)(mask + ((size_t)(b * PP + p)) * NN + nsrc);
    f.x = (nb4 + 0 < NN) ? f.x : NINF;   // pad columns n>=NN kill via exp(-inf)
    f.y = (nb4 + 1 < NN) ? f.y : NINF;
    f.z = (nb4 + 2 < NN) ? f.z : NINF;
    f.w = (nb4 + 3 < NN) ? f.w : NINF;
    *(float4*)&mask_lds[p * 132 + 4 * c] = f;
  }
  __syncthreads();

  bf16x8 qhi[4], qlo[4];
#pragma unroll
  for (int pt = 0; pt < 4; ++pt) {
    const int qrow = min(b * PP + pt * 32 + l31, BB * PP - 1);
    split8(Q + (size_t)qrow * DDIM + h * 16 + hi * 8, qhi[pt], qlo[pt]);
  }

  f32x16 oacc[4];
#pragma unroll
  for (int pt = 0; pt < 4; ++pt)
#pragma unroll
    for (int i = 0; i < 16; ++i) oacc[pt][i] = 0.f;
  float lacc[4] = {0.f, 0.f, 0.f, 0.f};

  const float* Kb = K + (size_t)b * NN * DDIM + h * 16;
  const float* Vb = V + (size_t)b * NN * DDIM + h * 16;
  const int dv = min(l31, 15);

#pragma unroll 1
  for (int nt = 0; nt < 4; ++nt) {
    const int nb = n0 + nt * 32;

    bf16x8 khi, klo;
    {
      const int krow = min(nb + l31, NN - 1);
      split8(Kb + (size_t)krow * DDIM + hi * 8, khi, klo);
    }
    bf16x8 vhi[2], vlo[2];
#pragma unroll
    for (int ks = 0; ks < 2; ++ks) {
      float vt[8];
#pragma unroll
      for (int i = 0; i < 8; ++i) {
        const int vrow = min(nb + ks * 16 + hi * 8 + i, NN - 1);
        vt[i] = Vb[(size_t)vrow * DDIM + dv];
      }
      unsigned vh[4], vl[4];
#pragma unroll
      for (int j = 0; j < 4; ++j) {
        const unsigned h0 = bf16rne(vt[2*j]), h1 = bf16rne(vt[2*j+1]);
        vh[j] = h0 | (h1 << 16);
        vl[j] = bf16rne(vt[2*j]   - __uint_as_float(h0 << 16)) |
                (bf16rne(vt[2*j+1] - __uint_as_float(h1 << 16)) << 16);
      }
      vhi[ks] = __builtin_bit_cast(bf16x8, u32x4{vh[0], vh[1], vh[2], vh[3]});
      vlo[ks] = __builtin_bit_cast(bf16x8, u32x4{vl[0], vl[1], vl[2], vl[3]});
    }

#pragma unroll
    for (int pt = 0; pt < 4; ++pt) {
      // S^T = K.Q^T with mask as C-in (layout of mq matches C exactly)
      const int prow = min(pt * 32 + l31, PP - 1);
      f32x16 s;
#pragma unroll
      for (int q = 0; q < 4; ++q) {
        const float4 f =
            *(const float4*)&mask_lds[prow * 132 + nt * 32 + q * 8 + hi * 4];
        s[4*q+0] = f.x; s[4*q+1] = f.y; s[4*q+2] = f.z; s[4*q+3] = f.w;
      }
      s = __builtin_amdgcn_mfma_f32_32x32x16_bf16(khi, qhi[pt], s, 0, 0, 0);
      s = __builtin_amdgcn_mfma_f32_32x32x16_bf16(khi, qlo[pt], s, 0, 0, 0);
      s = __builtin_amdgcn_mfma_f32_32x32x16_bf16(klo, qhi[pt], s, 0, 0, 0);

      float ev[16];
#pragma unroll
      for (int r = 0; r < 16; ++r) {
        const float e = __expf(s[r]);   // pad/masked cols: exp(-inf)=0
        ev[r] = e;
        lacc[pt] += e;
      }
      unsigned u[8];
#pragma unroll
      for (int j = 0; j < 8; ++j) u[j] = pk_bf16(ev[2*j], ev[2*j+1]);
      // route C-layout P -> A-frag via permlane32_swap (VALU half-exchange)
#pragma unroll
      for (int ks = 0; ks < 2; ++ks) {
        const unsigned t01 = u[ks*4+0], t23 = u[ks*4+1];
        const unsigned t45 = u[ks*4+2], t67 = u[ks*4+3];
        // swap(vdst=t01, src=t45): vdst[32:63] <-> src[0:31]
        const u32x2 r0 = __builtin_amdgcn_permlane32_swap(t01, t45, false, false);
        const u32x2 r1 = __builtin_amdgcn_permlane32_swap(t23, t67, false, false);
        const bf16x8 pah = __builtin_bit_cast(bf16x8,
            u32x4{r0[0], r1[0], r0[1], r1[1]});
        oacc[pt] = __builtin_amdgcn_mfma_f32_32x32x16_bf16(pah, vhi[ks], oacc[pt], 0, 0, 0);
        oacc[pt] = __builtin_amdgcn_mfma_f32_32x32x16_bf16(pah, vlo[ks], oacc[pt], 0, 0, 0);
      }
    }
  }

  const int base = (b * NSPL + chunk) * PP;
#pragma unroll
  for (int pt = 0; pt < 4; ++pt) {
    const float ltot = lacc[pt] + __shfl_xor(lacc[pt], 32, 64);
    const int pl = pt * 32 + l31;
    if (l < 32 && pl < PP)
      lsum[(size_t)(base + pl) * HH + h] = ltot;
#pragma unroll
    for (int r = 0; r < 16; ++r) {
      const int p = pt * 32 + (r & 3) + 8 * (r >> 2) + 4 * hi;
      if (l31 < 16 && p < PP)
        po[(size_t)(base + p) * DDIM + h * 16 + l31] = oacc[pt][r];
    }
  }
}

// ---------------------------------------------------------------------------
// merge: mh_in[b][p][d] = (sum_s po) / (sum_s lsum[h(d)])  (unchanged)
// ---------------------------------------------------------------------------
__global__ __launch_bounds__(256) void merge_kernel(
    const float* __restrict__ po, const float* __restrict__ lsum,
    float* __restrict__ mh_in)
{
  const int idx = blockIdx.x * 256 + threadIdx.x;   // over BB*PP*DDIM
  const int d = idx & 127;
  const int row = idx >> 7;        // b*PP + p
  const int b = row / PP;
  const int p = row - b * PP;
  const int h = d >> 4;
  float s = 0.f, lt = 0.f;
#pragma unroll
  for (int sp = 0; sp < NSPL; ++sp) {
    const int base = (b * NSPL + sp) * PP + p;
    s  += po[base * DDIM + d];
    lt += lsum[base * HH + h];
  }
  mh_in[idx] = s / lt;
}

// ---------------------------------------------------------------------------
// score2 via MFMA + fused epilogue; reduce tree hoisted out of ct loop. (r12)
// ---------------------------------------------------------------------------
__global__ __launch_bounds__(256) void score2_mfma_kernel(
    const float* __restrict__ enc, const float* __restrict__ mh,
    const float* __restrict__ mask, const float* __restrict__ bias_table,
    const int* __restrict__ group_ids, const int* __restrict__ cur_min,
    float* __restrict__ out, float* __restrict__ ssum)
{
  const int b   = blockIdx.x >> 4;
  const int nc  = blockIdx.x & 15;
  const int n0  = nc * 64;
  const int tid = threadIdx.x;
  const int lane = tid & 63;
  const int mt   = tid >> 6;
  const int half = lane >> 5;
  const int l31  = lane & 31;

  f32x16 acc[2];
#pragma unroll
  for (int c = 0; c < 2; ++c)
#pragma unroll
    for (int i = 0; i < 16; ++i) acc[c][i] = 0.f;

  const float* mha = mh + ((size_t)(b * PP + 32 * mt + l31)) * DDIM + half * 8;
  const float* encb = enc + (size_t)b * NN * DDIM + half * 8;
  const int nsrc0 = min(n0 + l31, NN - 1);
  const int nsrc1 = min(n0 + 32 + l31, NN - 1);

#pragma unroll 1
  for (int ks = 0; ks < 8; ++ks) {
    bf16x8 ahi, alo;
    split8(mha + ks * 16, ahi, alo);
    bf16x8 bhi0, blo0, bhi1, blo1;
    split8(encb + (size_t)nsrc0 * DDIM + ks * 16, bhi0, blo0);
    split8(encb + (size_t)nsrc1 * DDIM + ks * 16, bhi1, blo1);
    acc[0] = __builtin_amdgcn_mfma_f32_32x32x16_bf16(ahi, bhi0, acc[0], 0, 0, 0);
    acc[0] = __builtin_amdgcn_mfma_f32_32x32x16_bf16(ahi, blo0, acc[0], 0, 0, 0);
    acc[0] = __builtin_amdgcn_mfma_f32_32x32x16_bf16(alo, bhi0, acc[0], 0, 0, 0);
    acc[1] = __builtin_amdgcn_mfma_f32_32x32x16_bf16(ahi, bhi1, acc[1], 0, 0, 0);
    acc[1] = __builtin_amdgcn_mfma_f32_32x32x16_bf16(ahi, blo1, acc[1], 0, 0, 0);
    acc[1] = __builtin_amdgcn_mfma_f32_32x32x16_bf16(alo, bhi1, acc[1], 0, 0, 0);
  }

  const float t0 = bias_table[0], t1 = bias_table[1], t2 = bias_table[2],
              t3 = bias_table[3], t4 = bias_table[4];
  const float two_inv_sqrt_emb = 0.1767766952966369f;  // 2/sqrt(128)

  float rsum[16];
#pragma unroll
  for (int r = 0; r < 16; ++r) rsum[r] = 0.f;

#pragma unroll
  for (int ct = 0; ct < 2; ++ct) {
    const int n = n0 + ct * 32 + l31;
    const bool nvalid = n < NN;
    const int nr = nvalid ? n : NN - 1;
    const int gid = group_ids[b * NN + nr];
#pragma unroll
    for (int r = 0; r < 16; ++r) {
      const int p = 32 * mt + (r & 3) + 8 * (r >> 2) + 4 * half;
      const bool pvalid = p < PP;
      const int pr = pvalid ? p : PP - 1;
      const float m = mask[((size_t)(b * PP + pr)) * NN + nr];
      const float ex = __expf(acc[ct][r] * two_inv_sqrt_emb);
      const float sc = 10.0f - 20.0f / (ex + 1.0f);
      const int cmp = cur_min[b * PP + pr];
      int delta = gid - cmp;
      delta = delta < 0 ? 0 : (delta > 4 ? 4 : delta);
      const float pb = (delta == 0) ? t0 : (delta == 1) ? t1 : (delta == 2) ? t2
                     : (delta == 3) ? t3 : t4;
      float e = (nvalid && pvalid) ? __expf(sc + pb + m) : 0.0f;
      if (nvalid && pvalid) out[((size_t)(b * PP + p)) * NN + n] = e;
      rsum[r] += e;
    }
  }
  // one reduce tree per row (hoisted out of ct loop)
#pragma unroll
  for (int r = 0; r < 16; ++r) {
    float ws = rsum[r];
#pragma unroll
    for (int off = 1; off < 32; off <<= 1) ws += __shfl_xor(ws, off, 64);
    rsum[r] = ws;
  }
  if (l31 == 0) {
#pragma unroll
    for (int r = 0; r < 16; ++r) {
      const int p = 32 * mt + (r & 3) + 8 * (r >> 2) + 4 * half;
      if (p < PP) ssum[(size_t)(b * PP + p) * 16 + nc] = rsum[r];
    }
  }
}

// ---------------------------------------------------------------------------
// normalize: out[row][n] /= sum of 16 chunk partials  (unchanged)
// ---------------------------------------------------------------------------
__global__ __launch_bounds__(256) void norm_kernel(
    const float* __restrict__ ssum, float* __restrict__ out)
{
  const int row = blockIdx.x;   // b*PP + p
  float s = 0.f;
#pragma unroll
  for (int i = 0; i < 16; ++i) s += ssum[(size_t)row * 16 + i];
  const float inv = 1.0f / s;
#pragma unroll
  for (int i = 0; i < 4; ++i) {
    const int c = i * 256 + (int)threadIdx.x;
    if (c < NN) out[(size_t)row * NN + c] *= inv;
  }
}

// ---------------------------------------------------------------------------
extern "C" void kernel_launch(void* const* d_in, const int* in_sizes, int n_in,
                              void* d_out, int out_size, void* d_ws, size_t ws_size,
                              hipStream_t stream)
{
  (void)in_sizes; (void)n_in; (void)out_size; (void)ws_size;
  const float* enc_nodes  = (const float*)d_in[0];
  const float* enc_q1     = (const float*)d_in[1];
  const float* enc_last   = (const float*)d_in[2];
  const float* ninf       = (const float*)d_in[3];
  const float* Wq_first   = (const float*)d_in[4];
  const float* Wq_last    = (const float*)d_in[5];
  const float* Wk         = (const float*)d_in[6];
  const float* Wv         = (const float*)d_in[7];
  const float* W_comb     = (const float*)d_in[8];
  const float* b_comb     = (const float*)d_in[9];
  const float* bias_table = (const float*)d_in[10];
  const int*   group_ids  = (const int*)d_in[11];
  const int*   cur_min    = (const int*)d_in[12];
  float* out = (float*)d_out;
  float* ws  = (float*)d_ws;

  float* Qw = ws;                    //   819200 floats (reused as mh_in after attn)
  float* Kw = Qw + 819200;           //  8192000
  float* Vw = Kw + 8192000;          //  8192000
  float* po = Vw + 8192000;          //  6553600  (BB*NSPL*PP*DDIM)
  float* ls = po + 6553600;          //   409600  (BB*NSPL*PP*HH)
  float* mh = ls + 409600;           //   819200
  float* sm = mh + 819200;           //   102400  (BB*PP*16)

  // wfrag (320 KB, 5 matrices) aliases sm: consumed by proj kernels
  // (steps 2,3,6); sm first written by score2 (step 7) -- stream-safe.
  u32x4* wfrag = (u32x4*)sm;

  // pack all 5 weight matrices into split-bf16 MFMA fragments
  pack_w_kernel<<<40, 256, 0, stream>>>(Wk, Wv, Wq_first, Wq_last, W_comb, wfrag);
  // Q = (q1@Wq_first + last@Wq_last) * 0.25 via MFMA (fold 1/sqrt(QD))
  proj_q2_mfma_kernel<<<BB*PP/128, 256, 0, stream>>>(enc_q1, enc_last, wfrag,
                                                     Qw, 0.25f);
  // K, V projections via split-bf16 MFMA
  proj_kv_mfma_kernel<<<BB*NN/128, 256, 0, stream>>>(enc_nodes, wfrag, Kw, Vw);
  // attention partials via MFMA (QK^T and PV on the matrix pipe)
  attn_mfma_kernel<<<BB*NSPL, 512, 0, stream>>>(Qw, Kw, Vw, ninf, po, ls);
  // merge partials -> mh_in (reuses Qw)
  merge_kernel<<<3200, 256, 0, stream>>>(po, ls, Qw);
  // combine: mh = mh_in @ W_comb + b_comb via MFMA
  proj_comb_mfma_kernel<<<BB*PP/128, 256, 0, stream>>>(Qw, wfrag, b_comb, mh);
  // final scores via MFMA + fused epilogue
  score2_mfma_kernel<<<BB*16, 256, 0, stream>>>(enc_nodes, mh, ninf, bias_table,
                                                group_ids, cur_min, out, sm);
  // normalize
  norm_kernel<<<BB*PP, 256, 0, stream>>>(sm, out);
}

// Round 14
// 176.931 us; speedup vs baseline: 2.6009x; 1.0057x over previous
//
#include <hip/hip_runtime.h>

#define BB 64
#define PP 100
#define NN 1000
#define DDIM 128
#define HH 8
#define NSPL 8

typedef __attribute__((ext_vector_type(8))) short bf16x8;   // 8 bf16 = 4 VGPRs
typedef __attribute__((ext_vector_type(16))) float f32x16;  // MFMA 32x32 acc
typedef __attribute__((ext_vector_type(4))) unsigned u32x4;
typedef __attribute__((ext_vector_type(2))) unsigned u32x2;

__device__ __forceinline__ unsigned bf16rne(float x) {
  unsigned u = __float_as_uint(x);
  return (u + 0x7FFFu + ((u >> 16) & 1u)) >> 16;
}
__device__ __forceinline__ unsigned pk_bf16(float a, float b) {
  return bf16rne(a) | (bf16rne(b) << 16);
}

// split 8 contiguous floats into hi/lo bf16x8 fragments
__device__ __forceinline__ void split8(const float* __restrict__ p,
                                       bf16x8& hi8, bf16x8& lo8) {
  const float4 a = *(const float4*)p;
  const float4 c = *(const float4*)(p + 4);
  float v[8] = {a.x, a.y, a.z, a.w, c.x, c.y, c.z, c.w};
  unsigned hw[4], lw[4];
#pragma unroll
  for (int j = 0; j < 4; ++j) {
    const unsigned h0 = bf16rne(v[2*j]), h1 = bf16rne(v[2*j+1]);
    hw[j] = h0 | (h1 << 16);
    lw[j] = bf16rne(v[2*j]   - __uint_as_float(h0 << 16)) |
            (bf16rne(v[2*j+1] - __uint_as_float(h1 << 16)) << 16);
  }
  hi8 = __builtin_bit_cast(bf16x8, u32x4{hw[0], hw[1], hw[2], hw[3]});
  lo8 = __builtin_bit_cast(bf16x8, u32x4{lw[0], lw[1], lw[2], lw[3]});
}

// ---------------------------------------------------------------------------
// pack 5 weight matrices (fp32 128x128) -> MFMA B-fragment layout, split
// hi/lo bf16. mat: 0=Wk 1=Wv 2=Wq_first 3=Wq_last 4=W_comb. (unchanged)
// ---------------------------------------------------------------------------
__global__ __launch_bounds__(256) void pack_w_kernel(
    const float* __restrict__ W0, const float* __restrict__ W1,
    const float* __restrict__ W2, const float* __restrict__ W3,
    const float* __restrict__ W4, u32x4* __restrict__ wfrag)
{
  const int gid = blockIdx.x * 256 + threadIdx.x;  // [0, 10240)
  const int mat = gid >> 11;
  const int ct = (gid >> 9) & 3;
  const int ks = (gid >> 6) & 7;
  const int lane = gid & 63;
  const float* __restrict__ W =
      (mat == 0) ? W0 : (mat == 1) ? W1 : (mat == 2) ? W2 : (mat == 3) ? W3 : W4;
  const int col = ct * 32 + (lane & 31);
  const int k0 = ks * 16 + (lane >> 5) * 8;
  unsigned hi[4], lo[4];
#pragma unroll
  for (int j = 0; j < 4; ++j) {
    const float x0 = W[(k0 + 2 * j) * DDIM + col];
    const float x1 = W[(k0 + 2 * j + 1) * DDIM + col];
    const unsigned h0 = bf16rne(x0), h1 = bf16rne(x1);
    hi[j] = h0 | (h1 << 16);
    lo[j] = bf16rne(x0 - __uint_as_float(h0 << 16)) |
            (bf16rne(x1 - __uint_as_float(h1 << 16)) << 16);
  }
  const int base = (((mat * 4 + ct) * 8 + ks) * 2) * 64 + lane;
  wfrag[base]      = u32x4{hi[0], hi[1], hi[2], hi[3]};
  wfrag[base + 64] = u32x4{lo[0], lo[1], lo[2], lo[3]};
}

// ---------------------------------------------------------------------------
// pack enc_nodes -> fragment layout, split hi/lo bf16. One 32-row tile per
// (b,t): lane holds row 32t+(lane&31) (clamped to NN-1), k = 16ks+8(lane>>5)+i.
// Serves score2's B operand (col=row-index, same lane map as A). The scattered
// 32-line read happens ONCE here (L1-blocked); consumers read coalesced.
// grid = BB*32, block = 512 (ks = tid>>6).
// ---------------------------------------------------------------------------
__global__ __launch_bounds__(512) void pack_enc_kernel(
    const float* __restrict__ enc, u32x4* __restrict__ encp)
{
  const int b = blockIdx.x >> 5;
  const int t = blockIdx.x & 31;
  const int ks = threadIdx.x >> 6;
  const int lane = threadIdx.x & 63;
  const int n = min(32 * t + (lane & 31), NN - 1);
  const int k0 = ks * 16 + (lane >> 5) * 8;
  bf16x8 hi8, lo8;
  split8(enc + ((size_t)b * NN + n) * DDIM + k0, hi8, lo8);
  const size_t base = ((size_t)(b * 32 + t) * 8 + ks) * 128 + lane;
  encp[base]      = __builtin_bit_cast(u32x4, hi8);
  encp[base + 64] = __builtin_bit_cast(u32x4, lo8);
}

// ---------------------------------------------------------------------------
// pack mh -> A-fragment layout for score2. lane row = 32mt+(lane&31) clamp.
// grid = BB*4, block = 512.
// ---------------------------------------------------------------------------
__global__ __launch_bounds__(512) void pack_mh_kernel(
    const float* __restrict__ mh, u32x4* __restrict__ mhp)
{
  const int b = blockIdx.x >> 2;
  const int mt = blockIdx.x & 3;
  const int ks = threadIdx.x >> 6;
  const int lane = threadIdx.x & 63;
  const int p = min(32 * mt + (lane & 31), PP - 1);
  const int k0 = ks * 16 + (lane >> 5) * 8;
  bf16x8 hi8, lo8;
  split8(mh + ((size_t)b * PP + p) * DDIM + k0, hi8, lo8);
  const size_t base = ((size_t)(b * 4 + mt) * 8 + ks) * 128 + lane;
  mhp[base]      = __builtin_bit_cast(u32x4, hi8);
  mhp[base + 64] = __builtin_bit_cast(u32x4, lo8);
}

// ---------------------------------------------------------------------------
// K+V projection via MFMA 32x32x16 bf16, split-precision. (unchanged, r5)
// ---------------------------------------------------------------------------
__global__ __launch_bounds__(256) void proj_kv_mfma_kernel(
    const float* __restrict__ x, const u32x4* __restrict__ wfrag,
    float* __restrict__ outk, float* __restrict__ outv)
{
  const int tid = threadIdx.x;
  const int lane = tid & 63;
  const int wid = tid >> 6;
  const int rtp = wid >> 1;
  const int ctp = wid & 1;
  const int arow = blockIdx.x * 128 + rtp * 64 + (lane & 31);
  const int kgrp = (lane >> 5) * 8;

#pragma unroll 1
  for (int mat = 0; mat < 2; ++mat) {
    float* __restrict__ out = mat ? outv : outk;
    f32x16 acc[2][2];
#pragma unroll
    for (int a = 0; a < 2; ++a)
#pragma unroll
      for (int b = 0; b < 2; ++b)
#pragma unroll
        for (int i = 0; i < 16; ++i) acc[a][b][i] = 0.f;

#pragma unroll 1
    for (int ks = 0; ks < 8; ++ks) {
      bf16x8 ahi[2], alo[2];
#pragma unroll
      for (int rt = 0; rt < 2; ++rt) {
        const float* xp = x + (size_t)(arow + rt * 32) * DDIM + ks * 16 + kgrp;
        split8(xp, ahi[rt], alo[rt]);
      }
#pragma unroll
      for (int ct = 0; ct < 2; ++ct) {
        const int c = ctp * 2 + ct;
        const int fo = (((mat * 4 + c) * 8 + ks) * 2) * 64 + lane;
        const bf16x8 bhi = __builtin_bit_cast(bf16x8, wfrag[fo]);
        const bf16x8 blo = __builtin_bit_cast(bf16x8, wfrag[fo + 64]);
#pragma unroll
        for (int rt = 0; rt < 2; ++rt) {
          acc[rt][ct] = __builtin_amdgcn_mfma_f32_32x32x16_bf16(
              ahi[rt], bhi, acc[rt][ct], 0, 0, 0);
          acc[rt][ct] = __builtin_amdgcn_mfma_f32_32x32x16_bf16(
              ahi[rt], blo, acc[rt][ct], 0, 0, 0);
          acc[rt][ct] = __builtin_amdgcn_mfma_f32_32x32x16_bf16(
              alo[rt], bhi, acc[rt][ct], 0, 0, 0);
        }
      }
    }
#pragma unroll
    for (int rt = 0; rt < 2; ++rt)
#pragma unroll
      for (int ct = 0; ct < 2; ++ct) {
        const int colg = ctp * 64 + ct * 32 + (lane & 31);
        const int rowg0 = blockIdx.x * 128 + rtp * 64 + rt * 32 + 4 * (lane >> 5);
#pragma unroll
        for (int r = 0; r < 16; ++r) {
          const int rowg = rowg0 + (r & 3) + 8 * (r >> 2);
          out[(size_t)rowg * DDIM + colg] = acc[rt][ct][r];
        }
      }
  }
}

// ---------------------------------------------------------------------------
// Q projection via MFMA: out = (x1@Wq_first + x2@Wq_last) * scale. (r9)
// ---------------------------------------------------------------------------
__global__ __launch_bounds__(256) void proj_q2_mfma_kernel(
    const float* __restrict__ x1, const float* __restrict__ x2,
    const u32x4* __restrict__ wfrag, float* __restrict__ out, float scale)
{
  const int tid = threadIdx.x;
  const int lane = tid & 63;
  const int w = tid >> 6;
  const int hi = lane >> 5;
  const int l31 = lane & 31;
  const int row0 = blockIdx.x * 128 + w * 32;
  const float* xr1 = x1 + (size_t)(row0 + l31) * DDIM + hi * 8;
  const float* xr2 = x2 + (size_t)(row0 + l31) * DDIM + hi * 8;

  f32x16 acc[4];
#pragma unroll
  for (int ct = 0; ct < 4; ++ct)
#pragma unroll
    for (int i = 0; i < 16; ++i) acc[ct][i] = 0.f;

#pragma unroll 1
  for (int ks = 0; ks < 8; ++ks) {
    bf16x8 a1h, a1l, a2h, a2l;
    split8(xr1 + ks * 16, a1h, a1l);
    split8(xr2 + ks * 16, a2h, a2l);
#pragma unroll
    for (int ct = 0; ct < 4; ++ct) {
      const int fo1 = (((2 * 4 + ct) * 8 + ks) * 2) * 64 + lane;  // Wq_first
      const bf16x8 b1h = __builtin_bit_cast(bf16x8, wfrag[fo1]);
      const bf16x8 b1l = __builtin_bit_cast(bf16x8, wfrag[fo1 + 64]);
      acc[ct] = __builtin_amdgcn_mfma_f32_32x32x16_bf16(a1h, b1h, acc[ct], 0, 0, 0);
      acc[ct] = __builtin_amdgcn_mfma_f32_32x32x16_bf16(a1h, b1l, acc[ct], 0, 0, 0);
      acc[ct] = __builtin_amdgcn_mfma_f32_32x32x16_bf16(a1l, b1h, acc[ct], 0, 0, 0);
      const int fo2 = (((3 * 4 + ct) * 8 + ks) * 2) * 64 + lane;  // Wq_last
      const bf16x8 b2h = __builtin_bit_cast(bf16x8, wfrag[fo2]);
      const bf16x8 b2l = __builtin_bit_cast(bf16x8, wfrag[fo2 + 64]);
      acc[ct] = __builtin_amdgcn_mfma_f32_32x32x16_bf16(a2h, b2h, acc[ct], 0, 0, 0);
      acc[ct] = __builtin_amdgcn_mfma_f32_32x32x16_bf16(a2h, b2l, acc[ct], 0, 0, 0);
      acc[ct] = __builtin_amdgcn_mfma_f32_32x32x16_bf16(a2l, b2h, acc[ct], 0, 0, 0);
    }
  }
#pragma unroll
  for (int ct = 0; ct < 4; ++ct) {
    const int colg = ct * 32 + l31;
    const int rowg0 = row0 + 4 * hi;
#pragma unroll
    for (int r = 0; r < 16; ++r) {
      const int rowg = rowg0 + (r & 3) + 8 * (r >> 2);
      out[(size_t)rowg * DDIM + colg] = acc[ct][r] * scale;
    }
  }
}

// ---------------------------------------------------------------------------
// Combine projection via MFMA: out = x@W_comb + bias. (r9)
// ---------------------------------------------------------------------------
__global__ __launch_bounds__(256) void proj_comb_mfma_kernel(
    const float* __restrict__ x, const u32x4* __restrict__ wfrag,
    const float* __restrict__ bias, float* __restrict__ out)
{
  const int tid = threadIdx.x;
  const int lane = tid & 63;
  const int w = tid >> 6;
  const int hi = lane >> 5;
  const int l31 = lane & 31;
  const int row0 = blockIdx.x * 128 + w * 32;
  const float* xr = x + (size_t)(row0 + l31) * DDIM + hi * 8;

  f32x16 acc[4];
#pragma unroll
  for (int ct = 0; ct < 4; ++ct)
#pragma unroll
    for (int i = 0; i < 16; ++i) acc[ct][i] = 0.f;

#pragma unroll 1
  for (int ks = 0; ks < 8; ++ks) {
    bf16x8 ah, al;
    split8(xr + ks * 16, ah, al);
#pragma unroll
    for (int ct = 0; ct < 4; ++ct) {
      const int fo = (((4 * 4 + ct) * 8 + ks) * 2) * 64 + lane;  // W_comb
      const bf16x8 bh = __builtin_bit_cast(bf16x8, wfrag[fo]);
      const bf16x8 bl = __builtin_bit_cast(bf16x8, wfrag[fo + 64]);
      acc[ct] = __builtin_amdgcn_mfma_f32_32x32x16_bf16(ah, bh, acc[ct], 0, 0, 0);
      acc[ct] = __builtin_amdgcn_mfma_f32_32x32x16_bf16(ah, bl, acc[ct], 0, 0, 0);
      acc[ct] = __builtin_amdgcn_mfma_f32_32x32x16_bf16(al, bh, acc[ct], 0, 0, 0);
    }
  }
#pragma unroll
  for (int ct = 0; ct < 4; ++ct) {
    const int colg = ct * 32 + l31;
    const float bj = bias[colg];
    const int rowg0 = row0 + 4 * hi;
#pragma unroll
    for (int r = 0; r < 16; ++r) {
      const int rowg = rowg0 + (r & 3) + 8 * (r >> 2);
      out[(size_t)rowg * DDIM + colg] = acc[ct][r] + bj;
    }
  }
}

// ---------------------------------------------------------------------------
// MFMA attention. (unchanged, r13: permlane routing + mask-as-C-in)
// ---------------------------------------------------------------------------
__global__ __launch_bounds__(512) void attn_mfma_kernel(
    const float* __restrict__ Q, const float* __restrict__ K,
    const float* __restrict__ V, const float* __restrict__ mask,
    float* __restrict__ po, float* __restrict__ lsum)
{
  __shared__ float mask_lds[PP * 132];   // [p][n-chunk], pad 132 for banks

  const int b = blockIdx.x >> 3;
  const int chunk = blockIdx.x & 7;
  const int n0 = chunk * 128;
  const int tid = threadIdx.x;
  const int h = tid >> 6;          // wave = head
  const int l = tid & 63;
  const int hi = l >> 5;
  const int l31 = l & 31;

  const float NINF = -__builtin_huge_valf();
  for (int idx = tid; idx < PP * 32; idx += 512) {
    const int p = idx >> 5;
    const int c = idx & 31;
    const int nb4 = n0 + 4 * c;
    const int nsrc = min(nb4, NN - 4);
    float4 f = *(const float4*)(mask + ((size_t)(b * PP + p)) * NN + nsrc);
    f.x = (nb4 + 0 < NN) ? f.x : NINF;   // pad columns n>=NN kill via exp(-inf)
    f.y = (nb4 + 1 < NN) ? f.y : NINF;
    f.z = (nb4 + 2 < NN) ? f.z : NINF;
    f.w = (nb4 + 3 < NN) ? f.w : NINF;
    *(float4*)&mask_lds[p * 132 + 4 * c] = f;
  }
  __syncthreads();

  bf16x8 qhi[4], qlo[4];
#pragma unroll
  for (int pt = 0; pt < 4; ++pt) {
    const int qrow = min(b * PP + pt * 32 + l31, BB * PP - 1);
    split8(Q + (size_t)qrow * DDIM + h * 16 + hi * 8, qhi[pt], qlo[pt]);
  }

  f32x16 oacc[4];
#pragma unroll
  for (int pt = 0; pt < 4; ++pt)
#pragma unroll
    for (int i = 0; i < 16; ++i) oacc[pt][i] = 0.f;
  float lacc[4] = {0.f, 0.f, 0.f, 0.f};

  const float* Kb = K + (size_t)b * NN * DDIM + h * 16;
  const float* Vb = V + (size_t)b * NN * DDIM + h * 16;
  const int dv = min(l31, 15);

#pragma unroll 1
  for (int nt = 0; nt < 4; ++nt) {
    const int nb = n0 + nt * 32;

    bf16x8 khi, klo;
    {
      const int krow = min(nb + l31, NN - 1);
      split8(Kb + (size_t)krow * DDIM + hi * 8, khi, klo);
    }
    bf16x8 vhi[2], vlo[2];
#pragma unroll
    for (int ks = 0; ks < 2; ++ks) {
      float vt[8];
#pragma unroll
      for (int i = 0; i < 8; ++i) {
        const int vrow = min(nb + ks * 16 + hi * 8 + i, NN - 1);
        vt[i] = Vb[(size_t)vrow * DDIM + dv];
      }
      unsigned vh[4], vl[4];
#pragma unroll
      for (int j = 0; j < 4; ++j) {
        const unsigned h0 = bf16rne(vt[2*j]), h1 = bf16rne(vt[2*j+1]);
        vh[j] = h0 | (h1 << 16);
        vl[j] = bf16rne(vt[2*j]   - __uint_as_float(h0 << 16)) |
                (bf16rne(vt[2*j+1] - __uint_as_float(h1 << 16)) << 16);
      }
      vhi[ks] = __builtin_bit_cast(bf16x8, u32x4{vh[0], vh[1], vh[2], vh[3]});
      vlo[ks] = __builtin_bit_cast(bf16x8, u32x4{vl[0], vl[1], vl[2], vl[3]});
    }

#pragma unroll
    for (int pt = 0; pt < 4; ++pt) {
      // S^T = K.Q^T with mask as C-in (layout of mq matches C exactly)
      const int prow = min(pt * 32 + l31, PP - 1);
      f32x16 s;
#pragma unroll
      for (int q = 0; q < 4; ++q) {
        const float4 f =
            *(const float4*)&mask_lds[prow * 132 + nt * 32 + q * 8 + hi * 4];
        s[4*q+0] = f.x; s[4*q+1] = f.y; s[4*q+2] = f.z; s[4*q+3] = f.w;
      }
      s = __builtin_amdgcn_mfma_f32_32x32x16_bf16(khi, qhi[pt], s, 0, 0, 0);
      s = __builtin_amdgcn_mfma_f32_32x32x16_bf16(khi, qlo[pt], s, 0, 0, 0);
      s = __builtin_amdgcn_mfma_f32_32x32x16_bf16(klo, qhi[pt], s, 0, 0, 0);

      float ev[16];
#pragma unroll
      for (int r = 0; r < 16; ++r) {
        const float e = __expf(s[r]);   // pad/masked cols: exp(-inf)=0
        ev[r] = e;
        lacc[pt] += e;
      }
      unsigned u[8];
#pragma unroll
      for (int j = 0; j < 8; ++j) u[j] = pk_bf16(ev[2*j], ev[2*j+1]);
      // route C-layout P -> A-frag via permlane32_swap (VALU half-exchange)
#pragma unroll
      for (int ks = 0; ks < 2; ++ks) {
        const unsigned t01 = u[ks*4+0], t23 = u[ks*4+1];
        const unsigned t45 = u[ks*4+2], t67 = u[ks*4+3];
        const u32x2 r0 = __builtin_amdgcn_permlane32_swap(t01, t45, false, false);
        const u32x2 r1 = __builtin_amdgcn_permlane32_swap(t23, t67, false, false);
        const bf16x8 pah = __builtin_bit_cast(bf16x8,
            u32x4{r0[0], r1[0], r0[1], r1[1]});
        oacc[pt] = __builtin_amdgcn_mfma_f32_32x32x16_bf16(pah, vhi[ks], oacc[pt], 0, 0, 0);
        oacc[pt] = __builtin_amdgcn_mfma_f32_32x32x16_bf16(pah, vlo[ks], oacc[pt], 0, 0, 0);
      }
    }
  }

  const int base = (b * NSPL + chunk) * PP;
#pragma unroll
  for (int pt = 0; pt < 4; ++pt) {
    const float ltot = lacc[pt] + __shfl_xor(lacc[pt], 32, 64);
    const int pl = pt * 32 + l31;
    if (l < 32 && pl < PP)
      lsum[(size_t)(base + pl) * HH + h] = ltot;
#pragma unroll
    for (int r = 0; r < 16; ++r) {
      const int p = pt * 32 + (r & 3) + 8 * (r >> 2) + 4 * hi;
      if (l31 < 16 && p < PP)
        po[(size_t)(base + p) * DDIM + h * 16 + l31] = oacc[pt][r];
    }
  }
}

// ---------------------------------------------------------------------------
// merge: mh_in[b][p][d] = (sum_s po) / (sum_s lsum[h(d)])  (unchanged)
// ---------------------------------------------------------------------------
__global__ __launch_bounds__(256) void merge_kernel(
    const float* __restrict__ po, const float* __restrict__ lsum,
    float* __restrict__ mh_in)
{
  const int idx = blockIdx.x * 256 + threadIdx.x;   // over BB*PP*DDIM
  const int d = idx & 127;
  const int row = idx >> 7;        // b*PP + p
  const int b = row / PP;
  const int p = row - b * PP;
  const int h = d >> 4;
  float s = 0.f, lt = 0.f;
#pragma unroll
  for (int sp = 0; sp < NSPL; ++sp) {
    const int base = (b * NSPL + sp) * PP + p;
    s  += po[base * DDIM + d];
    lt += lsum[base * HH + h];
  }
  mh_in[idx] = s / lt;
}

// ---------------------------------------------------------------------------
// score2 round-14: A/B fragments from PREPACKED mhp/encp (round-13 version
// was latency-bound: per-lane 32-line scattered loads + ~96-instr split8
// chains between load and MFMA; MfmaUtil 3.7%, occupancy 19%). Loop is now
// pure coalesced dwordx4 loads + MFMA. Epilogue: cur_min hoisted.
// ---------------------------------------------------------------------------
__global__ __launch_bounds__(256) void score2_mfma_kernel(
    const u32x4* __restrict__ encp, const u32x4* __restrict__ mhp,
    const float* __restrict__ mask, const float* __restrict__ bias_table,
    const int* __restrict__ group_ids, const int* __restrict__ cur_min,
    float* __restrict__ out, float* __restrict__ ssum)
{
  const int b   = blockIdx.x >> 4;
  const int nc  = blockIdx.x & 15;
  const int n0  = nc * 64;
  const int tid = threadIdx.x;
  const int lane = tid & 63;
  const int mt   = tid >> 6;
  const int half = lane >> 5;
  const int l31  = lane & 31;

  f32x16 acc[2];
#pragma unroll
  for (int c = 0; c < 2; ++c)
#pragma unroll
    for (int i = 0; i < 16; ++i) acc[c][i] = 0.f;

  const u32x4* ma  = mhp  + ((size_t)(b * 4 + mt) * 8) * 128 + lane;
  const u32x4* eb0 = encp + ((size_t)(b * 32 + nc * 2) * 8) * 128 + lane;
  const u32x4* eb1 = encp + ((size_t)(b * 32 + nc * 2 + 1) * 8) * 128 + lane;

#pragma unroll 2
  for (int ks = 0; ks < 8; ++ks) {
    const bf16x8 ahi  = __builtin_bit_cast(bf16x8, ma[ks * 128]);
    const bf16x8 alo  = __builtin_bit_cast(bf16x8, ma[ks * 128 + 64]);
    const bf16x8 bhi0 = __builtin_bit_cast(bf16x8, eb0[ks * 128]);
    const bf16x8 blo0 = __builtin_bit_cast(bf16x8, eb0[ks * 128 + 64]);
    const bf16x8 bhi1 = __builtin_bit_cast(bf16x8, eb1[ks * 128]);
    const bf16x8 blo1 = __builtin_bit_cast(bf16x8, eb1[ks * 128 + 64]);
    acc[0] = __builtin_amdgcn_mfma_f32_32x32x16_bf16(ahi, bhi0, acc[0], 0, 0, 0);
    acc[0] = __builtin_amdgcn_mfma_f32_32x32x16_bf16(ahi, blo0, acc[0], 0, 0, 0);
    acc[0] = __builtin_amdgcn_mfma_f32_32x32x16_bf16(alo, bhi0, acc[0], 0, 0, 0);
    acc[1] = __builtin_amdgcn_mfma_f32_32x32x16_bf16(ahi, bhi1, acc[1], 0, 0, 0);
    acc[1] = __builtin_amdgcn_mfma_f32_32x32x16_bf16(ahi, blo1, acc[1], 0, 0, 0);
    acc[1] = __builtin_amdgcn_mfma_f32_32x32x16_bf16(alo, bhi1, acc[1], 0, 0, 0);
  }

  const float t0 = bias_table[0], t1 = bias_table[1], t2 = bias_table[2],
              t3 = bias_table[3], t4 = bias_table[4];
  const float two_inv_sqrt_emb = 0.1767766952966369f;  // 2/sqrt(128)

  // hoist per-row cur_min (independent of ct)
  int cmpv[16];
#pragma unroll
  for (int r = 0; r < 16; ++r) {
    const int p = 32 * mt + (r & 3) + 8 * (r >> 2) + 4 * half;
    cmpv[r] = cur_min[b * PP + min(p, PP - 1)];
  }

  float rsum[16];
#pragma unroll
  for (int r = 0; r < 16; ++r) rsum[r] = 0.f;

#pragma unroll
  for (int ct = 0; ct < 2; ++ct) {
    const int n = n0 + ct * 32 + l31;
    const bool nvalid = n < NN;
    const int nr = nvalid ? n : NN - 1;
    const int gid = group_ids[b * NN + nr];
#pragma unroll
    for (int r = 0; r < 16; ++r) {
      const int p = 32 * mt + (r & 3) + 8 * (r >> 2) + 4 * half;
      const bool pvalid = p < PP;
      const int pr = pvalid ? p : PP - 1;
      const float m = mask[((size_t)(b * PP + pr)) * NN + nr];
      const float ex = __expf(acc[ct][r] * two_inv_sqrt_emb);
      const float sc = 10.0f - 20.0f / (ex + 1.0f);
      int delta = gid - cmpv[r];
      delta = delta < 0 ? 0 : (delta > 4 ? 4 : delta);
      const float pb = (delta == 0) ? t0 : (delta == 1) ? t1 : (delta == 2) ? t2
                     : (delta == 3) ? t3 : t4;
      float e = (nvalid && pvalid) ? __expf(sc + pb + m) : 0.0f;
      if (nvalid && pvalid) out[((size_t)(b * PP + p)) * NN + n] = e;
      rsum[r] += e;
    }
  }
  // one reduce tree per row (hoisted out of ct loop)
#pragma unroll
  for (int r = 0; r < 16; ++r) {
    float ws = rsum[r];
#pragma unroll
    for (int off = 1; off < 32; off <<= 1) ws += __shfl_xor(ws, off, 64);
    rsum[r] = ws;
  }
  if (l31 == 0) {
#pragma unroll
    for (int r = 0; r < 16; ++r) {
      const int p = 32 * mt + (r & 3) + 8 * (r >> 2) + 4 * half;
      if (p < PP) ssum[(size_t)(b * PP + p) * 16 + nc] = rsum[r];
    }
  }
}

// ---------------------------------------------------------------------------
// normalize: out[row][n] /= sum of 16 chunk partials  (unchanged)
// ---------------------------------------------------------------------------
__global__ __launch_bounds__(256) void norm_kernel(
    const float* __restrict__ ssum, float* __restrict__ out)
{
  const int row = blockIdx.x;   // b*PP + p
  float s = 0.f;
#pragma unroll
  for (int i = 0; i < 16; ++i) s += ssum[(size_t)row * 16 + i];
  const float inv = 1.0f / s;
#pragma unroll
  for (int i = 0; i < 4; ++i) {
    const int c = i * 256 + (int)threadIdx.x;
    if (c < NN) out[(size_t)row * NN + c] *= inv;
  }
}

// ---------------------------------------------------------------------------
extern "C" void kernel_launch(void* const* d_in, const int* in_sizes, int n_in,
                              void* d_out, int out_size, void* d_ws, size_t ws_size,
                              hipStream_t stream)
{
  (void)in_sizes; (void)n_in; (void)out_size; (void)ws_size;
  const float* enc_nodes  = (const float*)d_in[0];
  const float* enc_q1     = (const float*)d_in[1];
  const float* enc_last   = (const float*)d_in[2];
  const float* ninf       = (const float*)d_in[3];
  const float* Wq_first   = (const float*)d_in[4];
  const float* Wq_last    = (const float*)d_in[5];
  const float* Wk         = (const float*)d_in[6];
  const float* Wv         = (const float*)d_in[7];
  const float* W_comb     = (const float*)d_in[8];
  const float* b_comb     = (const float*)d_in[9];
  const float* bias_table = (const float*)d_in[10];
  const int*   group_ids  = (const int*)d_in[11];
  const int*   cur_min    = (const int*)d_in[12];
  float* out = (float*)d_out;
  float* ws  = (float*)d_ws;

  float* Qw = ws;                    //   819200 floats (reused as mh_in after attn)
  float* Kw = Qw + 819200;           //  8192000
  float* Vw = Kw + 8192000;          //  8192000
  float* po = Vw + 8192000;          //  6553600  (BB*NSPL*PP*DDIM)
  float* ls = po + 6553600;          //   409600  (BB*NSPL*PP*HH)
  float* mh = ls + 409600;           //   819200
  float* sm = mh + 819200;           //   102400  (BB*PP*16)

  // wfrag (320 KB, 5 matrices) aliases sm: consumed by proj kernels
  // (steps 2,3,6); sm first written by score2 (step 7) -- stream-safe.
  u32x4* wfrag = (u32x4*)sm;
  // encp (33.5 MB) + mhp (4 MB) alias Kw/Vw: K/V dead after attn (step 4);
  // packed after merge (step 5), consumed by score2 (step 7). encp slightly
  // overruns Kw into Vw head; mhp placed after encp -- all within Kw+Vw.
  u32x4* encp = (u32x4*)Kw;                 // 2,097,152 u32x4
  u32x4* mhp  = ((u32x4*)Kw) + 2097152;     //   262,144 u32x4

  // pack all 5 weight matrices into split-bf16 MFMA fragments
  pack_w_kernel<<<40, 256, 0, stream>>>(Wk, Wv, Wq_first, Wq_last, W_comb, wfrag);
  // Q = (q1@Wq_first + last@Wq_last) * 0.25 via MFMA (fold 1/sqrt(QD))
  proj_q2_mfma_kernel<<<BB*PP/128, 256, 0, stream>>>(enc_q1, enc_last, wfrag,
                                                     Qw, 0.25f);
  // K, V projections via split-bf16 MFMA
  proj_kv_mfma_kernel<<<BB*NN/128, 256, 0, stream>>>(enc_nodes, wfrag, Kw, Vw);
  // attention partials via MFMA (QK^T and PV on the matrix pipe)
  attn_mfma_kernel<<<BB*NSPL, 512, 0, stream>>>(Qw, Kw, Vw, ninf, po, ls);
  // merge partials -> mh_in (reuses Qw)
  merge_kernel<<<3200, 256, 0, stream>>>(po, ls, Qw);
  // pack enc into fragment layout (K/V buffers now dead)
  pack_enc_kernel<<<BB*32, 512, 0, stream>>>(enc_nodes, encp);
  // combine: mh = mh_in @ W_comb + b_comb via MFMA
  proj_comb_mfma_kernel<<<BB*PP/128, 256, 0, stream>>>(Qw, wfrag, b_comb, mh);
  // pack mh into A-fragment layout
  pack_mh_kernel<<<BB*4, 512, 0, stream>>>(mh, mhp);
  // final scores via MFMA (prepacked operands) + fused epilogue
  score2_mfma_kernel<<<BB*16, 256, 0, stream>>>(encp, mhp, ninf, bias_table,
                                                group_ids, cur_min, out, sm);
  // normalize
  norm_kernel<<<BB*PP, 256, 0, stream>>>(sm, out);
}